// Round 1
// baseline (3124.273 us; speedup 1.0000x reference)
//
#include <hip/hip_runtime.h>
#include <hip/hip_bf16.h>
#include <math.h>
#include <stdint.h>

#define H_ 16
#define N_ 4096
#define D4_ 16          // 64 dims = 16 float4
#define NT_ 4064        // tail length
#define NL_ 2032        // LSH segment length
#define SINK_ 32
#define SAMP_ 256
#define SCALE_ 0.125f

// ---------------- helpers ----------------
__device__ __forceinline__ float dot64(const float4* __restrict__ a, const float4* __restrict__ b) {
  float s = 0.f;
#pragma unroll
  for (int d = 0; d < D4_; ++d) {
    float4 x = a[d], y = b[d];
    s = fmaf(x.x, y.x, s); s = fmaf(x.y, y.y, s);
    s = fmaf(x.z, y.z, s); s = fmaf(x.w, y.w, s);
  }
  return s;
}

__device__ __forceinline__ float logaddexpf_(float a, float b) {
  float mx = fmaxf(a, b);
  return mx + logf(expf(a - mx) + expf(b - mx));
}

__device__ __forceinline__ uint32_t rotl32_(uint32_t v, uint32_t d) {
  return (v << d) | (v >> (32u - d));
}

// JAX threefry2x32 block cipher (20 rounds)
__device__ inline void tf2x32(uint32_t k0, uint32_t k1, uint32_t& x0, uint32_t& x1) {
  uint32_t ks2 = k0 ^ k1 ^ 0x1BD11BDAu;
  x0 += k0; x1 += k1;
#define TFR(r) { x0 += x1; x1 = rotl32_(x1, r); x1 ^= x0; }
  TFR(13u) TFR(15u) TFR(26u) TFR(6u)
  x0 += k1;  x1 += ks2 + 1u;
  TFR(17u) TFR(29u) TFR(16u) TFR(24u)
  x0 += ks2; x1 += k0 + 2u;
  TFR(13u) TFR(15u) TFR(26u) TFR(6u)
  x0 += k0;  x1 += k1 + 3u;
  TFR(17u) TFR(29u) TFR(16u) TFR(24u)
  x0 += k1;  x1 += ks2 + 4u;
  TFR(13u) TFR(15u) TFR(26u) TFR(6u)
  x0 += ks2; x1 += k0 + 5u;
#undef TFR
}

// ---------------- hashing ----------------
// which==0: q side (query rows 2064+i), which==1: k side (key rows 32+i)
__global__ __launch_bounds__(256) void kern_hash(const float* __restrict__ Q, const float* __restrict__ K,
                                                 const float* __restrict__ proj,
                                                 int* __restrict__ hq, int* __restrict__ hk) {
  const int h = blockIdx.x, tile = blockIdx.y, which = blockIdx.z;
  __shared__ float pr[64 * 7];
  for (int u = threadIdx.x; u < 64 * 7; u += 256) pr[u] = proj[u];
  __syncthreads();
  const int i = tile * 256 + (int)threadIdx.x;
  if (i >= NL_) return;
  const int orig = (which == 0) ? (SINK_ + NL_ + i) : (SINK_ + i);
  const float* x = (which == 0 ? Q : K) + ((size_t)h * N_ + orig) * 64;
  float xr[64];
#pragma unroll
  for (int d = 0; d < 64; ++d) xr[d] = x[d];
  int bin = 0;
#pragma unroll
  for (int r = 0; r < 7; ++r) {
    float acc = 0.f;
#pragma unroll
    for (int d = 0; d < 64; ++d) acc = fmaf(xr[d], pr[d * 7 + r], acc);
    if (acc > 0.f) bin |= (1 << r);
  }
  const int g = bin ^ (bin >> 1);   // _PERM = Gray code
  (which == 0 ? hq : hk)[h * NL_ + i] = g;
}

// ---------------- stable counting sort (ascending hash, ties by index) ----------------
__global__ __launch_bounds__(128) void kern_sort(const int* __restrict__ hq, const int* __restrict__ hk,
                                                 int* __restrict__ q_sort, int* __restrict__ k_sort) {
  const int h = blockIdx.x;
  const int which = blockIdx.y;   // 0 = q, 1 = k
  const int* src = (which == 0 ? hq : hk) + h * NL_;
  __shared__ int lh[NL_];
  __shared__ int cnts[128];
  __shared__ int offs[128];
  for (int u = threadIdx.x; u < NL_; u += 128) lh[u] = src[u];
  __syncthreads();
  const int b = threadIdx.x;   // bucket 0..127
  int c = 0;
  for (int u = 0; u < NL_; ++u) c += (lh[u] == b) ? 1 : 0;
  cnts[b] = c;
  __syncthreads();
  if (b == 0) { int a = 0; for (int u = 0; u < 128; ++u) { offs[u] = a; a += cnts[u]; } }
  __syncthreads();
  int off = offs[b];
  int* dst = (which == 0 ? q_sort : k_sort) + h * NL_;
  for (int u = 0; u < NL_; ++u) {
    if (lh[u] == b) { dst[off] = u; ++off; }
  }
}

// ---------------- threefry sampling (JAX partitionable semantics) ----------------
__global__ void kern_sample(const int* __restrict__ k_sort,
                            int* __restrict__ samp_pos, int* __restrict__ samp_orig) {
  const int h = blockIdx.x;
  const int s = threadIdx.x;
  // skey = fold_in(key(1234), 0) = E_(0,1234)(0,0)
  uint32_t a0 = 0u, a1 = 0u; tf2x32(0u, 1234u, a0, a1);
  // split(skey) foldlike: k1 = E_skey(0,0), k2 = E_skey(0,1)
  uint32_t b0 = 0u, b1 = 0u; tf2x32(a0, a1, b0, b1);
  uint32_t c0 = 0u, c1 = 1u; tf2x32(a0, a1, c0, c1);
  const uint32_t j = (uint32_t)(h * SAMP_ + s);
  // random_bits(32) partitionable: bits = x0 ^ x1 of E(hi=0, lo=j)
  uint32_t h0 = 0u, h1 = j; tf2x32(b0, b1, h0, h1);
  uint32_t l0 = 0u, l1 = j; tf2x32(c0, c1, l0, l1);
  const uint32_t Hb = h0 ^ h1, Lb = l0 ^ l1;
  // randint: span=2032, multiplier = 2^32 % 2032 = 16
  const uint32_t off = ((Hb % 2032u) * 16u + (Lb % 2032u)) % 2032u;
  samp_pos[h * SAMP_ + s] = (int)off;
  samp_orig[h * SAMP_ + s] = k_sort[h * NL_ + (int)off];
}

// ---------------- P1: causal attention within 1016-chunks ----------------
__global__ __launch_bounds__(256) void kern_p1(const float* __restrict__ Q, const float* __restrict__ K,
                                               const float* __restrict__ V,
                                               float* __restrict__ tail_attn, float* __restrict__ tail_lse) {
  const int vh = blockIdx.x;           // 64 virtual heads
  const int h = vh >> 2, c = vh & 3;
  const int tile = blockIdx.y;         // 4
  const int tid = threadIdx.x;
  const int i = tile * 256 + tid;
  const bool active = (i < 1016);
  const int maxrow = min(1015, tile * 256 + 255);

  __shared__ float4 kk[64 * D4_];
  __shared__ float4 vv[64 * D4_];

  float4 q4[D4_], acc[D4_];
#pragma unroll
  for (int d = 0; d < D4_; ++d) acc[d] = make_float4(0.f, 0.f, 0.f, 0.f);
  if (active) {
    const float4* qp = (const float4*)(Q + ((size_t)h * N_ + (SINK_ + c * 1016 + i)) * 64);
#pragma unroll
    for (int d = 0; d < D4_; ++d) q4[d] = qp[d];
  }
  float m = -INFINITY, ssum = 0.f;
  const int krow0 = SINK_ + c * 1016;

  for (int jt = 0; jt <= maxrow; jt += 64) {
    for (int u = tid; u < 64 * D4_; u += 256) {
      const int r = u >> 4, d4 = u & 15;
      const int kr = jt + r;
      if (kr < 1016) {
        kk[u] = ((const float4*)(K + ((size_t)h * N_ + (krow0 + kr)) * 64))[d4];
        vv[u] = ((const float4*)(V + ((size_t)h * N_ + (krow0 + kr)) * 64))[d4];
      } else { kk[u] = make_float4(0,0,0,0); vv[u] = make_float4(0,0,0,0); }
    }
    __syncthreads();
    if (active) {
      const int jend = min(i, jt + 63);
      for (int j = jt; j <= jend; ++j) {
        const float sc = dot64(q4, &kk[(j - jt) * D4_]) * SCALE_;
        const float nm = fmaxf(m, sc);
        const float f = expf(m - nm), w = expf(sc - nm);
        ssum = ssum * f + w;
        const float4* v4 = &vv[(j - jt) * D4_];
#pragma unroll
        for (int d = 0; d < D4_; ++d) {
          acc[d].x = acc[d].x * f + w * v4[d].x;
          acc[d].y = acc[d].y * f + w * v4[d].y;
          acc[d].z = acc[d].z * f + w * v4[d].z;
          acc[d].w = acc[d].w * f + w * v4[d].w;
        }
        m = nm;
      }
    }
    __syncthreads();
  }
  if (active) {
    const int t = c * 1016 + i;
    const float inv = 1.f / ssum;
    float4* op = (float4*)(tail_attn + ((size_t)h * NT_ + t) * 64);
#pragma unroll
    for (int d = 0; d < D4_; ++d)
      op[d] = make_float4(acc[d].x * inv, acc[d].y * inv, acc[d].z * inv, acc[d].w * inv);
    tail_lse[h * NT_ + t] = m + logf(ssum);
  }
}

// ---------------- P2: off-diagonal non-causal, merged into tail ----------------
__global__ __launch_bounds__(256) void kern_p2(const float* __restrict__ Q, const float* __restrict__ K,
                                               const float* __restrict__ V,
                                               float* __restrict__ tail_attn, float* __restrict__ tail_lse) {
  const int vh = blockIdx.x;           // 32
  const int h = vh >> 1, pp = vh & 1;
  const int i = blockIdx.y * 256 + (int)threadIdx.x;
  const bool active = (i < 1016);
  const int t = pp * 2032 + 1016 + i;

  __shared__ float4 kk[64 * D4_];
  __shared__ float4 vv[64 * D4_];

  float4 q4[D4_], acc[D4_];
#pragma unroll
  for (int d = 0; d < D4_; ++d) acc[d] = make_float4(0.f, 0.f, 0.f, 0.f);
  if (active) {
    const float4* qp = (const float4*)(Q + ((size_t)h * N_ + (SINK_ + t)) * 64);
#pragma unroll
    for (int d = 0; d < D4_; ++d) q4[d] = qp[d];
  }
  float m = -INFINITY, ssum = 0.f;
  const int kbase = SINK_ + pp * 2032;

  for (int jt = 0; jt < 1016; jt += 64) {
    for (int u = threadIdx.x; u < 64 * D4_; u += 256) {
      const int r = u >> 4, d4 = u & 15;
      const int kr = jt + r;
      if (kr < 1016) {
        kk[u] = ((const float4*)(K + ((size_t)h * N_ + (kbase + kr)) * 64))[d4];
        vv[u] = ((const float4*)(V + ((size_t)h * N_ + (kbase + kr)) * 64))[d4];
      } else { kk[u] = make_float4(0,0,0,0); vv[u] = make_float4(0,0,0,0); }
    }
    __syncthreads();
    if (active) {
      const int jn = min(64, 1016 - jt);
      for (int j = 0; j < jn; ++j) {
        const float sc = dot64(q4, &kk[j * D4_]) * SCALE_;
        const float nm = fmaxf(m, sc);
        const float f = expf(m - nm), w = expf(sc - nm);
        ssum = ssum * f + w;
        const float4* v4 = &vv[j * D4_];
#pragma unroll
        for (int d = 0; d < D4_; ++d) {
          acc[d].x = acc[d].x * f + w * v4[d].x;
          acc[d].y = acc[d].y * f + w * v4[d].y;
          acc[d].z = acc[d].z * f + w * v4[d].z;
          acc[d].w = acc[d].w * f + w * v4[d].w;
        }
        m = nm;
      }
    }
    __syncthreads();
  }
  if (active) {
    const float un_lse = m + logf(ssum);
    const float inv = 1.f / ssum;
    float* tlp = tail_lse + h * NT_ + t;
    const float bl = *tlp;
    const float cmix = 1.f / (1.f + expf(un_lse - bl));   // sigmoid(bl - un_lse)
    float4* tp = (float4*)(tail_attn + ((size_t)h * NT_ + t) * 64);
#pragma unroll
    for (int d = 0; d < D4_; ++d) {
      float4 bd = tp[d];
      tp[d] = make_float4(cmix * bd.x + (1.f - cmix) * acc[d].x * inv,
                          cmix * bd.y + (1.f - cmix) * acc[d].y * inv,
                          cmix * bd.z + (1.f - cmix) * acc[d].z * inv,
                          cmix * bd.w + (1.f - cmix) * acc[d].w * inv);
    }
    *tlp = logaddexpf_(bl, un_lse);
  }
}

// ---------------- LSH block-diagonal attention (sorted coords) ----------------
__global__ __launch_bounds__(256) void kern_block(const float* __restrict__ Q, const float* __restrict__ K,
                                                  const float* __restrict__ V,
                                                  const int* __restrict__ q_sort, const int* __restrict__ k_sort,
                                                  float* __restrict__ attn_block, float* __restrict__ lse_block) {
  const int h = blockIdx.x, blk = blockIdx.y;
  const int tid = threadIdx.x;
  const int p = blk * 256 + tid;
  const bool active = (p < NL_);

  __shared__ int ksrt[256];
  const int slot = blk * 256 + tid;
  ksrt[tid] = (slot < NL_) ? k_sort[h * NL_ + slot] : -1;
  __syncthreads();

  __shared__ float4 kk[64 * D4_];
  __shared__ float4 vv[64 * D4_];

  float4 q4[D4_], acc[D4_];
#pragma unroll
  for (int d = 0; d < D4_; ++d) acc[d] = make_float4(0.f, 0.f, 0.f, 0.f);
  if (active) {
    const int qi = q_sort[h * NL_ + p];
    const float4* qp = (const float4*)(Q + ((size_t)h * N_ + (SINK_ + NL_ + qi)) * 64);
#pragma unroll
    for (int d = 0; d < D4_; ++d) q4[d] = qp[d];
  }
  float m = -INFINITY, ssum = 0.f;

  for (int jt = 0; jt < 256; jt += 64) {
    for (int u = tid; u < 64 * D4_; u += 256) {
      const int r = u >> 4, d4 = u & 15;
      const int ko = ksrt[jt + r];
      if (ko >= 0) {
        kk[u] = ((const float4*)(K + ((size_t)h * N_ + (SINK_ + ko)) * 64))[d4];
        vv[u] = ((const float4*)(V + ((size_t)h * N_ + (SINK_ + ko)) * 64))[d4];
      } else { kk[u] = make_float4(0,0,0,0); vv[u] = make_float4(0,0,0,0); }  // pad key: score 0, v 0
    }
    __syncthreads();
    if (active) {
      for (int j = 0; j < 64; ++j) {   // pad keys included (score exactly 0)
        const float sc = dot64(q4, &kk[j * D4_]) * SCALE_;
        const float nm = fmaxf(m, sc);
        const float f = expf(m - nm), w = expf(sc - nm);
        ssum = ssum * f + w;
        const float4* v4 = &vv[j * D4_];
#pragma unroll
        for (int d = 0; d < D4_; ++d) {
          acc[d].x = acc[d].x * f + w * v4[d].x;
          acc[d].y = acc[d].y * f + w * v4[d].y;
          acc[d].z = acc[d].z * f + w * v4[d].z;
          acc[d].w = acc[d].w * f + w * v4[d].w;
        }
        m = nm;
      }
    }
    __syncthreads();
  }
  if (active) {
    const float inv = 1.f / ssum;
    float4* op = (float4*)(attn_block + ((size_t)h * NL_ + p) * 64);
#pragma unroll
    for (int d = 0; d < D4_; ++d)
      op[d] = make_float4(acc[d].x * inv, acc[d].y * inv, acc[d].z * inv, acc[d].w * inv);
    lse_block[h * NL_ + p] = m + logf(ssum);
  }
}

// ---------------- sampled residual attention + LSH merge + unsort + merge into tail ----------------
__global__ __launch_bounds__(256) void kern_sampmerge(const float* __restrict__ Q, const float* __restrict__ K,
                                                      const float* __restrict__ V,
                                                      const int* __restrict__ q_sort,
                                                      const int* __restrict__ samp_pos, const int* __restrict__ samp_orig,
                                                      const float* __restrict__ attn_block, const float* __restrict__ lse_block,
                                                      float* __restrict__ tail_attn, float* __restrict__ tail_lse) {
  const int h = blockIdx.x, blk = blockIdx.y;   // qblk == blk for all threads (uniform mask)
  const int tid = threadIdx.x;
  const int p = blk * 256 + tid;
  const bool active = (p < NL_);

  __shared__ float4 kk[64 * D4_];
  __shared__ float4 vv[64 * D4_];
  __shared__ int kb[64];

  float4 q4[D4_], acc[D4_];
#pragma unroll
  for (int d = 0; d < D4_; ++d) acc[d] = make_float4(0.f, 0.f, 0.f, 0.f);
  int qi = 0;
  if (active) {
    qi = q_sort[h * NL_ + p];
    const float4* qp = (const float4*)(Q + ((size_t)h * N_ + (SINK_ + NL_ + qi)) * 64);
#pragma unroll
    for (int d = 0; d < D4_; ++d) q4[d] = qp[d];
  }
  float m = -INFINITY, ssum = 0.f;

  for (int st = 0; st < SAMP_; st += 64) {
    for (int u = tid; u < 64 * D4_; u += 256) {
      const int r = u >> 4, d4 = u & 15;
      const int so = samp_orig[h * SAMP_ + st + r];
      kk[u] = ((const float4*)(K + ((size_t)h * N_ + (SINK_ + so)) * 64))[d4];
      vv[u] = ((const float4*)(V + ((size_t)h * N_ + (SINK_ + so)) * 64))[d4];
    }
    if (tid < 64) kb[tid] = samp_pos[h * SAMP_ + st + tid] >> 8;
    __syncthreads();
    if (active) {
      for (int j = 0; j < 64; ++j) {
        if (kb[j] == blk) continue;   // bias: same-block samples masked out
        const float sc = dot64(q4, &kk[j * D4_]) * SCALE_;
        const float nm = fmaxf(m, sc);
        const float f = expf(m - nm), w = expf(sc - nm);
        ssum = ssum * f + w;
        const float4* v4 = &vv[j * D4_];
#pragma unroll
        for (int d = 0; d < D4_; ++d) {
          acc[d].x = acc[d].x * f + w * v4[d].x;
          acc[d].y = acc[d].y * f + w * v4[d].y;
          acc[d].z = acc[d].z * f + w * v4[d].z;
          acc[d].w = acc[d].w * f + w * v4[d].w;
        }
        m = nm;
      }
    }
    __syncthreads();
  }
  if (active) {
    float rl, inv;
    if (ssum > 0.f) { rl = m + logf(ssum) + logf(2032.0f / 256.0f); inv = 1.f / ssum; }
    else            { rl = -3.0e38f; inv = 0.f; }
    const float bl = lse_block[h * NL_ + p];
    const float c1 = 1.f / (1.f + expf(rl - bl));       // sigmoid(bl - rl)
    const float un_lse = logaddexpf_(bl, rl);
    const float4* ab = (const float4*)(attn_block + ((size_t)h * NL_ + p) * 64);
    const int t = NL_ + qi;                             // unsort: scatter to original row
    float* tlp = tail_lse + h * NT_ + t;
    const float bd = *tlp;
    const float c2 = 1.f / (1.f + expf(un_lse - bd));   // sigmoid(bd - un_lse)
    float4* tp = (float4*)(tail_attn + ((size_t)h * NT_ + t) * 64);
#pragma unroll
    for (int d = 0; d < D4_; ++d) {
      const float4 a_b = ab[d];
      const float ux = c1 * a_b.x + (1.f - c1) * acc[d].x * inv;
      const float uy = c1 * a_b.y + (1.f - c1) * acc[d].y * inv;
      const float uz = c1 * a_b.z + (1.f - c1) * acc[d].z * inv;
      const float uw = c1 * a_b.w + (1.f - c1) * acc[d].w * inv;
      const float4 tv = tp[d];
      tp[d] = make_float4(c2 * tv.x + (1.f - c2) * ux,
                          c2 * tv.y + (1.f - c2) * uy,
                          c2 * tv.z + (1.f - c2) * uz,
                          c2 * tv.w + (1.f - c2) * uw);
    }
    *tlp = logaddexpf_(bd, un_lse);
  }
}

// ---------------- sink prefix (computed on the fly) + final merge ----------------
__global__ __launch_bounds__(256) void kern_final(const float* __restrict__ Q, const float* __restrict__ K,
                                                  const float* __restrict__ V,
                                                  const float* __restrict__ tail_attn, const float* __restrict__ tail_lse,
                                                  float* __restrict__ out) {
  const int h = blockIdx.x;
  const int r = blockIdx.y * 256 + (int)threadIdx.x;   // 0..4095

  __shared__ float4 kk[SINK_ * D4_];
  __shared__ float4 vv[SINK_ * D4_];
  for (int u = threadIdx.x; u < SINK_ * D4_; u += 256) {
    const int row = u >> 4, d4 = u & 15;
    kk[u] = ((const float4*)(K + ((size_t)h * N_ + row) * 64))[d4];
    vv[u] = ((const float4*)(V + ((size_t)h * N_ + row) * 64))[d4];
  }
  __syncthreads();

  float4 q4[D4_], acc[D4_];
  const float4* qp = (const float4*)(Q + ((size_t)h * N_ + r) * 64);
#pragma unroll
  for (int d = 0; d < D4_; ++d) { q4[d] = qp[d]; acc[d] = make_float4(0.f, 0.f, 0.f, 0.f); }

  float m = -INFINITY, ssum = 0.f;
  const int nk = min(SINK_, r + 1);   // causal vs first 32 keys
  for (int j = 0; j < nk; ++j) {
    const float sc = dot64(q4, &kk[j * D4_]) * SCALE_;
    const float nm = fmaxf(m, sc);
    const float f = expf(m - nm), w = expf(sc - nm);
    ssum = ssum * f + w;
    const float4* v4 = &vv[j * D4_];
#pragma unroll
    for (int d = 0; d < D4_; ++d) {
      acc[d].x = acc[d].x * f + w * v4[d].x;
      acc[d].y = acc[d].y * f + w * v4[d].y;
      acc[d].z = acc[d].z * f + w * v4[d].z;
      acc[d].w = acc[d].w * f + w * v4[d].w;
    }
    m = nm;
  }
  const float pl = m + logf(ssum);
  const float inv = 1.f / ssum;
  float4* op = (float4*)(out + ((size_t)h * N_ + r) * 64);
  if (r < SINK_) {
#pragma unroll
    for (int d = 0; d < D4_; ++d)
      op[d] = make_float4(acc[d].x * inv, acc[d].y * inv, acc[d].z * inv, acc[d].w * inv);
  } else {
    const int t = r - SINK_;
    const float tl = tail_lse[h * NT_ + t];
    const float cc = 1.f / (1.f + expf(tl - pl));   // sigmoid(prefix_lse - tail_lse)
    const float4* tp = (const float4*)(tail_attn + ((size_t)h * NT_ + t) * 64);
#pragma unroll
    for (int d = 0; d < D4_; ++d) {
      const float4 tv = tp[d];
      op[d] = make_float4(cc * acc[d].x * inv + (1.f - cc) * tv.x,
                          cc * acc[d].y * inv + (1.f - cc) * tv.y,
                          cc * acc[d].z * inv + (1.f - cc) * tv.z,
                          cc * acc[d].w * inv + (1.f - cc) * tv.w);
    }
  }
}

// ---------------- host ----------------
extern "C" void kernel_launch(void* const* d_in, const int* in_sizes, int n_in,
                              void* d_out, int out_size, void* d_ws, size_t ws_size,
                              hipStream_t stream) {
  (void)in_sizes; (void)n_in; (void)out_size; (void)ws_size;
  const float* Q = (const float*)d_in[0];
  const float* K = (const float*)d_in[1];
  const float* V = (const float*)d_in[2];
  const float* proj = (const float*)d_in[3];
  float* out = (float*)d_out;

  char* w = (char*)d_ws;
  auto carve = [&](size_t bytes) { char* p = w; w += (bytes + 255) & ~(size_t)255; return p; };
  float* tail_attn  = (float*)carve((size_t)H_ * NT_ * 64 * sizeof(float));
  float* tail_lse   = (float*)carve((size_t)H_ * NT_ * sizeof(float));
  float* attn_block = (float*)carve((size_t)H_ * NL_ * 64 * sizeof(float));
  float* lse_block  = (float*)carve((size_t)H_ * NL_ * sizeof(float));
  int* hq        = (int*)carve((size_t)H_ * NL_ * sizeof(int));
  int* hk        = (int*)carve((size_t)H_ * NL_ * sizeof(int));
  int* q_sort    = (int*)carve((size_t)H_ * NL_ * sizeof(int));
  int* k_sort    = (int*)carve((size_t)H_ * NL_ * sizeof(int));
  int* samp_pos  = (int*)carve((size_t)H_ * SAMP_ * sizeof(int));
  int* samp_orig = (int*)carve((size_t)H_ * SAMP_ * sizeof(int));

  kern_hash<<<dim3(H_, 8, 2), 256, 0, stream>>>(Q, K, proj, hq, hk);
  kern_sort<<<dim3(H_, 2), 128, 0, stream>>>(hq, hk, q_sort, k_sort);
  kern_sample<<<dim3(H_), SAMP_, 0, stream>>>(k_sort, samp_pos, samp_orig);
  kern_p1<<<dim3(64, 4), 256, 0, stream>>>(Q, K, V, tail_attn, tail_lse);
  kern_p2<<<dim3(32, 4), 256, 0, stream>>>(Q, K, V, tail_attn, tail_lse);
  kern_block<<<dim3(H_, 8), 256, 0, stream>>>(Q, K, V, q_sort, k_sort, attn_block, lse_block);
  kern_sampmerge<<<dim3(H_, 8), 256, 0, stream>>>(Q, K, V, q_sort, samp_pos, samp_orig,
                                                  attn_block, lse_block, tail_attn, tail_lse);
  kern_final<<<dim3(H_, 16), 256, 0, stream>>>(Q, K, V, tail_attn, tail_lse, out);
}

// Round 2
// 1486.914 us; speedup vs baseline: 2.1012x; 2.1012x over previous
//
#include <hip/hip_runtime.h>
#include <hip/hip_bf16.h>
#include <math.h>
#include <stdint.h>

#define H_ 16
#define N_ 4096
#define NT_ 4064        // tail length
#define NL_ 2032        // LSH segment length
#define SINK_ 32
#define SAMP_ 256
#define SCALE_ 0.125f
#define NEGBIG_ -3.0e38f
#define LOGOFF_ 2.0719334f   // log(2032/256)

typedef unsigned int uint;

// ---------------- bf16 pack/unpack (RNE pack, bit-op unpack) ----------------
__device__ __forceinline__ float bl_(uint u) { return __uint_as_float(u << 16); }
__device__ __forceinline__ float bh_(uint u) { return __uint_as_float(u & 0xffff0000u); }
__device__ __forceinline__ uint bfpack(float a, float b) {
  uint ua = __float_as_uint(a), ub = __float_as_uint(b);
  ua += 0x7fffu + ((ua >> 16) & 1u);
  ub += 0x7fffu + ((ub >> 16) & 1u);
  return (ua >> 16) | (ub & 0xffff0000u);
}

__device__ __forceinline__ float logaddexpf_(float a, float b) {
  float mx = fmaxf(a, b);
  return mx + __logf(__expf(a - mx) + __expf(b - mx));
}

__device__ __forceinline__ uint32_t rotl32_(uint32_t v, uint32_t d) {
  return (v << d) | (v >> (32u - d));
}

// JAX threefry2x32 (20 rounds)
__device__ inline void tf2x32(uint32_t k0, uint32_t k1, uint32_t& x0, uint32_t& x1) {
  uint32_t ks2 = k0 ^ k1 ^ 0x1BD11BDAu;
  x0 += k0; x1 += k1;
#define TFR(r) { x0 += x1; x1 = rotl32_(x1, r); x1 ^= x0; }
  TFR(13u) TFR(15u) TFR(26u) TFR(6u)
  x0 += k1;  x1 += ks2 + 1u;
  TFR(17u) TFR(29u) TFR(16u) TFR(24u)
  x0 += ks2; x1 += k0 + 2u;
  TFR(13u) TFR(15u) TFR(26u) TFR(6u)
  x0 += k0;  x1 += k1 + 3u;
  TFR(17u) TFR(29u) TFR(16u) TFR(24u)
  x0 += k1;  x1 += ks2 + 4u;
  TFR(13u) TFR(15u) TFR(26u) TFR(6u)
  x0 += ks2; x1 += k0 + 5u;
#undef TFR
}

// ---------------- packed-bf16 dot: 64 dims, 4 independent chains ----------------
__device__ __forceinline__ float dot64bf(const float* __restrict__ qr, const uint* __restrict__ krow) {
  const uint4* kp = (const uint4*)krow;
  float p0 = 0.f, p1 = 0.f, p2 = 0.f, p3 = 0.f;
#pragma unroll
  for (int t = 0; t < 8; ++t) {
    uint4 a = kp[t];
    const float* q8 = qr + t * 8;
    p0 = fmaf(bl_(a.x), q8[0], p0); p1 = fmaf(bh_(a.x), q8[1], p1);
    p2 = fmaf(bl_(a.y), q8[2], p2); p3 = fmaf(bh_(a.y), q8[3], p3);
    p0 = fmaf(bl_(a.z), q8[4], p0); p1 = fmaf(bh_(a.z), q8[5], p1);
    p2 = fmaf(bl_(a.w), q8[6], p2); p3 = fmaf(bh_(a.w), q8[7], p3);
  }
  return (p0 + p1) + (p2 + p3);
}

// online-softmax update for 4 keys at once (scores pre-masked)
__device__ __forceinline__ void grp_update(float* __restrict__ ar,
                                           float s0, float s1, float s2, float s3,
                                           const uint* __restrict__ v0, const uint* __restrict__ v1,
                                           const uint* __restrict__ v2, const uint* __restrict__ v3,
                                           float& m, float& ssum) {
  const float nm = fmaxf(m, fmaxf(fmaxf(s0, s1), fmaxf(s2, s3)));
  const float f  = __expf(m - nm);
  const float w0 = __expf(s0 - nm), w1 = __expf(s1 - nm);
  const float w2 = __expf(s2 - nm), w3 = __expf(s3 - nm);
  ssum = ssum * f + ((w0 + w1) + (w2 + w3));
  const uint4* a0 = (const uint4*)v0; const uint4* a1 = (const uint4*)v1;
  const uint4* a2 = (const uint4*)v2; const uint4* a3 = (const uint4*)v3;
#pragma unroll
  for (int t = 0; t < 8; ++t) {
    uint4 x0 = a0[t], x1 = a1[t], x2 = a2[t], x3 = a3[t];
    float* a = ar + t * 8;
#define AUP(idx, EX, c) { float z = a[idx] * f; z = fmaf(w0, EX(x0.c), z); z = fmaf(w1, EX(x1.c), z); \
                          z = fmaf(w2, EX(x2.c), z); z = fmaf(w3, EX(x3.c), z); a[idx] = z; }
    AUP(0, bl_, x) AUP(1, bh_, x) AUP(2, bl_, y) AUP(3, bh_, y)
    AUP(4, bl_, z) AUP(5, bh_, z) AUP(6, bl_, w) AUP(7, bh_, w)
#undef AUP
  }
  m = nm;
}

// ---------------- hashing ----------------
__global__ __launch_bounds__(256) void kern_hash(const float* __restrict__ Q, const float* __restrict__ K,
                                                 const float* __restrict__ proj,
                                                 int* __restrict__ hq, int* __restrict__ hk) {
  const int h = blockIdx.x, tile = blockIdx.y, which = blockIdx.z;
  __shared__ float pr[64 * 7];
  for (int u = threadIdx.x; u < 64 * 7; u += 256) pr[u] = proj[u];
  __syncthreads();
  const int i = tile * 256 + (int)threadIdx.x;
  if (i >= NL_) return;
  const int orig = (which == 0) ? (SINK_ + NL_ + i) : (SINK_ + i);
  const float4* x = (const float4*)((which == 0 ? Q : K) + ((size_t)h * N_ + orig) * 64);
  float xr[64];
#pragma unroll
  for (int d = 0; d < 16; ++d) {
    float4 g = x[d];
    xr[4*d+0] = g.x; xr[4*d+1] = g.y; xr[4*d+2] = g.z; xr[4*d+3] = g.w;
  }
  int bin = 0;
#pragma unroll
  for (int r = 0; r < 7; ++r) {
    float acc = 0.f;
#pragma unroll
    for (int d = 0; d < 64; ++d) acc = fmaf(xr[d], pr[d * 7 + r], acc);
    if (acc > 0.f) bin |= (1 << r);
  }
  const int g = bin ^ (bin >> 1);   // _PERM = Gray code
  (which == 0 ? hq : hk)[h * NL_ + i] = g;
}

// ---------------- stable counting sort ----------------
__global__ __launch_bounds__(128) void kern_sort(const int* __restrict__ hq, const int* __restrict__ hk,
                                                 int* __restrict__ q_sort, int* __restrict__ k_sort) {
  const int h = blockIdx.x;
  const int which = blockIdx.y;
  const int* src = (which == 0 ? hq : hk) + h * NL_;
  __shared__ int lh[NL_];
  __shared__ int cnts[128];
  __shared__ int offs[128];
  for (int u = threadIdx.x; u < NL_; u += 128) lh[u] = src[u];
  __syncthreads();
  const int b = threadIdx.x;
  int c = 0;
  for (int u = 0; u < NL_; ++u) c += (lh[u] == b) ? 1 : 0;
  cnts[b] = c;
  __syncthreads();
  if (b == 0) { int a = 0; for (int u = 0; u < 128; ++u) { offs[u] = a; a += cnts[u]; } }
  __syncthreads();
  int off = offs[b];
  int* dst = (which == 0 ? q_sort : k_sort) + h * NL_;
  for (int u = 0; u < NL_; ++u) {
    if (lh[u] == b) { dst[off] = u; ++off; }
  }
}

// ---------------- threefry sampling ----------------
__global__ void kern_sample(const int* __restrict__ k_sort,
                            int* __restrict__ samp_pos, int* __restrict__ samp_orig) {
  const int h = blockIdx.x;
  const int s = threadIdx.x;
  uint32_t a0 = 0u, a1 = 0u; tf2x32(0u, 1234u, a0, a1);
  uint32_t b0 = 0u, b1 = 0u; tf2x32(a0, a1, b0, b1);
  uint32_t c0 = 0u, c1 = 1u; tf2x32(a0, a1, c0, c1);
  const uint32_t j = (uint32_t)(h * SAMP_ + s);
  uint32_t h0 = 0u, h1 = j; tf2x32(b0, b1, h0, h1);
  uint32_t l0 = 0u, l1 = j; tf2x32(c0, c1, l0, l1);
  const uint32_t Hb = h0 ^ h1, Lb = l0 ^ l1;
  const uint32_t off = ((Hb % 2032u) * 16u + (Lb % 2032u)) % 2032u;
  samp_pos[h * SAMP_ + s] = (int)off;
  samp_orig[h * SAMP_ + s] = k_sort[h * NL_ + (int)off];
}

// ---------------- fused P1 (causal chunks) + P2 (off-diagonal) ----------------
// blocks 0..255: p2 units (vh32 x 8 qtiles of 128 rows), all-heavy, dispatched first
// blocks 256..767: p1 units (qt descending = heavy-first LPT)
__global__ __launch_bounds__(128) void kern_attn(const float* __restrict__ Q, const float* __restrict__ K,
                                                 const float* __restrict__ V,
                                                 float* __restrict__ tail_attn, float* __restrict__ tail_lse,
                                                 float* __restrict__ attn2, float* __restrict__ lse2) {
  const int b = blockIdx.x;
  const int tid = threadIdx.x;
  __shared__ uint kk[64 * 32];
  __shared__ uint vv[64 * 32];

  int h, i, il, krow0, qrow, kmax, lim;
  bool causal, active;
  int p2vh = 0, p1t = 0;
  if (b < 256) {                      // P2
    const int u = b, vh = u & 31, qt = u >> 5;
    h = vh >> 1; const int pp = vh & 1;
    i = qt * 128 + tid; active = (i < 1016);
    qrow = SINK_ + pp * 2032 + 1016 + i;
    krow0 = SINK_ + pp * 2032;
    kmax = 1015; lim = 1015; causal = false;
    p2vh = vh; il = 0;
  } else {                            // P1
    const int u = b - 256, qtp = u >> 6, vh = u & 63;
    const int qt = 7 - qtp;
    h = vh >> 2; const int c = vh & 3;
    i = qt * 128 + tid; active = (i < 1016);
    qrow = SINK_ + c * 1016 + i;
    krow0 = SINK_ + c * 1016;
    kmax = min(1015, qt * 128 + 127);
    il = i; lim = i; causal = true;
    p1t = c * 1016 + i;
  }

  float qr[64], ar[64];
#pragma unroll
  for (int d = 0; d < 64; ++d) ar[d] = 0.f;
  if (active) {
    const float4* qp = (const float4*)(Q + ((size_t)h * N_ + qrow) * 64);
#pragma unroll
    for (int d = 0; d < 16; ++d) {
      float4 g = qp[d];
      qr[4*d+0] = g.x * SCALE_; qr[4*d+1] = g.y * SCALE_;
      qr[4*d+2] = g.z * SCALE_; qr[4*d+3] = g.w * SCALE_;
    }
  } else {
#pragma unroll
    for (int d = 0; d < 64; ++d) qr[d] = 0.f;
  }
  float m = -INFINITY, ssum = 0.f;

  for (int kt = 0; kt <= kmax; kt += 64) {
    // stage 64 keys as packed bf16
    for (int u = tid; u < 1024; u += 128) {
      const int r = u >> 4, d4 = u & 15;
      const int kr = kt + r;
      uint2 pk, pv;
      if (kr < 1016) {
        const float4 gk = ((const float4*)(K + ((size_t)h * N_ + krow0 + kr) * 64))[d4];
        const float4 gv = ((const float4*)(V + ((size_t)h * N_ + krow0 + kr) * 64))[d4];
        pk = make_uint2(bfpack(gk.x, gk.y), bfpack(gk.z, gk.w));
        pv = make_uint2(bfpack(gv.x, gv.y), bfpack(gv.z, gv.w));
      } else { pk = make_uint2(0u, 0u); pv = make_uint2(0u, 0u); }
      ((uint2*)kk)[u] = pk;
      ((uint2*)vv)[u] = pv;
    }
    __syncthreads();
    if (active) {
      for (int j0 = 0; j0 < 64; j0 += 4) {
        const int jj = kt + j0;
        const uint* k0 = kk + (j0 + 0) * 32; const uint* k1 = kk + (j0 + 1) * 32;
        const uint* k2 = kk + (j0 + 2) * 32; const uint* k3 = kk + (j0 + 3) * 32;
        float s0 = dot64bf(qr, k0), s1 = dot64bf(qr, k1);
        float s2 = dot64bf(qr, k2), s3 = dot64bf(qr, k3);
        s0 = (jj + 0 <= lim) ? s0 : NEGBIG_;
        s1 = (jj + 1 <= lim) ? s1 : NEGBIG_;
        s2 = (jj + 2 <= lim) ? s2 : NEGBIG_;
        s3 = (jj + 3 <= lim) ? s3 : NEGBIG_;
        grp_update(ar, s0, s1, s2, s3,
                   vv + (j0 + 0) * 32, vv + (j0 + 1) * 32,
                   vv + (j0 + 2) * 32, vv + (j0 + 3) * 32, m, ssum);
      }
    }
    __syncthreads();
  }

  if (active) {
    const float lse = m + __logf(ssum);
    const float inv = 1.f / ssum;
    if (causal) {
      float4* op = (float4*)(tail_attn + ((size_t)h * NT_ + p1t) * 64);
#pragma unroll
      for (int d = 0; d < 16; ++d)
        op[d] = make_float4(ar[4*d+0]*inv, ar[4*d+1]*inv, ar[4*d+2]*inv, ar[4*d+3]*inv);
      tail_lse[h * NT_ + p1t] = lse;
    } else {
      float4* op = (float4*)(attn2 + ((size_t)p2vh * 1016 + i) * 64);
#pragma unroll
      for (int d = 0; d < 16; ++d)
        op[d] = make_float4(ar[4*d+0]*inv, ar[4*d+1]*inv, ar[4*d+2]*inv, ar[4*d+3]*inv);
      lse2[p2vh * 1016 + i] = lse;
    }
  }
}

// ---------------- merge P2 into tail ----------------
__global__ __launch_bounds__(128) void kern_merge2(float* __restrict__ tail_attn, float* __restrict__ tail_lse,
                                                   const float* __restrict__ attn2, const float* __restrict__ lse2) {
  const int vh = blockIdx.x;              // 32
  const int i = blockIdx.y * 128 + (int)threadIdx.x;
  if (i >= 1016) return;
  const int h = vh >> 1, pp = vh & 1;
  const int t = pp * 2032 + 1016 + i;
  const float l2 = lse2[vh * 1016 + i];
  float* tlp = tail_lse + h * NT_ + t;
  const float bl = *tlp;
  const float c = 1.f / (1.f + __expf(l2 - bl));   // sigmoid(bl - l2)
  const float4* ap = (const float4*)(attn2 + ((size_t)vh * 1016 + i) * 64);
  float4* tp = (float4*)(tail_attn + ((size_t)h * NT_ + t) * 64);
#pragma unroll
  for (int d = 0; d < 16; ++d) {
    const float4 bd = tp[d], a2 = ap[d];
    tp[d] = make_float4(c * bd.x + (1.f - c) * a2.x,
                        c * bd.y + (1.f - c) * a2.y,
                        c * bd.z + (1.f - c) * a2.z,
                        c * bd.w + (1.f - c) * a2.w);
  }
  *tlp = logaddexpf_(bl, l2);
}

// ---------------- LSH: block-diagonal (256 sorted keys) + sampled residual (256 keys,
// scores offset by log(2032/256), same-block masked) in ONE online pass, merged into tail ----------------
__global__ __launch_bounds__(128) void kern_lsh(const float* __restrict__ Q, const float* __restrict__ K,
                                                const float* __restrict__ V,
                                                const int* __restrict__ q_sort, const int* __restrict__ k_sort,
                                                const int* __restrict__ samp_pos, const int* __restrict__ samp_orig,
                                                float* __restrict__ tail_attn, float* __restrict__ tail_lse) {
  const int h = blockIdx.x, pt = blockIdx.y;  // 16 x 16
  const int tid = threadIdx.x;
  const int p = pt * 128 + tid;
  const bool active = (p < NL_);
  const int blkq = pt >> 1;                   // uniform across block

  __shared__ uint kk[64 * 32];
  __shared__ uint vv[64 * 32];
  __shared__ int sblk[64];

  float qr[64], ar[64];
#pragma unroll
  for (int d = 0; d < 64; ++d) ar[d] = 0.f;
  int qi = 0;
  if (active) {
    qi = q_sort[h * NL_ + p];
    const float4* qp = (const float4*)(Q + ((size_t)h * N_ + (SINK_ + NL_ + qi)) * 64);
#pragma unroll
    for (int d = 0; d < 16; ++d) {
      float4 g = qp[d];
      qr[4*d+0] = g.x * SCALE_; qr[4*d+1] = g.y * SCALE_;
      qr[4*d+2] = g.z * SCALE_; qr[4*d+3] = g.w * SCALE_;
    }
  } else {
#pragma unroll
    for (int d = 0; d < 64; ++d) qr[d] = 0.f;
  }
  float m = -INFINITY, ssum = 0.f;

  for (int t4 = 0; t4 < 8; ++t4) {
    const bool sampled = (t4 >= 4);
    // stage
    for (int u = tid; u < 1024; u += 128) {
      const int r = u >> 4, d4 = u & 15;
      int ko;
      if (!sampled) {
        const int slot = blkq * 256 + t4 * 64 + r;
        ko = (slot < NL_) ? k_sort[h * NL_ + slot] : -1;
      } else {
        ko = samp_orig[h * SAMP_ + (t4 - 4) * 64 + r];
      }
      uint2 pk, pv;
      if (ko >= 0) {
        const float4 gk = ((const float4*)(K + ((size_t)h * N_ + (SINK_ + ko)) * 64))[d4];
        const float4 gv = ((const float4*)(V + ((size_t)h * N_ + (SINK_ + ko)) * 64))[d4];
        pk = make_uint2(bfpack(gk.x, gk.y), bfpack(gk.z, gk.w));
        pv = make_uint2(bfpack(gv.x, gv.y), bfpack(gv.z, gv.w));
      } else { pk = make_uint2(0u, 0u); pv = make_uint2(0u, 0u); }  // pad key: score 0
      ((uint2*)kk)[u] = pk;
      ((uint2*)vv)[u] = pv;
    }
    if (sampled && tid < 64) sblk[tid] = samp_pos[h * SAMP_ + (t4 - 4) * 64 + tid] >> 8;
    __syncthreads();
    if (active) {
      for (int j0 = 0; j0 < 64; j0 += 4) {
        const uint* k0 = kk + (j0 + 0) * 32; const uint* k1 = kk + (j0 + 1) * 32;
        const uint* k2 = kk + (j0 + 2) * 32; const uint* k3 = kk + (j0 + 3) * 32;
        float s0 = dot64bf(qr, k0), s1 = dot64bf(qr, k1);
        float s2 = dot64bf(qr, k2), s3 = dot64bf(qr, k3);
        if (sampled) {
          s0 = (sblk[j0 + 0] != blkq) ? (s0 + LOGOFF_) : NEGBIG_;
          s1 = (sblk[j0 + 1] != blkq) ? (s1 + LOGOFF_) : NEGBIG_;
          s2 = (sblk[j0 + 2] != blkq) ? (s2 + LOGOFF_) : NEGBIG_;
          s3 = (sblk[j0 + 3] != blkq) ? (s3 + LOGOFF_) : NEGBIG_;
        }
        grp_update(ar, s0, s1, s2, s3,
                   vv + (j0 + 0) * 32, vv + (j0 + 1) * 32,
                   vv + (j0 + 2) * 32, vv + (j0 + 3) * 32, m, ssum);
      }
    }
    __syncthreads();
  }

  if (active) {
    const float un_lse = m + __logf(ssum);
    const float inv = 1.f / ssum;
    const int t = NL_ + qi;                  // unsort scatter
    float* tlp = tail_lse + h * NT_ + t;
    const float bd = *tlp;
    const float c2 = 1.f / (1.f + __expf(un_lse - bd));
    float4* tp = (float4*)(tail_attn + ((size_t)h * NT_ + t) * 64);
#pragma unroll
    for (int d = 0; d < 16; ++d) {
      const float4 tv = tp[d];
      tp[d] = make_float4(c2 * tv.x + (1.f - c2) * ar[4*d+0] * inv,
                          c2 * tv.y + (1.f - c2) * ar[4*d+1] * inv,
                          c2 * tv.z + (1.f - c2) * ar[4*d+2] * inv,
                          c2 * tv.w + (1.f - c2) * ar[4*d+3] * inv);
    }
    *tlp = logaddexpf_(bd, un_lse);
  }
}

// ---------------- sink prefix + final merge ----------------
__global__ __launch_bounds__(256) void kern_final(const float* __restrict__ Q, const float* __restrict__ K,
                                                  const float* __restrict__ V,
                                                  const float* __restrict__ tail_attn, const float* __restrict__ tail_lse,
                                                  float* __restrict__ out) {
  const int h = blockIdx.x;
  const int r = blockIdx.y * 256 + (int)threadIdx.x;

  __shared__ float4 kk[SINK_ * 16];
  __shared__ float4 vv[SINK_ * 16];
  for (int u = threadIdx.x; u < SINK_ * 16; u += 256) {
    const int row = u >> 4, d4 = u & 15;
    kk[u] = ((const float4*)(K + ((size_t)h * N_ + row) * 64))[d4];
    vv[u] = ((const float4*)(V + ((size_t)h * N_ + row) * 64))[d4];
  }
  __syncthreads();

  float4 q4[16], acc[16];
  const float4* qp = (const float4*)(Q + ((size_t)h * N_ + r) * 64);
#pragma unroll
  for (int d = 0; d < 16; ++d) { q4[d] = qp[d]; acc[d] = make_float4(0.f, 0.f, 0.f, 0.f); }

  float m = -INFINITY, ssum = 0.f;
  const int nk = min(SINK_, r + 1);
  for (int j = 0; j < nk; ++j) {
    float s = 0.f;
#pragma unroll
    for (int d = 0; d < 16; ++d) {
      float4 x = q4[d], y = kk[j * 16 + d];
      s = fmaf(x.x, y.x, s); s = fmaf(x.y, y.y, s);
      s = fmaf(x.z, y.z, s); s = fmaf(x.w, y.w, s);
    }
    s *= SCALE_;
    const float nm = fmaxf(m, s);
    const float f = __expf(m - nm), w = __expf(s - nm);
    ssum = ssum * f + w;
    const float4* v4 = &vv[j * 16];
#pragma unroll
    for (int d = 0; d < 16; ++d) {
      acc[d].x = acc[d].x * f + w * v4[d].x;
      acc[d].y = acc[d].y * f + w * v4[d].y;
      acc[d].z = acc[d].z * f + w * v4[d].z;
      acc[d].w = acc[d].w * f + w * v4[d].w;
    }
    m = nm;
  }
  const float pl = m + __logf(ssum);
  const float inv = 1.f / ssum;
  float4* op = (float4*)(out + ((size_t)h * N_ + r) * 64);
  if (r < SINK_) {
#pragma unroll
    for (int d = 0; d < 16; ++d)
      op[d] = make_float4(acc[d].x * inv, acc[d].y * inv, acc[d].z * inv, acc[d].w * inv);
  } else {
    const int t = r - SINK_;
    const float tl = tail_lse[h * NT_ + t];
    const float cc = 1.f / (1.f + __expf(tl - pl));
    const float4* tp = (const float4*)(tail_attn + ((size_t)h * NT_ + t) * 64);
#pragma unroll
    for (int d = 0; d < 16; ++d) {
      const float4 tv = tp[d];
      op[d] = make_float4(cc * acc[d].x * inv + (1.f - cc) * tv.x,
                          cc * acc[d].y * inv + (1.f - cc) * tv.y,
                          cc * acc[d].z * inv + (1.f - cc) * tv.z,
                          cc * acc[d].w * inv + (1.f - cc) * tv.w);
    }
  }
}

// ---------------- host ----------------
extern "C" void kernel_launch(void* const* d_in, const int* in_sizes, int n_in,
                              void* d_out, int out_size, void* d_ws, size_t ws_size,
                              hipStream_t stream) {
  (void)in_sizes; (void)n_in; (void)out_size; (void)ws_size;
  const float* Q = (const float*)d_in[0];
  const float* K = (const float*)d_in[1];
  const float* V = (const float*)d_in[2];
  const float* proj = (const float*)d_in[3];
  float* out = (float*)d_out;

  char* w = (char*)d_ws;
  auto carve = [&](size_t bytes) { char* p = w; w += (bytes + 255) & ~(size_t)255; return p; };
  float* tail_attn = (float*)carve((size_t)H_ * NT_ * 64 * sizeof(float));
  float* tail_lse  = (float*)carve((size_t)H_ * NT_ * sizeof(float));
  float* attn2     = (float*)carve((size_t)32 * 1016 * 64 * sizeof(float));
  float* lse2      = (float*)carve((size_t)32 * 1016 * sizeof(float));
  int* hq        = (int*)carve((size_t)H_ * NL_ * sizeof(int));
  int* hk        = (int*)carve((size_t)H_ * NL_ * sizeof(int));
  int* q_sort    = (int*)carve((size_t)H_ * NL_ * sizeof(int));
  int* k_sort    = (int*)carve((size_t)H_ * NL_ * sizeof(int));
  int* samp_pos  = (int*)carve((size_t)H_ * SAMP_ * sizeof(int));
  int* samp_orig = (int*)carve((size_t)H_ * SAMP_ * sizeof(int));

  kern_hash<<<dim3(H_, 8, 2), 256, 0, stream>>>(Q, K, proj, hq, hk);
  kern_sort<<<dim3(H_, 2), 128, 0, stream>>>(hq, hk, q_sort, k_sort);
  kern_sample<<<dim3(H_), SAMP_, 0, stream>>>(k_sort, samp_pos, samp_orig);
  kern_attn<<<dim3(768), 128, 0, stream>>>(Q, K, V, tail_attn, tail_lse, attn2, lse2);
  kern_merge2<<<dim3(32, 8), 128, 0, stream>>>(tail_attn, tail_lse, attn2, lse2);
  kern_lsh<<<dim3(H_, 16), 128, 0, stream>>>(Q, K, V, q_sort, k_sort, samp_pos, samp_orig,
                                             tail_attn, tail_lse);
  kern_final<<<dim3(H_, 16), 256, 0, stream>>>(Q, K, V, tail_attn, tail_lse, out);
}

// Round 3
// 300.606 us; speedup vs baseline: 10.3933x; 4.9464x over previous
//
#include <hip/hip_runtime.h>
#include <hip/hip_bf16.h>
#include <math.h>
#include <stdint.h>

#define H_ 16
#define N_ 4096
#define NT_ 4064        // tail length
#define NL_ 2032        // LSH segment length
#define SINK_ 32
#define SAMP_ 256
#define SCALE_ 0.125f
#define NEGBIG_ -3.0e38f
#define LOGOFF_ 2.0719334f   // log(2032/256)

typedef unsigned int uint;
typedef short bf16x8 __attribute__((ext_vector_type(8)));   // 8 bf16 in 4 VGPRs
typedef float f32x4 __attribute__((ext_vector_type(4)));

union B8 { uint4 u; bf16x8 b; };

__device__ __forceinline__ f32x4 mfma16(const B8& a, const B8& b, f32x4 c) {
  return __builtin_amdgcn_mfma_f32_16x16x32_bf16(a.b, b.b, c, 0, 0, 0);
}

// ---------------- bf16 pack (RNE) ----------------
__device__ __forceinline__ uint bfpack(float a, float b) {
  uint ua = __float_as_uint(a), ub = __float_as_uint(b);
  ua += 0x7fffu + ((ua >> 16) & 1u);
  ub += 0x7fffu + ((ub >> 16) & 1u);
  return (ua >> 16) | (ub & 0xffff0000u);
}

__device__ __forceinline__ float logaddexpf_(float a, float b) {
  float mx = fmaxf(a, b);
  return mx + __logf(__expf(a - mx) + __expf(b - mx));
}

__device__ __forceinline__ uint32_t rotl32_(uint32_t v, uint32_t d) {
  return (v << d) | (v >> (32u - d));
}

// JAX threefry2x32 (20 rounds)
__device__ inline void tf2x32(uint32_t k0, uint32_t k1, uint32_t& x0, uint32_t& x1) {
  uint32_t ks2 = k0 ^ k1 ^ 0x1BD11BDAu;
  x0 += k0; x1 += k1;
#define TFR(r) { x0 += x1; x1 = rotl32_(x1, r); x1 ^= x0; }
  TFR(13u) TFR(15u) TFR(26u) TFR(6u)
  x0 += k1;  x1 += ks2 + 1u;
  TFR(17u) TFR(29u) TFR(16u) TFR(24u)
  x0 += ks2; x1 += k0 + 2u;
  TFR(13u) TFR(15u) TFR(26u) TFR(6u)
  x0 += k0;  x1 += k1 + 3u;
  TFR(17u) TFR(29u) TFR(16u) TFR(24u)
  x0 += k1;  x1 += ks2 + 4u;
  TFR(13u) TFR(15u) TFR(26u) TFR(6u)
  x0 += ks2; x1 += k0 + 5u;
#undef TFR
}

// ---------------- hashing ----------------
__global__ __launch_bounds__(256) void kern_hash(const float* __restrict__ Q, const float* __restrict__ K,
                                                 const float* __restrict__ proj,
                                                 int* __restrict__ hq, int* __restrict__ hk) {
  const int h = blockIdx.x, tile = blockIdx.y, which = blockIdx.z;
  __shared__ float pr[64 * 7];
  for (int u = threadIdx.x; u < 64 * 7; u += 256) pr[u] = proj[u];
  __syncthreads();
  const int i = tile * 256 + (int)threadIdx.x;
  if (i >= NL_) return;
  const int orig = (which == 0) ? (SINK_ + NL_ + i) : (SINK_ + i);
  const float4* x = (const float4*)((which == 0 ? Q : K) + ((size_t)h * N_ + orig) * 64);
  float xr[64];
#pragma unroll
  for (int d = 0; d < 16; ++d) {
    float4 g = x[d];
    xr[4*d+0] = g.x; xr[4*d+1] = g.y; xr[4*d+2] = g.z; xr[4*d+3] = g.w;
  }
  int bin = 0;
#pragma unroll
  for (int r = 0; r < 7; ++r) {
    float acc = 0.f;
#pragma unroll
    for (int d = 0; d < 64; ++d) acc = fmaf(xr[d], pr[d * 7 + r], acc);
    if (acc > 0.f) bin |= (1 << r);
  }
  const int g = bin ^ (bin >> 1);   // _PERM = Gray code
  (which == 0 ? hq : hk)[h * NL_ + i] = g;
}

// ---------------- stable counting sort ----------------
__global__ __launch_bounds__(128) void kern_sort(const int* __restrict__ hq, const int* __restrict__ hk,
                                                 int* __restrict__ q_sort, int* __restrict__ k_sort) {
  const int h = blockIdx.x;
  const int which = blockIdx.y;
  const int* src = (which == 0 ? hq : hk) + h * NL_;
  __shared__ int lh[NL_];
  __shared__ int cnts[128];
  __shared__ int offs[128];
  for (int u = threadIdx.x; u < NL_; u += 128) lh[u] = src[u];
  __syncthreads();
  const int b = threadIdx.x;
  int c = 0;
  for (int u = 0; u < NL_; ++u) c += (lh[u] == b) ? 1 : 0;
  cnts[b] = c;
  __syncthreads();
  if (b == 0) { int a = 0; for (int u = 0; u < 128; ++u) { offs[u] = a; a += cnts[u]; } }
  __syncthreads();
  int off = offs[b];
  int* dst = (which == 0 ? q_sort : k_sort) + h * NL_;
  for (int u = 0; u < NL_; ++u) {
    if (lh[u] == b) { dst[off] = u; ++off; }
  }
}

// ---------------- threefry sampling ----------------
__global__ void kern_sample(const int* __restrict__ k_sort,
                            int* __restrict__ samp_pos, int* __restrict__ samp_orig) {
  const int h = blockIdx.x;
  const int s = threadIdx.x;
  uint32_t a0 = 0u, a1 = 0u; tf2x32(0u, 1234u, a0, a1);
  uint32_t b0 = 0u, b1 = 0u; tf2x32(a0, a1, b0, b1);
  uint32_t c0 = 0u, c1 = 1u; tf2x32(a0, a1, c0, c1);
  const uint32_t j = (uint32_t)(h * SAMP_ + s);
  uint32_t h0 = 0u, h1 = j; tf2x32(b0, b1, h0, h1);
  uint32_t l0 = 0u, l1 = j; tf2x32(c0, c1, l0, l1);
  const uint32_t Hb = h0 ^ h1, Lb = l0 ^ l1;
  const uint32_t off = ((Hb % 2032u) * 16u + (Lb % 2032u)) % 2032u;
  samp_pos[h * SAMP_ + s] = (int)off;
  samp_orig[h * SAMP_ + s] = k_sort[h * NL_ + (int)off];
}

// =========================================================================
// MFMA flash attention for P1 (causal 1016-chunks) + P2 (off-diagonal).
// Block = 256 thr = 4 waves; wave = 16 q rows; 64-key LDS tiles.
// LDS: kk[64 keys][64 d] bf16, 144B row stride;  vv = V^T [64 d][64 keys]
// bf16, 144B stride;  pb = per-wave P buffer [16 q][32 keys] bf16, 64B rows
// with 16B-granule XOR(q&3) swizzle.
// S^T = mfma(A=K, B=Q^T)  -> lane holds S^T[key=4g+r][q=l&15]
// O^T = mfma(A=V^T, B=P^T)-> lane holds O^T[d=16dt+4g+r][q]
// =========================================================================
__global__ __launch_bounds__(256) void kern_attn_mfma(
    const float* __restrict__ Q, const float* __restrict__ K, const float* __restrict__ V,
    float* __restrict__ tail_attn, float* __restrict__ tail_lse,
    float* __restrict__ attn2, float* __restrict__ lse2) {
  __shared__ uint kk[2304];
  __shared__ uint vv[2304];
  __shared__ uint pbuf[1024];

  const int b = blockIdx.x;
  const int tid = threadIdx.x;
  const int lane = tid & 63, w = tid >> 6;
  const int g = lane >> 4, q = lane & 15;

  int h, q0, qbase, kbase, ntiles, p2vh = 0, chunkc = 0;
  bool causal;
  if (b < 512) {                       // P2: 32 vh x 16 qtiles (heavy, first)
    const int vh = b & 31; const int qt = b >> 5;
    h = vh >> 1; const int pp = vh & 1;
    q0 = qt * 64;
    qbase = SINK_ + pp * 2032 + 1016;
    kbase = SINK_ + pp * 2032;
    ntiles = 16; causal = false; p2vh = vh;
  } else {                             // P1: LPT descending qt
    const int u = b - 512; const int vh = u & 63;
    const int qt = 15 - (u >> 6);
    h = vh >> 2; chunkc = vh & 3;
    q0 = qt * 64;
    qbase = SINK_ + chunkc * 1016;
    kbase = qbase;
    ntiles = qt + 1; causal = true;
  }
  const size_t hN = (size_t)h * N_;
  const int qrow = q0 + w * 16 + q;         // local row, may exceed 1015 (padding)
  const int qrow_c = min(qrow, 1015);

  // Q B-frags: lane holds Q[q][8g+j] (half0) and Q[q][32+8g+j] (half1), scaled
  B8 qb0, qb1;
  {
    const float4* qp = (const float4*)(Q + (hN + qbase + qrow_c) * 64);
    float4 a = qp[2*g], c = qp[2*g+1];
    qb0.u = make_uint4(bfpack(a.x*SCALE_, a.y*SCALE_), bfpack(a.z*SCALE_, a.w*SCALE_),
                       bfpack(c.x*SCALE_, c.y*SCALE_), bfpack(c.z*SCALE_, c.w*SCALE_));
    float4 d = qp[8+2*g], e = qp[8+2*g+1];
    qb1.u = make_uint4(bfpack(d.x*SCALE_, d.y*SCALE_), bfpack(d.z*SCALE_, d.w*SCALE_),
                       bfpack(e.x*SCALE_, e.y*SCALE_), bfpack(e.z*SCALE_, e.w*SCALE_));
  }
  f32x4 o0 = {0.f,0.f,0.f,0.f}, o1 = o0, o2 = o0, o3 = o0;
  float m = -INFINITY, ssum = 0.f;
  const int qwmax = q0 + w * 16 + 15;

  const int skey = tid >> 2, sdb = (tid & 3) * 16;   // K-stage mapping
  const int vkp = tid & 31, vdb = (tid >> 5) * 8;    // V-stage mapping
  const int pwb = w * 1024 + q * 64;                 // P buffer base (bytes)

  for (int t = 0; t < ntiles; ++t) {
    const int kt = t * 64;
    __syncthreads();
    { // ---- stage K [key][d] bf16 ----
      const int kr = kt + skey;
      uint4 p0 = make_uint4(0,0,0,0), p1 = make_uint4(0,0,0,0);
      if (kr < 1016) {
        const float4* kp = (const float4*)(K + (hN + kbase + kr) * 64 + sdb);
        float4 f0 = kp[0], f1 = kp[1], f2 = kp[2], f3 = kp[3];
        p0 = make_uint4(bfpack(f0.x,f0.y), bfpack(f0.z,f0.w), bfpack(f1.x,f1.y), bfpack(f1.z,f1.w));
        p1 = make_uint4(bfpack(f2.x,f2.y), bfpack(f2.z,f2.w), bfpack(f3.x,f3.y), bfpack(f3.z,f3.w));
      }
      *(uint4*)((char*)kk + skey*144 + sdb*2) = p0;
      *(uint4*)((char*)kk + skey*144 + sdb*2 + 16) = p1;
    }
    { // ---- stage V^T [d][key] bf16 ----
      const int kr0 = kt + 2 * vkp;
      float e0[8] = {0,0,0,0,0,0,0,0}, e1[8] = {0,0,0,0,0,0,0,0};
      if (kr0 < 1016) {     // kr0 even, 1016 even -> pair never straddles
        const float4* v0p = (const float4*)(V + (hN + kbase + kr0) * 64 + vdb);
        const float4* v1p = (const float4*)(V + (hN + kbase + kr0 + 1) * 64 + vdb);
        float4 a0 = v0p[0], a1 = v0p[1], b0 = v1p[0], b1 = v1p[1];
        e0[0]=a0.x; e0[1]=a0.y; e0[2]=a0.z; e0[3]=a0.w; e0[4]=a1.x; e0[5]=a1.y; e0[6]=a1.z; e0[7]=a1.w;
        e1[0]=b0.x; e1[1]=b0.y; e1[2]=b0.z; e1[3]=b0.w; e1[4]=b1.x; e1[5]=b1.y; e1[6]=b1.z; e1[7]=b1.w;
      }
#pragma unroll
      for (int jd = 0; jd < 8; ++jd)
        *(uint*)((char*)vv + (vdb + jd)*144 + 4*vkp) = bfpack(e0[jd], e1[jd]);
    }
    __syncthreads();
    if (causal && kt > qwmax) continue;   // fully-masked tile for this wave

    // ---- QK: 4 subtiles of 16 keys ----
    f32x4 s0, s1, s2, s3;
    {
      B8 ka, kb2;
#define QKST(SREG, ST) { \
      ka.u  = *(const uint4*)((char*)kk + ((ST)*16 + q)*144 + g*16); \
      kb2.u = *(const uint4*)((char*)kk + ((ST)*16 + q)*144 + 64 + g*16); \
      f32x4 acc_ = {0.f,0.f,0.f,0.f}; \
      acc_ = mfma16(ka, qb0, acc_); \
      acc_ = mfma16(kb2, qb1, acc_); \
      SREG = acc_; }
      QKST(s0, 0) QKST(s1, 1) QKST(s2, 2) QKST(s3, 3)
#undef QKST
    }

    // ---- masks ----
    if (causal) {
      if (kt + 63 >= q0 + w * 16) {
        const int kb0 = kt + 4 * g;
#pragma unroll
        for (int r = 0; r < 4; ++r) {
          if (kb0 + r      > qrow) s0[r] = NEGBIG_;
          if (kb0 + 16 + r > qrow) s1[r] = NEGBIG_;
          if (kb0 + 32 + r > qrow) s2[r] = NEGBIG_;
          if (kb0 + 48 + r > qrow) s3[r] = NEGBIG_;
        }
      }
    } else if (kt + 63 >= 1016) {
      const int kb0 = kt + 4 * g;
#pragma unroll
      for (int r = 0; r < 4; ++r) {
        if (kb0 + r      >= 1016) s0[r] = NEGBIG_;
        if (kb0 + 16 + r >= 1016) s1[r] = NEGBIG_;
        if (kb0 + 32 + r >= 1016) s2[r] = NEGBIG_;
        if (kb0 + 48 + r >= 1016) s3[r] = NEGBIG_;
      }
    }

    // ---- online softmax over 64 keys ----
    float mx = fmaxf(fmaxf(s0[0], s0[1]), fmaxf(s0[2], s0[3]));
    mx = fmaxf(mx, fmaxf(fmaxf(s1[0], s1[1]), fmaxf(s1[2], s1[3])));
    mx = fmaxf(mx, fmaxf(fmaxf(s2[0], s2[1]), fmaxf(s2[2], s2[3])));
    mx = fmaxf(mx, fmaxf(fmaxf(s3[0], s3[1]), fmaxf(s3[2], s3[3])));
    mx = fmaxf(mx, __shfl_xor(mx, 16));
    mx = fmaxf(mx, __shfl_xor(mx, 32));
    const float nm = fmaxf(m, mx);
    const float fold = __expf(m - nm);
    float ts = 0.f;
#pragma unroll
    for (int r = 0; r < 4; ++r) {
      s0[r] = __expf(s0[r] - nm); ts += s0[r];
      s1[r] = __expf(s1[r] - nm); ts += s1[r];
      s2[r] = __expf(s2[r] - nm); ts += s2[r];
      s3[r] = __expf(s3[r] - nm); ts += s3[r];
    }
    ts += __shfl_xor(ts, 16);
    ts += __shfl_xor(ts, 32);
    ssum = ssum * fold + ts;
    o0 = o0 * fold; o1 = o1 * fold; o2 = o2 * fold; o3 = o3 * fold;
    m = nm;

    // ---- PV per 32-key half via P round-trip in per-wave LDS ----
#pragma unroll
    for (int hk = 0; hk < 2; ++hk) {
      f32x4 pa = (hk == 0) ? s0 : s2;
      f32x4 pc = (hk == 0) ? s1 : s3;
      uint2 w0 = make_uint2(bfpack(pa[0], pa[1]), bfpack(pa[2], pa[3]));
      uint2 w1 = make_uint2(bfpack(pc[0], pc[1]), bfpack(pc[2], pc[3]));
      *(uint2*)((char*)pbuf + pwb + ((((g>>1)    ) ^ (q&3))*16) + (g&1)*8) = w0;  // stl=0
      *(uint2*)((char*)pbuf + pwb + (((2 + (g>>1)) ^ (q&3))*16) + (g&1)*8) = w1;  // stl=1
      B8 pf, vf;
      pf.u = *(const uint4*)((char*)pbuf + pwb + ((g ^ (q&3))*16));
      vf.u = *(const uint4*)((char*)vv + (0*16 + q)*144 + hk*64 + g*16); o0 = mfma16(vf, pf, o0);
      vf.u = *(const uint4*)((char*)vv + (1*16 + q)*144 + hk*64 + g*16); o1 = mfma16(vf, pf, o1);
      vf.u = *(const uint4*)((char*)vv + (2*16 + q)*144 + hk*64 + g*16); o2 = mfma16(vf, pf, o2);
      vf.u = *(const uint4*)((char*)vv + (3*16 + q)*144 + hk*64 + g*16); o3 = mfma16(vf, pf, o3);
    }
  }

  // ---- epilogue ----
  if (qrow < 1016) {
    const float lse = m + __logf(ssum);
    const float inv = 1.f / ssum;
    f32x4 r0 = o0 * inv, r1 = o1 * inv, r2 = o2 * inv, r3 = o3 * inv;
    if (causal) {
      const int trow = chunkc * 1016 + qrow;
      float* tp = tail_attn + ((size_t)h * NT_ + trow) * 64;
      *(f32x4*)(tp +  0 + 4*g) = r0;
      *(f32x4*)(tp + 16 + 4*g) = r1;
      *(f32x4*)(tp + 32 + 4*g) = r2;
      *(f32x4*)(tp + 48 + 4*g) = r3;
      if (lane < 16) tail_lse[h * NT_ + trow] = lse;
    } else {
      float* tp = attn2 + ((size_t)p2vh * 1016 + qrow) * 64;
      *(f32x4*)(tp +  0 + 4*g) = r0;
      *(f32x4*)(tp + 16 + 4*g) = r1;
      *(f32x4*)(tp + 32 + 4*g) = r2;
      *(f32x4*)(tp + 48 + 4*g) = r3;
      if (lane < 16) lse2[p2vh * 1016 + qrow] = lse;
    }
  }
}

// ---------------- merge P2 into tail ----------------
__global__ __launch_bounds__(128) void kern_merge2(float* __restrict__ tail_attn, float* __restrict__ tail_lse,
                                                   const float* __restrict__ attn2, const float* __restrict__ lse2) {
  const int vh = blockIdx.x;
  const int i = blockIdx.y * 128 + (int)threadIdx.x;
  if (i >= 1016) return;
  const int h = vh >> 1, pp = vh & 1;
  const int t = pp * 2032 + 1016 + i;
  const float l2 = lse2[vh * 1016 + i];
  float* tlp = tail_lse + h * NT_ + t;
  const float bl = *tlp;
  const float c = 1.f / (1.f + __expf(l2 - bl));
  const float4* ap = (const float4*)(attn2 + ((size_t)vh * 1016 + i) * 64);
  float4* tp = (float4*)(tail_attn + ((size_t)h * NT_ + t) * 64);
#pragma unroll
  for (int d = 0; d < 16; ++d) {
    const float4 bd = tp[d], a2 = ap[d];
    tp[d] = make_float4(c * bd.x + (1.f - c) * a2.x,
                        c * bd.y + (1.f - c) * a2.y,
                        c * bd.z + (1.f - c) * a2.z,
                        c * bd.w + (1.f - c) * a2.w);
  }
  *tlp = logaddexpf_(bl, l2);
}

// =========================================================================
// MFMA LSH: per block 64 sorted-q rows; 8 key-tiles (4 block-diag sorted,
// 4 sampled w/ bias). Fused online softmax, merged into tail.
// =========================================================================
__global__ __launch_bounds__(256) void kern_lsh_mfma(
    const float* __restrict__ Q, const float* __restrict__ K, const float* __restrict__ V,
    const int* __restrict__ q_sort, const int* __restrict__ k_sort,
    const int* __restrict__ samp_pos, const int* __restrict__ samp_orig,
    float* __restrict__ tail_attn, float* __restrict__ tail_lse) {
  __shared__ uint kk[2304];
  __shared__ uint vv[2304];
  __shared__ uint pbuf[1024];
  __shared__ float bias_s[64];

  const int b = blockIdx.x;
  const int h = b >> 5, pt = b & 31;
  const int tid = threadIdx.x;
  const int lane = tid & 63, w = tid >> 6;
  const int g = lane >> 4, q = lane & 15;
  const int blkq = pt >> 2;
  const size_t hN = (size_t)h * N_;

  const int p = pt * 64 + w * 16 + q;
  const int pc = min(p, NL_ - 1);
  const int qi = q_sort[h * NL_ + pc];

  B8 qb0, qb1;
  {
    const float4* qp = (const float4*)(Q + (hN + SINK_ + NL_ + qi) * 64);
    float4 a = qp[2*g], c = qp[2*g+1];
    qb0.u = make_uint4(bfpack(a.x*SCALE_, a.y*SCALE_), bfpack(a.z*SCALE_, a.w*SCALE_),
                       bfpack(c.x*SCALE_, c.y*SCALE_), bfpack(c.z*SCALE_, c.w*SCALE_));
    float4 d = qp[8+2*g], e = qp[8+2*g+1];
    qb1.u = make_uint4(bfpack(d.x*SCALE_, d.y*SCALE_), bfpack(d.z*SCALE_, d.w*SCALE_),
                       bfpack(e.x*SCALE_, e.y*SCALE_), bfpack(e.z*SCALE_, e.w*SCALE_));
  }
  f32x4 o0 = {0.f,0.f,0.f,0.f}, o1 = o0, o2 = o0, o3 = o0;
  float m = -INFINITY, ssum = 0.f;

  const int skey = tid >> 2, sdb = (tid & 3) * 16;
  const int vkp = tid & 31, vdb = (tid >> 5) * 8;
  const int pwb = w * 1024 + q * 64;

  for (int t = 0; t < 8; ++t) {
    __syncthreads();
    { // ---- stage K (gathered) ----
      int krow = -1;
      if (t < 4) {
        const int slot = blkq * 256 + t * 64 + skey;
        if (slot < NL_) krow = k_sort[h * NL_ + slot];
      } else {
        krow = samp_orig[h * SAMP_ + (t - 4) * 64 + skey];
      }
      uint4 p0 = make_uint4(0,0,0,0), p1 = make_uint4(0,0,0,0);
      if (krow >= 0) {
        const float4* kp = (const float4*)(K + (hN + SINK_ + krow) * 64 + sdb);
        float4 f0 = kp[0], f1 = kp[1], f2 = kp[2], f3 = kp[3];
        p0 = make_uint4(bfpack(f0.x,f0.y), bfpack(f0.z,f0.w), bfpack(f1.x,f1.y), bfpack(f1.z,f1.w));
        p1 = make_uint4(bfpack(f2.x,f2.y), bfpack(f2.z,f2.w), bfpack(f3.x,f3.y), bfpack(f3.z,f3.w));
      }
      *(uint4*)((char*)kk + skey*144 + sdb*2) = p0;
      *(uint4*)((char*)kk + skey*144 + sdb*2 + 16) = p1;
    }
    { // ---- stage V^T (gathered) ----
      int kr0 = -1, kr1 = -1;
      if (t < 4) {
        const int slot0 = blkq * 256 + t * 64 + 2 * vkp;
        if (slot0 < NL_)     kr0 = k_sort[h * NL_ + slot0];
        if (slot0 + 1 < NL_) kr1 = k_sort[h * NL_ + slot0 + 1];
      } else {
        const int si = (t - 4) * 64 + 2 * vkp;
        kr0 = samp_orig[h * SAMP_ + si];
        kr1 = samp_orig[h * SAMP_ + si + 1];
      }
      float e0[8] = {0,0,0,0,0,0,0,0}, e1[8] = {0,0,0,0,0,0,0,0};
      if (kr0 >= 0) {
        const float4* v0p = (const float4*)(V + (hN + SINK_ + kr0) * 64 + vdb);
        float4 a0 = v0p[0], a1 = v0p[1];
        e0[0]=a0.x; e0[1]=a0.y; e0[2]=a0.z; e0[3]=a0.w; e0[4]=a1.x; e0[5]=a1.y; e0[6]=a1.z; e0[7]=a1.w;
      }
      if (kr1 >= 0) {
        const float4* v1p = (const float4*)(V + (hN + SINK_ + kr1) * 64 + vdb);
        float4 b0 = v1p[0], b1 = v1p[1];
        e1[0]=b0.x; e1[1]=b0.y; e1[2]=b0.z; e1[3]=b0.w; e1[4]=b1.x; e1[5]=b1.y; e1[6]=b1.z; e1[7]=b1.w;
      }
#pragma unroll
      for (int jd = 0; jd < 8; ++jd)
        *(uint*)((char*)vv + (vdb + jd)*144 + 4*vkp) = bfpack(e0[jd], e1[jd]);
    }
    if (t >= 4 && tid < 64)
      bias_s[tid] = ((samp_pos[h * SAMP_ + (t - 4) * 64 + tid] >> 8) == blkq) ? NEGBIG_ : LOGOFF_;
    __syncthreads();

    // ---- QK ----
    f32x4 s0, s1, s2, s3;
    {
      B8 ka, kb2;
#define QKST(SREG, ST) { \
      ka.u  = *(const uint4*)((char*)kk + ((ST)*16 + q)*144 + g*16); \
      kb2.u = *(const uint4*)((char*)kk + ((ST)*16 + q)*144 + 64 + g*16); \
      f32x4 acc_ = {0.f,0.f,0.f,0.f}; \
      acc_ = mfma16(ka, qb0, acc_); \
      acc_ = mfma16(kb2, qb1, acc_); \
      SREG = acc_; }
      QKST(s0, 0) QKST(s1, 1) QKST(s2, 2) QKST(s3, 3)
#undef QKST
    }
    if (t >= 4) {   // sampled tiles: +log(2032/256) or -inf (same-block)
      const f32x4* bp = (const f32x4*)bias_s;
      s0 = s0 + bp[0*4 + g];
      s1 = s1 + bp[1*4 + g];
      s2 = s2 + bp[2*4 + g];
      s3 = s3 + bp[3*4 + g];
    }

    // ---- online softmax ----
    float mx = fmaxf(fmaxf(s0[0], s0[1]), fmaxf(s0[2], s0[3]));
    mx = fmaxf(mx, fmaxf(fmaxf(s1[0], s1[1]), fmaxf(s1[2], s1[3])));
    mx = fmaxf(mx, fmaxf(fmaxf(s2[0], s2[1]), fmaxf(s2[2], s2[3])));
    mx = fmaxf(mx, fmaxf(fmaxf(s3[0], s3[1]), fmaxf(s3[2], s3[3])));
    mx = fmaxf(mx, __shfl_xor(mx, 16));
    mx = fmaxf(mx, __shfl_xor(mx, 32));
    const float nm = fmaxf(m, mx);
    const float fold = __expf(m - nm);
    float ts = 0.f;
#pragma unroll
    for (int r = 0; r < 4; ++r) {
      s0[r] = __expf(s0[r] - nm); ts += s0[r];
      s1[r] = __expf(s1[r] - nm); ts += s1[r];
      s2[r] = __expf(s2[r] - nm); ts += s2[r];
      s3[r] = __expf(s3[r] - nm); ts += s3[r];
    }
    ts += __shfl_xor(ts, 16);
    ts += __shfl_xor(ts, 32);
    ssum = ssum * fold + ts;
    o0 = o0 * fold; o1 = o1 * fold; o2 = o2 * fold; o3 = o3 * fold;
    m = nm;

    // ---- PV ----
#pragma unroll
    for (int hk = 0; hk < 2; ++hk) {
      f32x4 pa = (hk == 0) ? s0 : s2;
      f32x4 pc = (hk == 0) ? s1 : s3;
      uint2 w0 = make_uint2(bfpack(pa[0], pa[1]), bfpack(pa[2], pa[3]));
      uint2 w1 = make_uint2(bfpack(pc[0], pc[1]), bfpack(pc[2], pc[3]));
      *(uint2*)((char*)pbuf + pwb + ((((g>>1)    ) ^ (q&3))*16) + (g&1)*8) = w0;
      *(uint2*)((char*)pbuf + pwb + (((2 + (g>>1)) ^ (q&3))*16) + (g&1)*8) = w1;
      B8 pf, vf;
      pf.u = *(const uint4*)((char*)pbuf + pwb + ((g ^ (q&3))*16));
      vf.u = *(const uint4*)((char*)vv + (0*16 + q)*144 + hk*64 + g*16); o0 = mfma16(vf, pf, o0);
      vf.u = *(const uint4*)((char*)vv + (1*16 + q)*144 + hk*64 + g*16); o1 = mfma16(vf, pf, o1);
      vf.u = *(const uint4*)((char*)vv + (2*16 + q)*144 + hk*64 + g*16); o2 = mfma16(vf, pf, o2);
      vf.u = *(const uint4*)((char*)vv + (3*16 + q)*144 + hk*64 + g*16); o3 = mfma16(vf, pf, o3);
    }
  }

  // ---- merge into tail (unsort scatter) ----
  if (p < NL_) {
    const float un = m + __logf(ssum);
    const float inv = 1.f / ssum;
    const int trow = NL_ + qi;
    float* tlp = tail_lse + h * NT_ + trow;
    const float bd = *tlp;
    const float c2 = 1.f / (1.f + __expf(un - bd));
    const float w2 = inv * (1.f - c2);
    float* tp = tail_attn + ((size_t)h * NT_ + trow) * 64;
    f32x4 t0 = *(f32x4*)(tp +  0 + 4*g);
    f32x4 t1 = *(f32x4*)(tp + 16 + 4*g);
    f32x4 t2 = *(f32x4*)(tp + 32 + 4*g);
    f32x4 t3 = *(f32x4*)(tp + 48 + 4*g);
    *(f32x4*)(tp +  0 + 4*g) = t0 * c2 + o0 * w2;
    *(f32x4*)(tp + 16 + 4*g) = t1 * c2 + o1 * w2;
    *(f32x4*)(tp + 32 + 4*g) = t2 * c2 + o2 * w2;
    *(f32x4*)(tp + 48 + 4*g) = t3 * c2 + o3 * w2;
    if (lane < 16) *tlp = logaddexpf_(bd, un);
  }
}

// ---------------- sink prefix + final merge ----------------
__global__ __launch_bounds__(256) void kern_final(const float* __restrict__ Q, const float* __restrict__ K,
                                                  const float* __restrict__ V,
                                                  const float* __restrict__ tail_attn, const float* __restrict__ tail_lse,
                                                  float* __restrict__ out) {
  const int h = blockIdx.x;
  const int r = blockIdx.y * 256 + (int)threadIdx.x;

  __shared__ float4 kk[SINK_ * 16];
  __shared__ float4 vv[SINK_ * 16];
  for (int u = threadIdx.x; u < SINK_ * 16; u += 256) {
    const int row = u >> 4, d4 = u & 15;
    kk[u] = ((const float4*)(K + ((size_t)h * N_ + row) * 64))[d4];
    vv[u] = ((const float4*)(V + ((size_t)h * N_ + row) * 64))[d4];
  }
  __syncthreads();

  float4 q4[16], acc[16];
  const float4* qp = (const float4*)(Q + ((size_t)h * N_ + r) * 64);
#pragma unroll
  for (int d = 0; d < 16; ++d) { q4[d] = qp[d]; acc[d] = make_float4(0.f, 0.f, 0.f, 0.f); }

  float m = -INFINITY, ssum = 0.f;
  const int nk = min(SINK_, r + 1);
  for (int j = 0; j < nk; ++j) {
    float s = 0.f;
#pragma unroll
    for (int d = 0; d < 16; ++d) {
      float4 x = q4[d], y = kk[j * 16 + d];
      s = fmaf(x.x, y.x, s); s = fmaf(x.y, y.y, s);
      s = fmaf(x.z, y.z, s); s = fmaf(x.w, y.w, s);
    }
    s *= SCALE_;
    const float nm = fmaxf(m, s);
    const float f = __expf(m - nm), w = __expf(s - nm);
    ssum = ssum * f + w;
    const float4* v4 = &vv[j * 16];
#pragma unroll
    for (int d = 0; d < 16; ++d) {
      acc[d].x = acc[d].x * f + w * v4[d].x;
      acc[d].y = acc[d].y * f + w * v4[d].y;
      acc[d].z = acc[d].z * f + w * v4[d].z;
      acc[d].w = acc[d].w * f + w * v4[d].w;
    }
    m = nm;
  }
  const float pl = m + __logf(ssum);
  const float inv = 1.f / ssum;
  float4* op = (float4*)(out + ((size_t)h * N_ + r) * 64);
  if (r < SINK_) {
#pragma unroll
    for (int d = 0; d < 16; ++d)
      op[d] = make_float4(acc[d].x * inv, acc[d].y * inv, acc[d].z * inv, acc[d].w * inv);
  } else {
    const int t = r - SINK_;
    const float tl = tail_lse[h * NT_ + t];
    const float cc = 1.f / (1.f + __expf(tl - pl));
    const float4* tp = (const float4*)(tail_attn + ((size_t)h * NT_ + t) * 64);
#pragma unroll
    for (int d = 0; d < 16; ++d) {
      const float4 tv = tp[d];
      op[d] = make_float4(cc * acc[d].x * inv + (1.f - cc) * tv.x,
                          cc * acc[d].y * inv + (1.f - cc) * tv.y,
                          cc * acc[d].z * inv + (1.f - cc) * tv.z,
                          cc * acc[d].w * inv + (1.f - cc) * tv.w);
    }
  }
}

// ---------------- host ----------------
extern "C" void kernel_launch(void* const* d_in, const int* in_sizes, int n_in,
                              void* d_out, int out_size, void* d_ws, size_t ws_size,
                              hipStream_t stream) {
  (void)in_sizes; (void)n_in; (void)out_size; (void)ws_size;
  const float* Q = (const float*)d_in[0];
  const float* K = (const float*)d_in[1];
  const float* V = (const float*)d_in[2];
  const float* proj = (const float*)d_in[3];
  float* out = (float*)d_out;

  char* w = (char*)d_ws;
  auto carve = [&](size_t bytes) { char* p = w; w += (bytes + 255) & ~(size_t)255; return p; };
  float* tail_attn = (float*)carve((size_t)H_ * NT_ * 64 * sizeof(float));
  float* tail_lse  = (float*)carve((size_t)H_ * NT_ * sizeof(float));
  float* attn2     = (float*)carve((size_t)32 * 1016 * 64 * sizeof(float));
  float* lse2      = (float*)carve((size_t)32 * 1016 * sizeof(float));
  int* hq        = (int*)carve((size_t)H_ * NL_ * sizeof(int));
  int* hk        = (int*)carve((size_t)H_ * NL_ * sizeof(int));
  int* q_sort    = (int*)carve((size_t)H_ * NL_ * sizeof(int));
  int* k_sort    = (int*)carve((size_t)H_ * NL_ * sizeof(int));
  int* samp_pos  = (int*)carve((size_t)H_ * SAMP_ * sizeof(int));
  int* samp_orig = (int*)carve((size_t)H_ * SAMP_ * sizeof(int));

  kern_hash<<<dim3(H_, 8, 2), 256, 0, stream>>>(Q, K, proj, hq, hk);
  kern_sort<<<dim3(H_, 2), 128, 0, stream>>>(hq, hk, q_sort, k_sort);
  kern_sample<<<dim3(H_), SAMP_, 0, stream>>>(k_sort, samp_pos, samp_orig);
  kern_attn_mfma<<<dim3(1536), 256, 0, stream>>>(Q, K, V, tail_attn, tail_lse, attn2, lse2);
  kern_merge2<<<dim3(32, 8), 128, 0, stream>>>(tail_attn, tail_lse, attn2, lse2);
  kern_lsh_mfma<<<dim3(512), 256, 0, stream>>>(Q, K, V, q_sort, k_sort, samp_pos, samp_orig,
                                               tail_attn, tail_lse);
  kern_final<<<dim3(H_, 16), 256, 0, stream>>>(Q, K, V, tail_attn, tail_lse, out);
}

// Round 4
// 193.423 us; speedup vs baseline: 16.1525x; 1.5541x over previous
//
#include <hip/hip_runtime.h>
#include <hip/hip_bf16.h>
#include <math.h>
#include <stdint.h>

#define H_ 16
#define N_ 4096
#define NT_ 4064        // tail length
#define NL_ 2032        // LSH segment length
#define SINK_ 32
#define SAMP_ 256
#define SCALE_ 0.125f
#define NEGBIG_ -3.0e38f
#define LOGOFF_ 2.0719334f   // log(2032/256)

typedef unsigned int uint;
typedef unsigned short ushort;
typedef short bf16x8 __attribute__((ext_vector_type(8)));   // 8 bf16 in 4 VGPRs
typedef float f32x4 __attribute__((ext_vector_type(4)));

union B8 { uint4 u; bf16x8 b; };

__device__ __forceinline__ f32x4 mfma16(const B8& a, const B8& b, f32x4 c) {
  return __builtin_amdgcn_mfma_f32_16x16x32_bf16(a.b, b.b, c, 0, 0, 0);
}

// ---------------- bf16 pack (RNE) ----------------
__device__ __forceinline__ uint bfpack(float a, float b) {
  uint ua = __float_as_uint(a), ub = __float_as_uint(b);
  ua += 0x7fffu + ((ua >> 16) & 1u);
  ub += 0x7fffu + ((ub >> 16) & 1u);
  return (ua >> 16) | (ub & 0xffff0000u);
}

__device__ __forceinline__ float logaddexpf_(float a, float b) {
  float mx = fmaxf(a, b);
  return mx + __logf(__expf(a - mx) + __expf(b - mx));
}

__device__ __forceinline__ uint32_t rotl32_(uint32_t v, uint32_t d) {
  return (v << d) | (v >> (32u - d));
}

// JAX threefry2x32 (20 rounds)
__device__ inline void tf2x32(uint32_t k0, uint32_t k1, uint32_t& x0, uint32_t& x1) {
  uint32_t ks2 = k0 ^ k1 ^ 0x1BD11BDAu;
  x0 += k0; x1 += k1;
#define TFR(r) { x0 += x1; x1 = rotl32_(x1, r); x1 ^= x0; }
  TFR(13u) TFR(15u) TFR(26u) TFR(6u)
  x0 += k1;  x1 += ks2 + 1u;
  TFR(17u) TFR(29u) TFR(16u) TFR(24u)
  x0 += ks2; x1 += k0 + 2u;
  TFR(13u) TFR(15u) TFR(26u) TFR(6u)
  x0 += k0;  x1 += k1 + 3u;
  TFR(17u) TFR(29u) TFR(16u) TFR(24u)
  x0 += k1;  x1 += ks2 + 4u;
  TFR(13u) TFR(15u) TFR(26u) TFR(6u)
  x0 += ks2; x1 += k0 + 5u;
#undef TFR
}

// =========================================================================
// Fused hash + stable counting sort + threefry sample.
// grid (16, 2): blockIdx.x = head, blockIdx.y = which (0=q side, 1=k side).
// 256 threads. Chunked sort: 64 chunks x 32 elems, M[c][b] ushort histograms.
// =========================================================================
__global__ __launch_bounds__(256) void kern_prep(
    const float* __restrict__ Q, const float* __restrict__ K,
    const float* __restrict__ proj,
    int* __restrict__ q_sort, int* __restrict__ k_sort,
    int* __restrict__ samp_pos, int* __restrict__ samp_orig) {
  const int h = blockIdx.x, which = blockIdx.y;
  const int tid = threadIdx.x;

  __shared__ float pr[448];
  __shared__ unsigned char keys8[NL_];
  __shared__ ushort M[64 * 130];            // per-chunk histograms, padded stride
  __shared__ int btot[128];
  __shared__ int bscan[128];
  __shared__ ushort srt[NL_];

  for (int u = tid; u < 448; u += 256) pr[u] = proj[u];
  // zero M
  for (int u = tid; u < 64 * 130 / 2; u += 256) ((uint*)M)[u] = 0u;
  __syncthreads();

  // ---- Phase A: hash (8 rows/thread) ----
  const float* base = (which == 0) ? (Q + ((size_t)h * N_ + SINK_ + NL_) * 64)
                                   : (K + ((size_t)h * N_ + SINK_) * 64);
  for (int u = tid; u < NL_; u += 256) {
    const float4* x = (const float4*)(base + (size_t)u * 64);
    float xr[64];
#pragma unroll
    for (int d = 0; d < 16; ++d) {
      float4 g = x[d];
      xr[4*d+0] = g.x; xr[4*d+1] = g.y; xr[4*d+2] = g.z; xr[4*d+3] = g.w;
    }
    int bin = 0;
#pragma unroll
    for (int r = 0; r < 7; ++r) {
      float acc = 0.f;
#pragma unroll
      for (int d = 0; d < 64; ++d) acc = fmaf(xr[d], pr[d * 7 + r], acc);
      if (acc > 0.f) bin |= (1 << r);
    }
    keys8[u] = (unsigned char)(bin ^ (bin >> 1));   // Gray code
  }
  __syncthreads();

  // ---- Phase B: per-chunk histograms (thread c owns chunk c) ----
  if (tid < 64) {
    const int c = tid;
#pragma unroll 4
    for (int j = 0; j < 32; ++j) {
      const int u = c * 32 + j;
      if (u < NL_) ++M[c * 130 + keys8[u]];
    }
  }
  __syncthreads();

  // ---- Phase C: per-bucket chunk-prefix + totals ----
  if (tid < 128) {
    const int b = tid;
    int run = 0;
    for (int c = 0; c < 64; ++c) {
      const int v = M[c * 130 + b];
      M[c * 130 + b] = (ushort)run;
      run += v;
    }
    btot[b] = run;
    bscan[b] = run;
  }
  __syncthreads();

  // ---- Phase D: Hillis-Steele inclusive scan of 128 totals ----
  for (int ofs = 1; ofs < 128; ofs <<= 1) {
    int v = 0;
    if (tid < 128 && tid >= ofs) v = bscan[tid - ofs];
    __syncthreads();
    if (tid < 128) bscan[tid] += v;
    __syncthreads();
  }
  // exclusive base = inclusive - own
  __syncthreads();

  // ---- Phase E: scatter (stable) ----
  int* dst = (which == 0 ? q_sort : k_sort) + h * NL_;
  if (tid < 64) {
    const int c = tid;
    for (int j = 0; j < 32; ++j) {
      const int u = c * 32 + j;
      if (u < NL_) {
        const int k = keys8[u];
        const int pos = (bscan[k] - btot[k]) + M[c * 130 + k];
        M[c * 130 + k] += 1;
        dst[pos] = u;
        srt[pos] = (ushort)u;
      }
    }
  }
  __syncthreads();

  // ---- Phase F: threefry sample (k side only) ----
  if (which == 1) {
    const int s = tid;   // 256 threads = 256 samples
    uint32_t a0 = 0u, a1 = 0u; tf2x32(0u, 1234u, a0, a1);
    uint32_t b0 = 0u, b1 = 0u; tf2x32(a0, a1, b0, b1);
    uint32_t c0 = 0u, c1 = 1u; tf2x32(a0, a1, c0, c1);
    const uint32_t j = (uint32_t)(h * SAMP_ + s);
    uint32_t h0 = 0u, h1 = j; tf2x32(b0, b1, h0, h1);
    uint32_t l0 = 0u, l1 = j; tf2x32(c0, c1, l0, l1);
    const uint32_t Hb = h0 ^ h1, Lb = l0 ^ l1;
    const uint32_t off = ((Hb % 2032u) * 16u + (Lb % 2032u)) % 2032u;
    samp_pos[h * SAMP_ + s] = (int)off;
    samp_orig[h * SAMP_ + s] = (int)srt[off];
  }
}

// =========================================================================
// MFMA flash attention for P1 (causal 1016-chunks) + P2 (off-diagonal).
// =========================================================================
__global__ __launch_bounds__(256) void kern_attn_mfma(
    const float* __restrict__ Q, const float* __restrict__ K, const float* __restrict__ V,
    float* __restrict__ tail_attn, float* __restrict__ tail_lse,
    float* __restrict__ attn2, float* __restrict__ lse2) {
  __shared__ uint kk[2304];
  __shared__ uint vv[2304];
  __shared__ uint pbuf[1024];

  const int b = blockIdx.x;
  const int tid = threadIdx.x;
  const int lane = tid & 63, w = tid >> 6;
  const int g = lane >> 4, q = lane & 15;

  int h, q0, qbase, kbase, ntiles, p2vh = 0, chunkc = 0;
  bool causal;
  if (b < 512) {                       // P2: 32 vh x 16 qtiles (heavy, first)
    const int vh = b & 31; const int qt = b >> 5;
    h = vh >> 1; const int pp = vh & 1;
    q0 = qt * 64;
    qbase = SINK_ + pp * 2032 + 1016;
    kbase = SINK_ + pp * 2032;
    ntiles = 16; causal = false; p2vh = vh;
  } else {                             // P1: LPT descending qt
    const int u = b - 512; const int vh = u & 63;
    const int qt = 15 - (u >> 6);
    h = vh >> 2; chunkc = vh & 3;
    q0 = qt * 64;
    qbase = SINK_ + chunkc * 1016;
    kbase = qbase;
    ntiles = qt + 1; causal = true;
  }
  const size_t hN = (size_t)h * N_;
  const int qrow = q0 + w * 16 + q;
  const int qrow_c = min(qrow, 1015);

  B8 qb0, qb1;
  {
    const float4* qp = (const float4*)(Q + (hN + qbase + qrow_c) * 64);
    float4 a = qp[2*g], c = qp[2*g+1];
    qb0.u = make_uint4(bfpack(a.x*SCALE_, a.y*SCALE_), bfpack(a.z*SCALE_, a.w*SCALE_),
                       bfpack(c.x*SCALE_, c.y*SCALE_), bfpack(c.z*SCALE_, c.w*SCALE_));
    float4 d = qp[8+2*g], e = qp[8+2*g+1];
    qb1.u = make_uint4(bfpack(d.x*SCALE_, d.y*SCALE_), bfpack(d.z*SCALE_, d.w*SCALE_),
                       bfpack(e.x*SCALE_, e.y*SCALE_), bfpack(e.z*SCALE_, e.w*SCALE_));
  }
  f32x4 o0 = {0.f,0.f,0.f,0.f}, o1 = o0, o2 = o0, o3 = o0;
  float m = -INFINITY, ssum = 0.f;
  const int qwmax = q0 + w * 16 + 15;

  const int skey = tid >> 2, sdb = (tid & 3) * 16;
  const int vkp = tid & 31, vdb = (tid >> 5) * 8;
  const int pwb = w * 1024 + q * 64;

  for (int t = 0; t < ntiles; ++t) {
    const int kt = t * 64;
    __syncthreads();
    { // ---- stage K [key][d] bf16 ----
      const int kr = kt + skey;
      uint4 p0 = make_uint4(0,0,0,0), p1 = make_uint4(0,0,0,0);
      if (kr < 1016) {
        const float4* kp = (const float4*)(K + (hN + kbase + kr) * 64 + sdb);
        float4 f0 = kp[0], f1 = kp[1], f2 = kp[2], f3 = kp[3];
        p0 = make_uint4(bfpack(f0.x,f0.y), bfpack(f0.z,f0.w), bfpack(f1.x,f1.y), bfpack(f1.z,f1.w));
        p1 = make_uint4(bfpack(f2.x,f2.y), bfpack(f2.z,f2.w), bfpack(f3.x,f3.y), bfpack(f3.z,f3.w));
      }
      *(uint4*)((char*)kk + skey*144 + sdb*2) = p0;
      *(uint4*)((char*)kk + skey*144 + sdb*2 + 16) = p1;
    }
    { // ---- stage V^T [d][key] bf16 ----
      const int kr0 = kt + 2 * vkp;
      float e0[8] = {0,0,0,0,0,0,0,0}, e1[8] = {0,0,0,0,0,0,0,0};
      if (kr0 < 1016) {
        const float4* v0p = (const float4*)(V + (hN + kbase + kr0) * 64 + vdb);
        const float4* v1p = (const float4*)(V + (hN + kbase + kr0 + 1) * 64 + vdb);
        float4 a0 = v0p[0], a1 = v0p[1], b0 = v1p[0], b1 = v1p[1];
        e0[0]=a0.x; e0[1]=a0.y; e0[2]=a0.z; e0[3]=a0.w; e0[4]=a1.x; e0[5]=a1.y; e0[6]=a1.z; e0[7]=a1.w;
        e1[0]=b0.x; e1[1]=b0.y; e1[2]=b0.z; e1[3]=b0.w; e1[4]=b1.x; e1[5]=b1.y; e1[6]=b1.z; e1[7]=b1.w;
      }
#pragma unroll
      for (int jd = 0; jd < 8; ++jd)
        *(uint*)((char*)vv + (vdb + jd)*144 + 4*vkp) = bfpack(e0[jd], e1[jd]);
    }
    __syncthreads();
    if (causal && kt > qwmax) continue;

    f32x4 s0, s1, s2, s3;
    {
      B8 ka, kb2;
#define QKST(SREG, ST) { \
      ka.u  = *(const uint4*)((char*)kk + ((ST)*16 + q)*144 + g*16); \
      kb2.u = *(const uint4*)((char*)kk + ((ST)*16 + q)*144 + 64 + g*16); \
      f32x4 acc_ = {0.f,0.f,0.f,0.f}; \
      acc_ = mfma16(ka, qb0, acc_); \
      acc_ = mfma16(kb2, qb1, acc_); \
      SREG = acc_; }
      QKST(s0, 0) QKST(s1, 1) QKST(s2, 2) QKST(s3, 3)
#undef QKST
    }

    if (causal) {
      if (kt + 63 >= q0 + w * 16) {
        const int kb0 = kt + 4 * g;
#pragma unroll
        for (int r = 0; r < 4; ++r) {
          if (kb0 + r      > qrow) s0[r] = NEGBIG_;
          if (kb0 + 16 + r > qrow) s1[r] = NEGBIG_;
          if (kb0 + 32 + r > qrow) s2[r] = NEGBIG_;
          if (kb0 + 48 + r > qrow) s3[r] = NEGBIG_;
        }
      }
    } else if (kt + 63 >= 1016) {
      const int kb0 = kt + 4 * g;
#pragma unroll
      for (int r = 0; r < 4; ++r) {
        if (kb0 + r      >= 1016) s0[r] = NEGBIG_;
        if (kb0 + 16 + r >= 1016) s1[r] = NEGBIG_;
        if (kb0 + 32 + r >= 1016) s2[r] = NEGBIG_;
        if (kb0 + 48 + r >= 1016) s3[r] = NEGBIG_;
      }
    }

    float mx = fmaxf(fmaxf(s0[0], s0[1]), fmaxf(s0[2], s0[3]));
    mx = fmaxf(mx, fmaxf(fmaxf(s1[0], s1[1]), fmaxf(s1[2], s1[3])));
    mx = fmaxf(mx, fmaxf(fmaxf(s2[0], s2[1]), fmaxf(s2[2], s2[3])));
    mx = fmaxf(mx, fmaxf(fmaxf(s3[0], s3[1]), fmaxf(s3[2], s3[3])));
    mx = fmaxf(mx, __shfl_xor(mx, 16));
    mx = fmaxf(mx, __shfl_xor(mx, 32));
    const float nm = fmaxf(m, mx);
    const float fold = __expf(m - nm);
    float ts = 0.f;
#pragma unroll
    for (int r = 0; r < 4; ++r) {
      s0[r] = __expf(s0[r] - nm); ts += s0[r];
      s1[r] = __expf(s1[r] - nm); ts += s1[r];
      s2[r] = __expf(s2[r] - nm); ts += s2[r];
      s3[r] = __expf(s3[r] - nm); ts += s3[r];
    }
    ts += __shfl_xor(ts, 16);
    ts += __shfl_xor(ts, 32);
    ssum = ssum * fold + ts;
    o0 = o0 * fold; o1 = o1 * fold; o2 = o2 * fold; o3 = o3 * fold;
    m = nm;

#pragma unroll
    for (int hk = 0; hk < 2; ++hk) {
      f32x4 pa = (hk == 0) ? s0 : s2;
      f32x4 pc = (hk == 0) ? s1 : s3;
      uint2 w0 = make_uint2(bfpack(pa[0], pa[1]), bfpack(pa[2], pa[3]));
      uint2 w1 = make_uint2(bfpack(pc[0], pc[1]), bfpack(pc[2], pc[3]));
      *(uint2*)((char*)pbuf + pwb + ((((g>>1)    ) ^ (q&3))*16) + (g&1)*8) = w0;
      *(uint2*)((char*)pbuf + pwb + (((2 + (g>>1)) ^ (q&3))*16) + (g&1)*8) = w1;
      B8 pf, vf;
      pf.u = *(const uint4*)((char*)pbuf + pwb + ((g ^ (q&3))*16));
      vf.u = *(const uint4*)((char*)vv + (0*16 + q)*144 + hk*64 + g*16); o0 = mfma16(vf, pf, o0);
      vf.u = *(const uint4*)((char*)vv + (1*16 + q)*144 + hk*64 + g*16); o1 = mfma16(vf, pf, o1);
      vf.u = *(const uint4*)((char*)vv + (2*16 + q)*144 + hk*64 + g*16); o2 = mfma16(vf, pf, o2);
      vf.u = *(const uint4*)((char*)vv + (3*16 + q)*144 + hk*64 + g*16); o3 = mfma16(vf, pf, o3);
    }
  }

  if (qrow < 1016) {
    const float lse = m + __logf(ssum);
    const float inv = 1.f / ssum;
    f32x4 r0 = o0 * inv, r1 = o1 * inv, r2 = o2 * inv, r3 = o3 * inv;
    if (causal) {
      const int trow = chunkc * 1016 + qrow;
      float* tp = tail_attn + ((size_t)h * NT_ + trow) * 64;
      *(f32x4*)(tp +  0 + 4*g) = r0;
      *(f32x4*)(tp + 16 + 4*g) = r1;
      *(f32x4*)(tp + 32 + 4*g) = r2;
      *(f32x4*)(tp + 48 + 4*g) = r3;
      if (lane < 16) tail_lse[h * NT_ + trow] = lse;
    } else {
      float* tp = attn2 + ((size_t)p2vh * 1016 + qrow) * 64;
      *(f32x4*)(tp +  0 + 4*g) = r0;
      *(f32x4*)(tp + 16 + 4*g) = r1;
      *(f32x4*)(tp + 32 + 4*g) = r2;
      *(f32x4*)(tp + 48 + 4*g) = r3;
      if (lane < 16) lse2[p2vh * 1016 + qrow] = lse;
    }
  }
}

// ---------------- merge P2 into tail ----------------
__global__ __launch_bounds__(128) void kern_merge2(float* __restrict__ tail_attn, float* __restrict__ tail_lse,
                                                   const float* __restrict__ attn2, const float* __restrict__ lse2) {
  const int vh = blockIdx.x;
  const int i = blockIdx.y * 128 + (int)threadIdx.x;
  if (i >= 1016) return;
  const int h = vh >> 1, pp = vh & 1;
  const int t = pp * 2032 + 1016 + i;
  const float l2 = lse2[vh * 1016 + i];
  float* tlp = tail_lse + h * NT_ + t;
  const float bl = *tlp;
  const float c = 1.f / (1.f + __expf(l2 - bl));
  const float4* ap = (const float4*)(attn2 + ((size_t)vh * 1016 + i) * 64);
  float4* tp = (float4*)(tail_attn + ((size_t)h * NT_ + t) * 64);
#pragma unroll
  for (int d = 0; d < 16; ++d) {
    const float4 bd = tp[d], a2 = ap[d];
    tp[d] = make_float4(c * bd.x + (1.f - c) * a2.x,
                        c * bd.y + (1.f - c) * a2.y,
                        c * bd.z + (1.f - c) * a2.z,
                        c * bd.w + (1.f - c) * a2.w);
  }
  *tlp = logaddexpf_(bl, l2);
}

// =========================================================================
// MFMA LSH attention (block-diag sorted + sampled residual), merged into tail.
// =========================================================================
__global__ __launch_bounds__(256) void kern_lsh_mfma(
    const float* __restrict__ Q, const float* __restrict__ K, const float* __restrict__ V,
    const int* __restrict__ q_sort, const int* __restrict__ k_sort,
    const int* __restrict__ samp_pos, const int* __restrict__ samp_orig,
    float* __restrict__ tail_attn, float* __restrict__ tail_lse) {
  __shared__ uint kk[2304];
  __shared__ uint vv[2304];
  __shared__ uint pbuf[1024];
  __shared__ float bias_s[64];

  const int b = blockIdx.x;
  const int h = b >> 5, pt = b & 31;
  const int tid = threadIdx.x;
  const int lane = tid & 63, w = tid >> 6;
  const int g = lane >> 4, q = lane & 15;
  const int blkq = pt >> 2;
  const size_t hN = (size_t)h * N_;

  const int p = pt * 64 + w * 16 + q;
  const int pc = min(p, NL_ - 1);
  const int qi = q_sort[h * NL_ + pc];

  B8 qb0, qb1;
  {
    const float4* qp = (const float4*)(Q + (hN + SINK_ + NL_ + qi) * 64);
    float4 a = qp[2*g], c = qp[2*g+1];
    qb0.u = make_uint4(bfpack(a.x*SCALE_, a.y*SCALE_), bfpack(a.z*SCALE_, a.w*SCALE_),
                       bfpack(c.x*SCALE_, c.y*SCALE_), bfpack(c.z*SCALE_, c.w*SCALE_));
    float4 d = qp[8+2*g], e = qp[8+2*g+1];
    qb1.u = make_uint4(bfpack(d.x*SCALE_, d.y*SCALE_), bfpack(d.z*SCALE_, d.w*SCALE_),
                       bfpack(e.x*SCALE_, e.y*SCALE_), bfpack(e.z*SCALE_, e.w*SCALE_));
  }
  f32x4 o0 = {0.f,0.f,0.f,0.f}, o1 = o0, o2 = o0, o3 = o0;
  float m = -INFINITY, ssum = 0.f;

  const int skey = tid >> 2, sdb = (tid & 3) * 16;
  const int vkp = tid & 31, vdb = (tid >> 5) * 8;
  const int pwb = w * 1024 + q * 64;

  for (int t = 0; t < 8; ++t) {
    __syncthreads();
    { // ---- stage K (gathered) ----
      int krow = -1;
      if (t < 4) {
        const int slot = blkq * 256 + t * 64 + skey;
        if (slot < NL_) krow = k_sort[h * NL_ + slot];
      } else {
        krow = samp_orig[h * SAMP_ + (t - 4) * 64 + skey];
      }
      uint4 p0 = make_uint4(0,0,0,0), p1 = make_uint4(0,0,0,0);
      if (krow >= 0) {
        const float4* kp = (const float4*)(K + (hN + SINK_ + krow) * 64 + sdb);
        float4 f0 = kp[0], f1 = kp[1], f2 = kp[2], f3 = kp[3];
        p0 = make_uint4(bfpack(f0.x,f0.y), bfpack(f0.z,f0.w), bfpack(f1.x,f1.y), bfpack(f1.z,f1.w));
        p1 = make_uint4(bfpack(f2.x,f2.y), bfpack(f2.z,f2.w), bfpack(f3.x,f3.y), bfpack(f3.z,f3.w));
      }
      *(uint4*)((char*)kk + skey*144 + sdb*2) = p0;
      *(uint4*)((char*)kk + skey*144 + sdb*2 + 16) = p1;
    }
    { // ---- stage V^T (gathered) ----
      int kr0 = -1, kr1 = -1;
      if (t < 4) {
        const int slot0 = blkq * 256 + t * 64 + 2 * vkp;
        if (slot0 < NL_)     kr0 = k_sort[h * NL_ + slot0];
        if (slot0 + 1 < NL_) kr1 = k_sort[h * NL_ + slot0 + 1];
      } else {
        const int si = (t - 4) * 64 + 2 * vkp;
        kr0 = samp_orig[h * SAMP_ + si];
        kr1 = samp_orig[h * SAMP_ + si + 1];
      }
      float e0[8] = {0,0,0,0,0,0,0,0}, e1[8] = {0,0,0,0,0,0,0,0};
      if (kr0 >= 0) {
        const float4* v0p = (const float4*)(V + (hN + SINK_ + kr0) * 64 + vdb);
        float4 a0 = v0p[0], a1 = v0p[1];
        e0[0]=a0.x; e0[1]=a0.y; e0[2]=a0.z; e0[3]=a0.w; e0[4]=a1.x; e0[5]=a1.y; e0[6]=a1.z; e0[7]=a1.w;
      }
      if (kr1 >= 0) {
        const float4* v1p = (const float4*)(V + (hN + SINK_ + kr1) * 64 + vdb);
        float4 b0 = v1p[0], b1 = v1p[1];
        e1[0]=b0.x; e1[1]=b0.y; e1[2]=b0.z; e1[3]=b0.w; e1[4]=b1.x; e1[5]=b1.y; e1[6]=b1.z; e1[7]=b1.w;
      }
#pragma unroll
      for (int jd = 0; jd < 8; ++jd)
        *(uint*)((char*)vv + (vdb + jd)*144 + 4*vkp) = bfpack(e0[jd], e1[jd]);
    }
    if (t >= 4 && tid < 64)
      bias_s[tid] = ((samp_pos[h * SAMP_ + (t - 4) * 64 + tid] >> 8) == blkq) ? NEGBIG_ : LOGOFF_;
    __syncthreads();

    f32x4 s0, s1, s2, s3;
    {
      B8 ka, kb2;
#define QKST(SREG, ST) { \
      ka.u  = *(const uint4*)((char*)kk + ((ST)*16 + q)*144 + g*16); \
      kb2.u = *(const uint4*)((char*)kk + ((ST)*16 + q)*144 + 64 + g*16); \
      f32x4 acc_ = {0.f,0.f,0.f,0.f}; \
      acc_ = mfma16(ka, qb0, acc_); \
      acc_ = mfma16(kb2, qb1, acc_); \
      SREG = acc_; }
      QKST(s0, 0) QKST(s1, 1) QKST(s2, 2) QKST(s3, 3)
#undef QKST
    }
    if (t >= 4) {
      const f32x4* bp = (const f32x4*)bias_s;
      s0 = s0 + bp[0*4 + g];
      s1 = s1 + bp[1*4 + g];
      s2 = s2 + bp[2*4 + g];
      s3 = s3 + bp[3*4 + g];
    }

    float mx = fmaxf(fmaxf(s0[0], s0[1]), fmaxf(s0[2], s0[3]));
    mx = fmaxf(mx, fmaxf(fmaxf(s1[0], s1[1]), fmaxf(s1[2], s1[3])));
    mx = fmaxf(mx, fmaxf(fmaxf(s2[0], s2[1]), fmaxf(s2[2], s2[3])));
    mx = fmaxf(mx, fmaxf(fmaxf(s3[0], s3[1]), fmaxf(s3[2], s3[3])));
    mx = fmaxf(mx, __shfl_xor(mx, 16));
    mx = fmaxf(mx, __shfl_xor(mx, 32));
    const float nm = fmaxf(m, mx);
    const float fold = __expf(m - nm);
    float ts = 0.f;
#pragma unroll
    for (int r = 0; r < 4; ++r) {
      s0[r] = __expf(s0[r] - nm); ts += s0[r];
      s1[r] = __expf(s1[r] - nm); ts += s1[r];
      s2[r] = __expf(s2[r] - nm); ts += s2[r];
      s3[r] = __expf(s3[r] - nm); ts += s3[r];
    }
    ts += __shfl_xor(ts, 16);
    ts += __shfl_xor(ts, 32);
    ssum = ssum * fold + ts;
    o0 = o0 * fold; o1 = o1 * fold; o2 = o2 * fold; o3 = o3 * fold;
    m = nm;

#pragma unroll
    for (int hk = 0; hk < 2; ++hk) {
      f32x4 pa = (hk == 0) ? s0 : s2;
      f32x4 pc = (hk == 0) ? s1 : s3;
      uint2 w0 = make_uint2(bfpack(pa[0], pa[1]), bfpack(pa[2], pa[3]));
      uint2 w1 = make_uint2(bfpack(pc[0], pc[1]), bfpack(pc[2], pc[3]));
      *(uint2*)((char*)pbuf + pwb + ((((g>>1)    ) ^ (q&3))*16) + (g&1)*8) = w0;
      *(uint2*)((char*)pbuf + pwb + (((2 + (g>>1)) ^ (q&3))*16) + (g&1)*8) = w1;
      B8 pf, vf;
      pf.u = *(const uint4*)((char*)pbuf + pwb + ((g ^ (q&3))*16));
      vf.u = *(const uint4*)((char*)vv + (0*16 + q)*144 + hk*64 + g*16); o0 = mfma16(vf, pf, o0);
      vf.u = *(const uint4*)((char*)vv + (1*16 + q)*144 + hk*64 + g*16); o1 = mfma16(vf, pf, o1);
      vf.u = *(const uint4*)((char*)vv + (2*16 + q)*144 + hk*64 + g*16); o2 = mfma16(vf, pf, o2);
      vf.u = *(const uint4*)((char*)vv + (3*16 + q)*144 + hk*64 + g*16); o3 = mfma16(vf, pf, o3);
    }
  }

  if (p < NL_) {
    const float un = m + __logf(ssum);
    const float inv = 1.f / ssum;
    const int trow = NL_ + qi;
    float* tlp = tail_lse + h * NT_ + trow;
    const float bd = *tlp;
    const float c2 = 1.f / (1.f + __expf(un - bd));
    const float w2 = inv * (1.f - c2);
    float* tp = tail_attn + ((size_t)h * NT_ + trow) * 64;
    f32x4 t0 = *(f32x4*)(tp +  0 + 4*g);
    f32x4 t1 = *(f32x4*)(tp + 16 + 4*g);
    f32x4 t2 = *(f32x4*)(tp + 32 + 4*g);
    f32x4 t3 = *(f32x4*)(tp + 48 + 4*g);
    *(f32x4*)(tp +  0 + 4*g) = t0 * c2 + o0 * w2;
    *(f32x4*)(tp + 16 + 4*g) = t1 * c2 + o1 * w2;
    *(f32x4*)(tp + 32 + 4*g) = t2 * c2 + o2 * w2;
    *(f32x4*)(tp + 48 + 4*g) = t3 * c2 + o3 * w2;
    if (lane < 16) *tlp = logaddexpf_(bd, un);
  }
}

// ---------------- sink prefix + final merge ----------------
__global__ __launch_bounds__(256) void kern_final(const float* __restrict__ Q, const float* __restrict__ K,
                                                  const float* __restrict__ V,
                                                  const float* __restrict__ tail_attn, const float* __restrict__ tail_lse,
                                                  float* __restrict__ out) {
  const int h = blockIdx.x;
  const int r = blockIdx.y * 256 + (int)threadIdx.x;

  __shared__ float4 kk[SINK_ * 16];
  __shared__ float4 vv[SINK_ * 16];
  for (int u = threadIdx.x; u < SINK_ * 16; u += 256) {
    const int row = u >> 4, d4 = u & 15;
    kk[u] = ((const float4*)(K + ((size_t)h * N_ + row) * 64))[d4];
    vv[u] = ((const float4*)(V + ((size_t)h * N_ + row) * 64))[d4];
  }
  __syncthreads();

  float4 q4[16], acc[16];
  const float4* qp = (const float4*)(Q + ((size_t)h * N_ + r) * 64);
#pragma unroll
  for (int d = 0; d < 16; ++d) { q4[d] = qp[d]; acc[d] = make_float4(0.f, 0.f, 0.f, 0.f); }

  float m = -INFINITY, ssum = 0.f;
  const int nk = min(SINK_, r + 1);
  for (int j = 0; j < nk; ++j) {
    float s = 0.f;
#pragma unroll
    for (int d = 0; d < 16; ++d) {
      float4 x = q4[d], y = kk[j * 16 + d];
      s = fmaf(x.x, y.x, s); s = fmaf(x.y, y.y, s);
      s = fmaf(x.z, y.z, s); s = fmaf(x.w, y.w, s);
    }
    s *= SCALE_;
    const float nm = fmaxf(m, s);
    const float f = __expf(m - nm), w = __expf(s - nm);
    ssum = ssum * f + w;
    const float4* v4 = &vv[j * 16];
#pragma unroll
    for (int d = 0; d < 16; ++d) {
      acc[d].x = acc[d].x * f + w * v4[d].x;
      acc[d].y = acc[d].y * f + w * v4[d].y;
      acc[d].z = acc[d].z * f + w * v4[d].z;
      acc[d].w = acc[d].w * f + w * v4[d].w;
    }
    m = nm;
  }
  const float pl = m + __logf(ssum);
  const float inv = 1.f / ssum;
  float4* op = (float4*)(out + ((size_t)h * N_ + r) * 64);
  if (r < SINK_) {
#pragma unroll
    for (int d = 0; d < 16; ++d)
      op[d] = make_float4(acc[d].x * inv, acc[d].y * inv, acc[d].z * inv, acc[d].w * inv);
  } else {
    const int t = r - SINK_;
    const float tl = tail_lse[h * NT_ + t];
    const float cc = 1.f / (1.f + __expf(tl - pl));
    const float4* tp = (const float4*)(tail_attn + ((size_t)h * NT_ + t) * 64);
#pragma unroll
    for (int d = 0; d < 16; ++d) {
      const float4 tv = tp[d];
      op[d] = make_float4(cc * acc[d].x * inv + (1.f - cc) * tv.x,
                          cc * acc[d].y * inv + (1.f - cc) * tv.y,
                          cc * acc[d].z * inv + (1.f - cc) * tv.z,
                          cc * acc[d].w * inv + (1.f - cc) * tv.w);
    }
  }
}

// ---------------- host ----------------
extern "C" void kernel_launch(void* const* d_in, const int* in_sizes, int n_in,
                              void* d_out, int out_size, void* d_ws, size_t ws_size,
                              hipStream_t stream) {
  (void)in_sizes; (void)n_in; (void)out_size; (void)ws_size;
  const float* Q = (const float*)d_in[0];
  const float* K = (const float*)d_in[1];
  const float* V = (const float*)d_in[2];
  const float* proj = (const float*)d_in[3];
  float* out = (float*)d_out;

  char* w = (char*)d_ws;
  auto carve = [&](size_t bytes) { char* p = w; w += (bytes + 255) & ~(size_t)255; return p; };
  float* tail_attn = (float*)carve((size_t)H_ * NT_ * 64 * sizeof(float));
  float* tail_lse  = (float*)carve((size_t)H_ * NT_ * sizeof(float));
  float* attn2     = (float*)carve((size_t)32 * 1016 * 64 * sizeof(float));
  float* lse2      = (float*)carve((size_t)32 * 1016 * sizeof(float));
  int* q_sort    = (int*)carve((size_t)H_ * NL_ * sizeof(int));
  int* k_sort    = (int*)carve((size_t)H_ * NL_ * sizeof(int));
  int* samp_pos  = (int*)carve((size_t)H_ * SAMP_ * sizeof(int));
  int* samp_orig = (int*)carve((size_t)H_ * SAMP_ * sizeof(int));

  kern_prep<<<dim3(H_, 2), 256, 0, stream>>>(Q, K, proj, q_sort, k_sort, samp_pos, samp_orig);
  kern_attn_mfma<<<dim3(1536), 256, 0, stream>>>(Q, K, V, tail_attn, tail_lse, attn2, lse2);
  kern_merge2<<<dim3(32, 8), 128, 0, stream>>>(tail_attn, tail_lse, attn2, lse2);
  kern_lsh_mfma<<<dim3(512), 256, 0, stream>>>(Q, K, V, q_sort, k_sort, samp_pos, samp_orig,
                                               tail_attn, tail_lse);
  kern_final<<<dim3(H_, 16), 256, 0, stream>>>(Q, K, V, tail_attn, tail_lse, out);
}

// Round 5
// 178.579 us; speedup vs baseline: 17.4952x; 1.0831x over previous
//
#include <hip/hip_runtime.h>
#include <hip/hip_bf16.h>
#include <math.h>
#include <stdint.h>

#define H_ 16
#define N_ 4096
#define NT_ 4064        // tail length
#define NL_ 2032        // LSH segment length
#define SINK_ 32
#define SAMP_ 256
#define SCALE_ 0.125f
#define NEGBIG_ -3.0e38f
#define LOGOFF_ 2.0719334f   // log(2032/256)

typedef unsigned int uint;
typedef unsigned short ushort;
typedef short bf16x8 __attribute__((ext_vector_type(8)));
typedef float f32x4 __attribute__((ext_vector_type(4)));

union B8 { uint4 u; bf16x8 b; };

__device__ __forceinline__ f32x4 mfma16(const B8& a, const B8& b, f32x4 c) {
  return __builtin_amdgcn_mfma_f32_16x16x32_bf16(a.b, b.b, c, 0, 0, 0);
}

__device__ __forceinline__ uint bfpack(float a, float b) {
  uint ua = __float_as_uint(a), ub = __float_as_uint(b);
  ua += 0x7fffu + ((ua >> 16) & 1u);
  ub += 0x7fffu + ((ub >> 16) & 1u);
  return (ua >> 16) | (ub & 0xffff0000u);
}

__device__ __forceinline__ float logaddexpf_(float a, float b) {
  float mx = fmaxf(a, b);
  return mx + __logf(__expf(a - mx) + __expf(b - mx));
}

__device__ __forceinline__ uint32_t rotl32_(uint32_t v, uint32_t d) {
  return (v << d) | (v >> (32u - d));
}

// JAX threefry2x32 (20 rounds)
__device__ inline void tf2x32(uint32_t k0, uint32_t k1, uint32_t& x0, uint32_t& x1) {
  uint32_t ks2 = k0 ^ k1 ^ 0x1BD11BDAu;
  x0 += k0; x1 += k1;
#define TFR(r) { x0 += x1; x1 = rotl32_(x1, r); x1 ^= x0; }
  TFR(13u) TFR(15u) TFR(26u) TFR(6u)
  x0 += k1;  x1 += ks2 + 1u;
  TFR(17u) TFR(29u) TFR(16u) TFR(24u)
  x0 += ks2; x1 += k0 + 2u;
  TFR(13u) TFR(15u) TFR(26u) TFR(6u)
  x0 += k0;  x1 += k1 + 3u;
  TFR(17u) TFR(29u) TFR(16u) TFR(24u)
  x0 += k1;  x1 += ks2 + 4u;
  TFR(13u) TFR(15u) TFR(26u) TFR(6u)
  x0 += ks2; x1 += k0 + 5u;
#undef TFR
}

// ---------------- online softmax helpers ----------------
__device__ __forceinline__ void online_sm(f32x4 s[4], float& m, float& ssum, f32x4 o[4]) {
  float mx = fmaxf(fmaxf(s[0][0], s[0][1]), fmaxf(s[0][2], s[0][3]));
  mx = fmaxf(mx, fmaxf(fmaxf(s[1][0], s[1][1]), fmaxf(s[1][2], s[1][3])));
  mx = fmaxf(mx, fmaxf(fmaxf(s[2][0], s[2][1]), fmaxf(s[2][2], s[2][3])));
  mx = fmaxf(mx, fmaxf(fmaxf(s[3][0], s[3][1]), fmaxf(s[3][2], s[3][3])));
  mx = fmaxf(mx, __shfl_xor(mx, 16));
  mx = fmaxf(mx, __shfl_xor(mx, 32));
  const float nm = fmaxf(m, mx);
  const float fold = __expf(m - nm);
  float ts = 0.f;
#pragma unroll
  for (int st = 0; st < 4; ++st) {
#pragma unroll
    for (int r = 0; r < 4; ++r) { s[st][r] = __expf(s[st][r] - nm); ts += s[st][r]; }
  }
  ts += __shfl_xor(ts, 16);
  ts += __shfl_xor(ts, 32);
  ssum = ssum * fold + ts;
  o[0] = o[0] * fold; o[1] = o[1] * fold; o[2] = o[2] * fold; o[3] = o[3] * fold;
  m = nm;
}

__device__ __forceinline__ void pv_step(const f32x4 s[4], f32x4 o[4],
                                        const uint* vvb, char* pw, int g, int q) {
#pragma unroll
  for (int hk2 = 0; hk2 < 2; ++hk2) {
    const f32x4 pa = s[2 * hk2], pc = s[2 * hk2 + 1];
    uint2 w0 = make_uint2(bfpack(pa[0], pa[1]), bfpack(pa[2], pa[3]));
    uint2 w1 = make_uint2(bfpack(pc[0], pc[1]), bfpack(pc[2], pc[3]));
    *(uint2*)(pw + ((((g >> 1)    ) ^ (q & 3)) * 16) + (g & 1) * 8) = w0;
    *(uint2*)(pw + (((2 + (g >> 1)) ^ (q & 3)) * 16) + (g & 1) * 8) = w1;
    B8 pf, vf;
    pf.u = *(const uint4*)(pw + ((g ^ (q & 3)) * 16));
    vf.u = *(const uint4*)((char*)vvb + (0 * 16 + q) * 144 + hk2 * 64 + g * 16); o[0] = mfma16(vf, pf, o[0]);
    vf.u = *(const uint4*)((char*)vvb + (1 * 16 + q) * 144 + hk2 * 64 + g * 16); o[1] = mfma16(vf, pf, o[1]);
    vf.u = *(const uint4*)((char*)vvb + (2 * 16 + q) * 144 + hk2 * 64 + g * 16); o[2] = mfma16(vf, pf, o[2]);
    vf.u = *(const uint4*)((char*)vvb + (3 * 16 + q) * 144 + hk2 * 64 + g * 16); o[3] = mfma16(vf, pf, o[3]);
  }
}

// ---------------- bf16 pre-pack: Kb, Vb ----------------
__global__ __launch_bounds__(256) void kern_pack(const float* __restrict__ K, const float* __restrict__ V,
                                                 ushort* __restrict__ Kb, ushort* __restrict__ Vb) {
  const int which = blockIdx.x;
  const size_t idx = (size_t)blockIdx.y * 256 + threadIdx.x;   // 524288 per array
  const float4* s = (const float4*)((which == 0 ? K : V) + idx * 8);
  float4 f0 = s[0], f1 = s[1];
  uint4 p = make_uint4(bfpack(f0.x, f0.y), bfpack(f0.z, f0.w),
                       bfpack(f1.x, f1.y), bfpack(f1.z, f1.w));
  *(uint4*)((which == 0 ? Kb : Vb) + idx * 8) = p;
}

// ---------------- hashing ----------------
__global__ __launch_bounds__(256) void kern_hash(const float* __restrict__ Q, const float* __restrict__ K,
                                                 const float* __restrict__ proj,
                                                 int* __restrict__ hq, int* __restrict__ hk) {
  const int h = blockIdx.x, tile = blockIdx.y, which = blockIdx.z;
  __shared__ float pr[448];
  for (int u = threadIdx.x; u < 448; u += 256) pr[u] = proj[u];
  __syncthreads();
  const int i = tile * 256 + (int)threadIdx.x;
  if (i >= NL_) return;
  const int orig = (which == 0) ? (SINK_ + NL_ + i) : (SINK_ + i);
  const float4* x = (const float4*)((which == 0 ? Q : K) + ((size_t)h * N_ + orig) * 64);
  float xr[64];
#pragma unroll
  for (int d = 0; d < 16; ++d) {
    float4 g = x[d];
    xr[4*d+0] = g.x; xr[4*d+1] = g.y; xr[4*d+2] = g.z; xr[4*d+3] = g.w;
  }
  int bin = 0;
#pragma unroll
  for (int r = 0; r < 7; ++r) {
    float acc = 0.f;
#pragma unroll
    for (int d = 0; d < 64; ++d) acc = fmaf(xr[d], pr[d * 7 + r], acc);
    if (acc > 0.f) bin |= (1 << r);
  }
  const int g = bin ^ (bin >> 1);   // _PERM = Gray code
  (which == 0 ? hq : hk)[h * NL_ + i] = g;
}

// ---------------- chunked stable counting sort + threefry sample ----------------
__global__ __launch_bounds__(256) void kern_sortsamp(
    const int* __restrict__ hq, const int* __restrict__ hk,
    int* __restrict__ q_sort, int* __restrict__ k_sort,
    int* __restrict__ samp_pos, int* __restrict__ samp_orig) {
  const int h = blockIdx.x, which = blockIdx.y;
  const int tid = threadIdx.x;

  __shared__ unsigned char keys8[NL_];
  __shared__ ushort M[64 * 130];
  __shared__ int btot[128];
  __shared__ int bscan[128];
  __shared__ ushort srt[NL_];

  const int* src = (which == 0 ? hq : hk) + h * NL_;
  for (int u = tid; u < 64 * 130 / 2; u += 256) ((uint*)M)[u] = 0u;
  for (int u = tid; u < NL_; u += 256) keys8[u] = (unsigned char)src[u];
  __syncthreads();

  if (tid < 64) {           // per-chunk histograms
    const int c = tid;
#pragma unroll 4
    for (int j = 0; j < 32; ++j) {
      const int u = c * 32 + j;
      if (u < NL_) ++M[c * 130 + keys8[u]];
    }
  }
  __syncthreads();

  if (tid < 128) {          // per-bucket chunk-prefix + totals
    const int b = tid;
    int run = 0;
    for (int c = 0; c < 64; ++c) {
      const int v = M[c * 130 + b];
      M[c * 130 + b] = (ushort)run;
      run += v;
    }
    btot[b] = run;
    bscan[b] = run;
  }
  __syncthreads();

  for (int ofs = 1; ofs < 128; ofs <<= 1) {   // Hillis-Steele inclusive scan
    int v = 0;
    if (tid < 128 && tid >= ofs) v = bscan[tid - ofs];
    __syncthreads();
    if (tid < 128) bscan[tid] += v;
    __syncthreads();
  }

  int* dst = (which == 0 ? q_sort : k_sort) + h * NL_;
  if (tid < 64) {           // stable scatter
    const int c = tid;
    for (int j = 0; j < 32; ++j) {
      const int u = c * 32 + j;
      if (u < NL_) {
        const int k = keys8[u];
        const int pos = (bscan[k] - btot[k]) + M[c * 130 + k];
        M[c * 130 + k] += 1;
        dst[pos] = u;
        srt[pos] = (ushort)u;
      }
    }
  }
  __syncthreads();

  if (which == 1) {         // threefry sample
    const int s = tid;
    uint32_t a0 = 0u, a1 = 0u; tf2x32(0u, 1234u, a0, a1);
    uint32_t b0 = 0u, b1 = 0u; tf2x32(a0, a1, b0, b1);
    uint32_t c0 = 0u, c1 = 1u; tf2x32(a0, a1, c0, c1);
    const uint32_t j = (uint32_t)(h * SAMP_ + s);
    uint32_t h0 = 0u, h1 = j; tf2x32(b0, b1, h0, h1);
    uint32_t l0 = 0u, l1 = j; tf2x32(c0, c1, l0, l1);
    const uint32_t Hb = h0 ^ h1, Lb = l0 ^ l1;
    const uint32_t off = ((Hb % 2032u) * 16u + (Lb % 2032u)) % 2032u;
    samp_pos[h * SAMP_ + s] = (int)off;
    samp_orig[h * SAMP_ + s] = (int)srt[off];
  }
}

// =========================================================================
// MFMA flash attention, 128 q-rows/block (2 fragments per wave).
// blocks 0..255: P2 (8 qt x 32 vh); 256..767: P1 (LPT descending qt).
// =========================================================================
__global__ __launch_bounds__(256) void kern_attn_mfma(
    const float* __restrict__ Q, const ushort* __restrict__ Kb, const ushort* __restrict__ Vb,
    float* __restrict__ tail_attn, float* __restrict__ tail_lse,
    float* __restrict__ attn2, float* __restrict__ lse2) {
  __shared__ uint kk[2304];
  __shared__ uint vv[2304];
  __shared__ uint pbuf[1024];

  const int b = blockIdx.x;
  const int tid = threadIdx.x;
  const int lane = tid & 63, w = tid >> 6;
  const int g = lane >> 4, q = lane & 15;

  int h, q0, qbase, kbase, ntiles, p2vh = 0, chunkc = 0;
  bool causal;
  if (b < 256) {                       // P2
    const int vh = b & 31; const int qt = b >> 5;
    h = vh >> 1; const int pp = vh & 1;
    q0 = qt * 128;
    qbase = SINK_ + pp * 2032 + 1016;
    kbase = SINK_ + pp * 2032;
    ntiles = 16; causal = false; p2vh = vh;
  } else {                             // P1
    const int u = b - 256; const int vh = u & 63;
    const int qt = 7 - (u >> 6);
    h = vh >> 2; chunkc = vh & 3;
    q0 = qt * 128;
    qbase = SINK_ + chunkc * 1016;
    kbase = qbase;
    ntiles = 2 * qt + 2; causal = true;
  }
  const size_t hN = (size_t)h * N_;
  const int qrowA = q0 + w * 16 + q;
  const int qrowB = qrowA + 64;
  const int qcA = min(qrowA, 1015), qcB = min(qrowB, 1015);

  B8 qbA0, qbA1, qbB0, qbB1;
  {
    const float4* qp = (const float4*)(Q + (hN + qbase + qcA) * 64);
    float4 a = qp[2*g], c = qp[2*g+1], d = qp[8+2*g], e = qp[8+2*g+1];
    qbA0.u = make_uint4(bfpack(a.x*SCALE_, a.y*SCALE_), bfpack(a.z*SCALE_, a.w*SCALE_),
                        bfpack(c.x*SCALE_, c.y*SCALE_), bfpack(c.z*SCALE_, c.w*SCALE_));
    qbA1.u = make_uint4(bfpack(d.x*SCALE_, d.y*SCALE_), bfpack(d.z*SCALE_, d.w*SCALE_),
                        bfpack(e.x*SCALE_, e.y*SCALE_), bfpack(e.z*SCALE_, e.w*SCALE_));
    const float4* qp2 = (const float4*)(Q + (hN + qbase + qcB) * 64);
    a = qp2[2*g]; c = qp2[2*g+1]; d = qp2[8+2*g]; e = qp2[8+2*g+1];
    qbB0.u = make_uint4(bfpack(a.x*SCALE_, a.y*SCALE_), bfpack(a.z*SCALE_, a.w*SCALE_),
                        bfpack(c.x*SCALE_, c.y*SCALE_), bfpack(c.z*SCALE_, c.w*SCALE_));
    qbB1.u = make_uint4(bfpack(d.x*SCALE_, d.y*SCALE_), bfpack(d.z*SCALE_, d.w*SCALE_),
                        bfpack(e.x*SCALE_, e.y*SCALE_), bfpack(e.z*SCALE_, e.w*SCALE_));
  }
  f32x4 oA[4] = {{0,0,0,0},{0,0,0,0},{0,0,0,0},{0,0,0,0}};
  f32x4 oB[4] = {{0,0,0,0},{0,0,0,0},{0,0,0,0},{0,0,0,0}};
  float mA = -INFINITY, sA_ = 0.f, mB = -INFINITY, sB_ = 0.f;
  const int qwmaxA = q0 + w * 16 + 15;

  const int skey = tid >> 2;
  const int vkp = tid & 31, vdb = (tid >> 5) * 8;
  char* pw = (char*)pbuf + w * 1024 + q * 64;

  for (int t = 0; t < ntiles; ++t) {
    const int kt = t * 64;
    __syncthreads();
    { // ---- stage K (bf16 copy) ----
      const int kr = kt + skey;
      uint4 p0 = make_uint4(0,0,0,0), p1 = make_uint4(0,0,0,0);
      if (kr < 1016) {
        const ushort* src = Kb + (hN + kbase + kr) * 64 + (tid & 3) * 16;
        p0 = *(const uint4*)src; p1 = *(const uint4*)(src + 8);
      }
      *(uint4*)((char*)kk + skey*144 + (tid&3)*32) = p0;
      *(uint4*)((char*)kk + skey*144 + (tid&3)*32 + 16) = p1;
    }
    { // ---- stage V^T (bf16 repack) ----
      const int kr0 = kt + 2 * vkp;
      uint aw0=0,aw1=0,aw2=0,aw3=0, bw0=0,bw1=0,bw2=0,bw3=0;
      if (kr0 < 1016) {
        uint4 a = *(const uint4*)(Vb + (hN + kbase + kr0) * 64 + vdb);
        uint4 bb = *(const uint4*)(Vb + (hN + kbase + kr0 + 1) * 64 + vdb);
        aw0=a.x; aw1=a.y; aw2=a.z; aw3=a.w; bw0=bb.x; bw1=bb.y; bw2=bb.z; bw3=bb.w;
      }
#define VPAIR(jw, AW, BW) { \
      *(uint*)((char*)vv + (vdb + 2*(jw)    )*144 + 4*vkp) = (AW & 0xffffu) | (BW << 16); \
      *(uint*)((char*)vv + (vdb + 2*(jw) + 1)*144 + 4*vkp) = (AW >> 16) | (BW & 0xffff0000u); }
      VPAIR(0, aw0, bw0) VPAIR(1, aw1, bw1) VPAIR(2, aw2, bw2) VPAIR(3, aw3, bw3)
#undef VPAIR
    }
    __syncthreads();

    const bool doA = !(causal && kt > qwmaxA);
    f32x4 sA[4], sB[4];
#pragma unroll
    for (int st = 0; st < 4; ++st) {
      B8 ka, kb2;
      ka.u  = *(const uint4*)((char*)kk + (st*16 + q)*144 + g*16);
      kb2.u = *(const uint4*)((char*)kk + (st*16 + q)*144 + 64 + g*16);
      if (doA) {
        f32x4 acc = {0.f,0.f,0.f,0.f};
        acc = mfma16(ka, qbA0, acc); acc = mfma16(kb2, qbA1, acc);
        sA[st] = acc;
      }
      f32x4 acc2 = {0.f,0.f,0.f,0.f};
      acc2 = mfma16(ka, qbB0, acc2); acc2 = mfma16(kb2, qbB1, acc2);
      sB[st] = acc2;
    }

    if (causal) {
      const int kb0 = kt + 4 * g;
      if (doA && kt + 63 > qwmaxA - 15) {   // boundary region for frag A
#pragma unroll
        for (int st = 0; st < 4; ++st)
#pragma unroll
          for (int r = 0; r < 4; ++r)
            if (kb0 + st * 16 + r > qrowA) sA[st][r] = NEGBIG_;
      }
      if (kt + 63 >= q0 + 64 + w * 16) {
#pragma unroll
        for (int st = 0; st < 4; ++st)
#pragma unroll
          for (int r = 0; r < 4; ++r)
            if (kb0 + st * 16 + r > qrowB) sB[st][r] = NEGBIG_;
      }
    } else if (kt + 63 >= 1016) {
      const int kb0 = kt + 4 * g;
#pragma unroll
      for (int st = 0; st < 4; ++st)
#pragma unroll
        for (int r = 0; r < 4; ++r)
          if (kb0 + st * 16 + r >= 1016) { sA[st][r] = NEGBIG_; sB[st][r] = NEGBIG_; }
    }

    if (doA) {
      online_sm(sA, mA, sA_, oA);
      pv_step(sA, oA, vv, pw, g, q);
    }
    online_sm(sB, mB, sB_, oB);
    pv_step(sB, oB, vv, pw, g, q);
  }

  // ---- epilogue: two rows per lane ----
#pragma unroll
  for (int fr = 0; fr < 2; ++fr) {
    const int qrow = fr == 0 ? qrowA : qrowB;
    if (qrow >= 1016) continue;
    f32x4* o = fr == 0 ? oA : oB;
    const float m = fr == 0 ? mA : mB;
    const float ss = fr == 0 ? sA_ : sB_;
    const float lse = m + __logf(ss);
    const float inv = 1.f / ss;
    if (causal) {
      const int trow = chunkc * 1016 + qrow;
      float* tp = tail_attn + ((size_t)h * NT_ + trow) * 64;
      *(f32x4*)(tp +  0 + 4*g) = o[0] * inv;
      *(f32x4*)(tp + 16 + 4*g) = o[1] * inv;
      *(f32x4*)(tp + 32 + 4*g) = o[2] * inv;
      *(f32x4*)(tp + 48 + 4*g) = o[3] * inv;
      if (lane < 16) tail_lse[h * NT_ + trow] = lse;
    } else {
      float* tp = attn2 + ((size_t)p2vh * 1016 + qrow) * 64;
      *(f32x4*)(tp +  0 + 4*g) = o[0] * inv;
      *(f32x4*)(tp + 16 + 4*g) = o[1] * inv;
      *(f32x4*)(tp + 32 + 4*g) = o[2] * inv;
      *(f32x4*)(tp + 48 + 4*g) = o[3] * inv;
      if (lane < 16) lse2[p2vh * 1016 + qrow] = lse;
    }
  }
}

// ---------------- merge P2 into tail ----------------
__global__ __launch_bounds__(128) void kern_merge2(float* __restrict__ tail_attn, float* __restrict__ tail_lse,
                                                   const float* __restrict__ attn2, const float* __restrict__ lse2) {
  const int vh = blockIdx.x;
  const int i = blockIdx.y * 128 + (int)threadIdx.x;
  if (i >= 1016) return;
  const int h = vh >> 1, pp = vh & 1;
  const int t = pp * 2032 + 1016 + i;
  const float l2 = lse2[vh * 1016 + i];
  float* tlp = tail_lse + h * NT_ + t;
  const float bl = *tlp;
  const float c = 1.f / (1.f + __expf(l2 - bl));
  const float4* ap = (const float4*)(attn2 + ((size_t)vh * 1016 + i) * 64);
  float4* tp = (float4*)(tail_attn + ((size_t)h * NT_ + t) * 64);
#pragma unroll
  for (int d = 0; d < 16; ++d) {
    const float4 bd = tp[d], a2 = ap[d];
    tp[d] = make_float4(c * bd.x + (1.f - c) * a2.x,
                        c * bd.y + (1.f - c) * a2.y,
                        c * bd.z + (1.f - c) * a2.z,
                        c * bd.w + (1.f - c) * a2.w);
  }
  *tlp = logaddexpf_(bl, l2);
}

// =========================================================================
// MFMA LSH attention, 128 q-rows/block (2 frags/wave), merged into tail.
// =========================================================================
__global__ __launch_bounds__(256) void kern_lsh_mfma(
    const float* __restrict__ Q, const ushort* __restrict__ Kb, const ushort* __restrict__ Vb,
    const int* __restrict__ q_sort, const int* __restrict__ k_sort,
    const int* __restrict__ samp_pos, const int* __restrict__ samp_orig,
    float* __restrict__ tail_attn, float* __restrict__ tail_lse) {
  __shared__ uint kk[2304];
  __shared__ uint vv[2304];
  __shared__ uint pbuf[1024];
  __shared__ float bias_s[64];

  const int b = blockIdx.x;
  const int h = b >> 4, pt = b & 15;
  const int tid = threadIdx.x;
  const int lane = tid & 63, w = tid >> 6;
  const int g = lane >> 4, q = lane & 15;
  const int blkq = pt >> 1;
  const size_t hN = (size_t)h * N_;

  const int pA = pt * 128 + w * 16 + q;
  const int pB = pA + 64;
  const int qiA = q_sort[h * NL_ + min(pA, NL_ - 1)];
  const int qiB = q_sort[h * NL_ + min(pB, NL_ - 1)];

  B8 qbA0, qbA1, qbB0, qbB1;
  {
    const float4* qp = (const float4*)(Q + (hN + SINK_ + NL_ + qiA) * 64);
    float4 a = qp[2*g], c = qp[2*g+1], d = qp[8+2*g], e = qp[8+2*g+1];
    qbA0.u = make_uint4(bfpack(a.x*SCALE_, a.y*SCALE_), bfpack(a.z*SCALE_, a.w*SCALE_),
                        bfpack(c.x*SCALE_, c.y*SCALE_), bfpack(c.z*SCALE_, c.w*SCALE_));
    qbA1.u = make_uint4(bfpack(d.x*SCALE_, d.y*SCALE_), bfpack(d.z*SCALE_, d.w*SCALE_),
                        bfpack(e.x*SCALE_, e.y*SCALE_), bfpack(e.z*SCALE_, e.w*SCALE_));
    const float4* qp2 = (const float4*)(Q + (hN + SINK_ + NL_ + qiB) * 64);
    a = qp2[2*g]; c = qp2[2*g+1]; d = qp2[8+2*g]; e = qp2[8+2*g+1];
    qbB0.u = make_uint4(bfpack(a.x*SCALE_, a.y*SCALE_), bfpack(a.z*SCALE_, a.w*SCALE_),
                        bfpack(c.x*SCALE_, c.y*SCALE_), bfpack(c.z*SCALE_, c.w*SCALE_));
    qbB1.u = make_uint4(bfpack(d.x*SCALE_, d.y*SCALE_), bfpack(d.z*SCALE_, d.w*SCALE_),
                        bfpack(e.x*SCALE_, e.y*SCALE_), bfpack(e.z*SCALE_, e.w*SCALE_));
  }
  f32x4 oA[4] = {{0,0,0,0},{0,0,0,0},{0,0,0,0},{0,0,0,0}};
  f32x4 oB[4] = {{0,0,0,0},{0,0,0,0},{0,0,0,0},{0,0,0,0}};
  float mA = -INFINITY, sA_ = 0.f, mB = -INFINITY, sB_ = 0.f;

  const int skey = tid >> 2;
  const int vkp = tid & 31, vdb = (tid >> 5) * 8;
  char* pw = (char*)pbuf + w * 1024 + q * 64;

  for (int t = 0; t < 8; ++t) {
    __syncthreads();
    { // ---- stage K (gathered bf16) ----
      int krow = -1;
      if (t < 4) {
        const int slot = blkq * 256 + t * 64 + skey;
        if (slot < NL_) krow = k_sort[h * NL_ + slot];
      } else {
        krow = samp_orig[h * SAMP_ + (t - 4) * 64 + skey];
      }
      uint4 p0 = make_uint4(0,0,0,0), p1 = make_uint4(0,0,0,0);
      if (krow >= 0) {
        const ushort* src = Kb + (hN + SINK_ + krow) * 64 + (tid & 3) * 16;
        p0 = *(const uint4*)src; p1 = *(const uint4*)(src + 8);
      }
      *(uint4*)((char*)kk + skey*144 + (tid&3)*32) = p0;
      *(uint4*)((char*)kk + skey*144 + (tid&3)*32 + 16) = p1;
    }
    { // ---- stage V^T (gathered bf16 repack) ----
      int kr0 = -1, kr1 = -1;
      if (t < 4) {
        const int slot0 = blkq * 256 + t * 64 + 2 * vkp;
        if (slot0 < NL_)     kr0 = k_sort[h * NL_ + slot0];
        if (slot0 + 1 < NL_) kr1 = k_sort[h * NL_ + slot0 + 1];
      } else {
        const int si = (t - 4) * 64 + 2 * vkp;
        kr0 = samp_orig[h * SAMP_ + si];
        kr1 = samp_orig[h * SAMP_ + si + 1];
      }
      uint aw0=0,aw1=0,aw2=0,aw3=0, bw0=0,bw1=0,bw2=0,bw3=0;
      if (kr0 >= 0) {
        uint4 a = *(const uint4*)(Vb + (hN + SINK_ + kr0) * 64 + vdb);
        aw0=a.x; aw1=a.y; aw2=a.z; aw3=a.w;
      }
      if (kr1 >= 0) {
        uint4 bb = *(const uint4*)(Vb + (hN + SINK_ + kr1) * 64 + vdb);
        bw0=bb.x; bw1=bb.y; bw2=bb.z; bw3=bb.w;
      }
#define VPAIR(jw, AW, BW) { \
      *(uint*)((char*)vv + (vdb + 2*(jw)    )*144 + 4*vkp) = (AW & 0xffffu) | (BW << 16); \
      *(uint*)((char*)vv + (vdb + 2*(jw) + 1)*144 + 4*vkp) = (AW >> 16) | (BW & 0xffff0000u); }
      VPAIR(0, aw0, bw0) VPAIR(1, aw1, bw1) VPAIR(2, aw2, bw2) VPAIR(3, aw3, bw3)
#undef VPAIR
    }
    if (t >= 4 && tid < 64)
      bias_s[tid] = ((samp_pos[h * SAMP_ + (t - 4) * 64 + tid] >> 8) == blkq) ? NEGBIG_ : LOGOFF_;
    __syncthreads();

    f32x4 sA[4], sB[4];
#pragma unroll
    for (int st = 0; st < 4; ++st) {
      B8 ka, kb2;
      ka.u  = *(const uint4*)((char*)kk + (st*16 + q)*144 + g*16);
      kb2.u = *(const uint4*)((char*)kk + (st*16 + q)*144 + 64 + g*16);
      f32x4 acc = {0.f,0.f,0.f,0.f};
      acc = mfma16(ka, qbA0, acc); acc = mfma16(kb2, qbA1, acc);
      sA[st] = acc;
      f32x4 acc2 = {0.f,0.f,0.f,0.f};
      acc2 = mfma16(ka, qbB0, acc2); acc2 = mfma16(kb2, qbB1, acc2);
      sB[st] = acc2;
    }
    if (t >= 4) {
      const f32x4* bp = (const f32x4*)bias_s;
#pragma unroll
      for (int st = 0; st < 4; ++st) {
        sA[st] = sA[st] + bp[st * 4 + g];
        sB[st] = sB[st] + bp[st * 4 + g];
      }
    }

    online_sm(sA, mA, sA_, oA);
    pv_step(sA, oA, vv, pw, g, q);
    online_sm(sB, mB, sB_, oB);
    pv_step(sB, oB, vv, pw, g, q);
  }

  // ---- merge into tail (unsort scatter), two rows ----
#pragma unroll
  for (int fr = 0; fr < 2; ++fr) {
    const int p = fr == 0 ? pA : pB;
    if (p >= NL_) continue;
    const int qi = fr == 0 ? qiA : qiB;
    f32x4* o = fr == 0 ? oA : oB;
    const float m = fr == 0 ? mA : mB;
    const float ss = fr == 0 ? sA_ : sB_;
    const float un = m + __logf(ss);
    const float inv = 1.f / ss;
    const int trow = NL_ + qi;
    float* tlp = tail_lse + h * NT_ + trow;
    const float bd = *tlp;
    const float c2 = 1.f / (1.f + __expf(un - bd));
    const float w2 = inv * (1.f - c2);
    float* tp = tail_attn + ((size_t)h * NT_ + trow) * 64;
    f32x4 t0 = *(f32x4*)(tp +  0 + 4*g);
    f32x4 t1 = *(f32x4*)(tp + 16 + 4*g);
    f32x4 t2 = *(f32x4*)(tp + 32 + 4*g);
    f32x4 t3 = *(f32x4*)(tp + 48 + 4*g);
    *(f32x4*)(tp +  0 + 4*g) = t0 * c2 + o[0] * w2;
    *(f32x4*)(tp + 16 + 4*g) = t1 * c2 + o[1] * w2;
    *(f32x4*)(tp + 32 + 4*g) = t2 * c2 + o[2] * w2;
    *(f32x4*)(tp + 48 + 4*g) = t3 * c2 + o[3] * w2;
    if (lane < 16) *tlp = logaddexpf_(bd, un);
  }
}

// ---------------- sink prefix + final merge ----------------
__global__ __launch_bounds__(256) void kern_final(const float* __restrict__ Q, const float* __restrict__ K,
                                                  const float* __restrict__ V,
                                                  const float* __restrict__ tail_attn, const float* __restrict__ tail_lse,
                                                  float* __restrict__ out) {
  const int h = blockIdx.x;
  const int r = blockIdx.y * 256 + (int)threadIdx.x;

  __shared__ float4 kk[SINK_ * 16];
  __shared__ float4 vv[SINK_ * 16];
  for (int u = threadIdx.x; u < SINK_ * 16; u += 256) {
    const int row = u >> 4, d4 = u & 15;
    kk[u] = ((const float4*)(K + ((size_t)h * N_ + row) * 64))[d4];
    vv[u] = ((const float4*)(V + ((size_t)h * N_ + row) * 64))[d4];
  }
  __syncthreads();

  float4 q4[16], acc[16];
  const float4* qp = (const float4*)(Q + ((size_t)h * N_ + r) * 64);
#pragma unroll
  for (int d = 0; d < 16; ++d) { q4[d] = qp[d]; acc[d] = make_float4(0.f, 0.f, 0.f, 0.f); }

  float m = -INFINITY, ssum = 0.f;
  const int nk = min(SINK_, r + 1);
  for (int j = 0; j < nk; ++j) {
    float s = 0.f;
#pragma unroll
    for (int d = 0; d < 16; ++d) {
      float4 x = q4[d], y = kk[j * 16 + d];
      s = fmaf(x.x, y.x, s); s = fmaf(x.y, y.y, s);
      s = fmaf(x.z, y.z, s); s = fmaf(x.w, y.w, s);
    }
    s *= SCALE_;
    const float nm = fmaxf(m, s);
    const float f = __expf(m - nm), wgt = __expf(s - nm);
    ssum = ssum * f + wgt;
    const float4* v4 = &vv[j * 16];
#pragma unroll
    for (int d = 0; d < 16; ++d) {
      acc[d].x = acc[d].x * f + wgt * v4[d].x;
      acc[d].y = acc[d].y * f + wgt * v4[d].y;
      acc[d].z = acc[d].z * f + wgt * v4[d].z;
      acc[d].w = acc[d].w * f + wgt * v4[d].w;
    }
    m = nm;
  }
  const float pl = m + __logf(ssum);
  const float inv = 1.f / ssum;
  float4* op = (float4*)(out + ((size_t)h * N_ + r) * 64);
  if (r < SINK_) {
#pragma unroll
    for (int d = 0; d < 16; ++d)
      op[d] = make_float4(acc[d].x * inv, acc[d].y * inv, acc[d].z * inv, acc[d].w * inv);
  } else {
    const int t = r - SINK_;
    const float tl = tail_lse[h * NT_ + t];
    const float cc = 1.f / (1.f + __expf(tl - pl));
    const float4* tp = (const float4*)(tail_attn + ((size_t)h * NT_ + t) * 64);
#pragma unroll
    for (int d = 0; d < 16; ++d) {
      const float4 tv = tp[d];
      op[d] = make_float4(cc * acc[d].x * inv + (1.f - cc) * tv.x,
                          cc * acc[d].y * inv + (1.f - cc) * tv.y,
                          cc * acc[d].z * inv + (1.f - cc) * tv.z,
                          cc * acc[d].w * inv + (1.f - cc) * tv.w);
    }
  }
}

// ---------------- host ----------------
extern "C" void kernel_launch(void* const* d_in, const int* in_sizes, int n_in,
                              void* d_out, int out_size, void* d_ws, size_t ws_size,
                              hipStream_t stream) {
  (void)in_sizes; (void)n_in; (void)out_size; (void)ws_size;
  const float* Q = (const float*)d_in[0];
  const float* K = (const float*)d_in[1];
  const float* V = (const float*)d_in[2];
  const float* proj = (const float*)d_in[3];
  float* out = (float*)d_out;

  char* w = (char*)d_ws;
  auto carve = [&](size_t bytes) { char* p = w; w += (bytes + 255) & ~(size_t)255; return p; };
  float* tail_attn = (float*)carve((size_t)H_ * NT_ * 64 * sizeof(float));
  float* tail_lse  = (float*)carve((size_t)H_ * NT_ * sizeof(float));
  float* attn2     = (float*)carve((size_t)32 * 1016 * 64 * sizeof(float));
  float* lse2      = (float*)carve((size_t)32 * 1016 * sizeof(float));
  ushort* Kb     = (ushort*)carve((size_t)H_ * N_ * 64 * sizeof(ushort));
  ushort* Vb     = (ushort*)carve((size_t)H_ * N_ * 64 * sizeof(ushort));
  int* hq        = (int*)carve((size_t)H_ * NL_ * sizeof(int));
  int* hk        = (int*)carve((size_t)H_ * NL_ * sizeof(int));
  int* q_sort    = (int*)carve((size_t)H_ * NL_ * sizeof(int));
  int* k_sort    = (int*)carve((size_t)H_ * NL_ * sizeof(int));
  int* samp_pos  = (int*)carve((size_t)H_ * SAMP_ * sizeof(int));
  int* samp_orig = (int*)carve((size_t)H_ * SAMP_ * sizeof(int));

  kern_pack<<<dim3(2, 2048), 256, 0, stream>>>(K, V, Kb, Vb);
  kern_hash<<<dim3(H_, 8, 2), 256, 0, stream>>>(Q, K, proj, hq, hk);
  kern_sortsamp<<<dim3(H_, 2), 256, 0, stream>>>(hq, hk, q_sort, k_sort, samp_pos, samp_orig);
  kern_attn_mfma<<<dim3(768), 256, 0, stream>>>(Q, Kb, Vb, tail_attn, tail_lse, attn2, lse2);
  kern_merge2<<<dim3(32, 8), 128, 0, stream>>>(tail_attn, tail_lse, attn2, lse2);
  kern_lsh_mfma<<<dim3(256), 256, 0, stream>>>(Q, Kb, Vb, q_sort, k_sort, samp_pos, samp_orig,
                                               tail_attn, tail_lse);
  kern_final<<<dim3(H_, 16), 256, 0, stream>>>(Q, K, V, tail_attn, tail_lse, out);
}

// Round 6
// 167.352 us; speedup vs baseline: 18.6689x; 1.0671x over previous
//
#include <hip/hip_runtime.h>
#include <hip/hip_bf16.h>
#include <math.h>
#include <stdint.h>

#define H_ 16
#define N_ 4096
#define NT_ 4064        // tail length
#define NL_ 2032        // LSH segment length
#define SINK_ 32
#define SAMP_ 256
#define SCALE_ 0.125f
#define NEGBIG_ -3.0e38f
#define LOGOFF_ 2.0719334f   // log(2032/256)

typedef unsigned int uint;
typedef unsigned short ushort;
typedef short bf16x8 __attribute__((ext_vector_type(8)));
typedef float f32x4 __attribute__((ext_vector_type(4)));

union B8 { uint4 u; bf16x8 b; };

__device__ __forceinline__ f32x4 mfma16(const B8& a, const B8& b, f32x4 c) {
  return __builtin_amdgcn_mfma_f32_16x16x32_bf16(a.b, b.b, c, 0, 0, 0);
}

__device__ __forceinline__ uint bfpack(float a, float b) {
  uint ua = __float_as_uint(a), ub = __float_as_uint(b);
  ua += 0x7fffu + ((ua >> 16) & 1u);
  ub += 0x7fffu + ((ub >> 16) & 1u);
  return (ua >> 16) | (ub & 0xffff0000u);
}

__device__ __forceinline__ float logaddexpf_(float a, float b) {
  float mx = fmaxf(a, b);
  return mx + __logf(__expf(a - mx) + __expf(b - mx));
}

__device__ __forceinline__ uint32_t rotl32_(uint32_t v, uint32_t d) {
  return (v << d) | (v >> (32u - d));
}

// JAX threefry2x32 (20 rounds)
__device__ inline void tf2x32(uint32_t k0, uint32_t k1, uint32_t& x0, uint32_t& x1) {
  uint32_t ks2 = k0 ^ k1 ^ 0x1BD11BDAu;
  x0 += k0; x1 += k1;
#define TFR(r) { x0 += x1; x1 = rotl32_(x1, r); x1 ^= x0; }
  TFR(13u) TFR(15u) TFR(26u) TFR(6u)
  x0 += k1;  x1 += ks2 + 1u;
  TFR(17u) TFR(29u) TFR(16u) TFR(24u)
  x0 += ks2; x1 += k0 + 2u;
  TFR(13u) TFR(15u) TFR(26u) TFR(6u)
  x0 += k0;  x1 += k1 + 3u;
  TFR(17u) TFR(29u) TFR(16u) TFR(24u)
  x0 += k1;  x1 += ks2 + 4u;
  TFR(13u) TFR(15u) TFR(26u) TFR(6u)
  x0 += ks2; x1 += k0 + 5u;
#undef TFR
}

// ---------------- online softmax + PV helpers ----------------
__device__ __forceinline__ void online_sm(f32x4 s[4], float& m, float& ssum, f32x4 o[4]) {
  float mx = fmaxf(fmaxf(s[0][0], s[0][1]), fmaxf(s[0][2], s[0][3]));
  mx = fmaxf(mx, fmaxf(fmaxf(s[1][0], s[1][1]), fmaxf(s[1][2], s[1][3])));
  mx = fmaxf(mx, fmaxf(fmaxf(s[2][0], s[2][1]), fmaxf(s[2][2], s[2][3])));
  mx = fmaxf(mx, fmaxf(fmaxf(s[3][0], s[3][1]), fmaxf(s[3][2], s[3][3])));
  mx = fmaxf(mx, __shfl_xor(mx, 16));
  mx = fmaxf(mx, __shfl_xor(mx, 32));
  const float nm = fmaxf(m, mx);
  const float fold = __expf(m - nm);
  float ts = 0.f;
#pragma unroll
  for (int st = 0; st < 4; ++st) {
#pragma unroll
    for (int r = 0; r < 4; ++r) { s[st][r] = __expf(s[st][r] - nm); ts += s[st][r]; }
  }
  ts += __shfl_xor(ts, 16);
  ts += __shfl_xor(ts, 32);
  ssum = ssum * fold + ts;
  o[0] = o[0] * fold; o[1] = o[1] * fold; o[2] = o[2] * fold; o[3] = o[3] * fold;
  m = nm;
}

// pbuf rows: 80B stride (conflict-friendly), write keys 4g..4g+3 (w0) / 16+4g.. (w1)
__device__ __forceinline__ void pv_step(const f32x4 s[4], f32x4 o[4],
                                        const char* vq, char* pw, int g, int voff) {
#pragma unroll
  for (int hk2 = 0; hk2 < 2; ++hk2) {
    const f32x4 pa = s[2 * hk2], pc = s[2 * hk2 + 1];
    uint2 w0 = make_uint2(bfpack(pa[0], pa[1]), bfpack(pa[2], pa[3]));
    uint2 w1 = make_uint2(bfpack(pc[0], pc[1]), bfpack(pc[2], pc[3]));
    *(uint2*)(pw + 8 * g) = w0;
    *(uint2*)(pw + 32 + 8 * g) = w1;
    B8 pf, vf;
    pf.u = *(const uint4*)(pw - 8 * g - (g ? 0 : 0) + g * 16 - g * 8);  // placeholder (unused)
    pf.u = *(const uint4*)((pw - 0) + g * 16);
    const int vb = voff + hk2 * 64;
    vf.u = *(const uint4*)(vq + 0 * 16 * 272 + vb); o[0] = mfma16(vf, pf, o[0]);
    vf.u = *(const uint4*)(vq + 1 * 16 * 272 + vb); o[1] = mfma16(vf, pf, o[1]);
    vf.u = *(const uint4*)(vq + 2 * 16 * 272 + vb); o[2] = mfma16(vf, pf, o[2]);
    vf.u = *(const uint4*)(vq + 3 * 16 * 272 + vb); o[3] = mfma16(vf, pf, o[3]);
  }
}

// lsh variant: vv stride 144
__device__ __forceinline__ void pv_step144(const f32x4 s[4], f32x4 o[4],
                                           const char* vq, char* pw, int g) {
#pragma unroll
  for (int hk2 = 0; hk2 < 2; ++hk2) {
    const f32x4 pa = s[2 * hk2], pc = s[2 * hk2 + 1];
    uint2 w0 = make_uint2(bfpack(pa[0], pa[1]), bfpack(pa[2], pa[3]));
    uint2 w1 = make_uint2(bfpack(pc[0], pc[1]), bfpack(pc[2], pc[3]));
    *(uint2*)(pw + 8 * g) = w0;
    *(uint2*)(pw + 32 + 8 * g) = w1;
    B8 pf, vf;
    pf.u = *(const uint4*)(pw + g * 16);
    vf.u = *(const uint4*)(vq + 0 * 16 * 144 + hk2 * 64); o[0] = mfma16(vf, pf, o[0]);
    vf.u = *(const uint4*)(vq + 1 * 16 * 144 + hk2 * 64); o[1] = mfma16(vf, pf, o[1]);
    vf.u = *(const uint4*)(vq + 2 * 16 * 144 + hk2 * 64); o[2] = mfma16(vf, pf, o[2]);
    vf.u = *(const uint4*)(vq + 3 * 16 * 144 + hk2 * 64); o[3] = mfma16(vf, pf, o[3]);
  }
}

// ---------------- fused pack (bf16 K/V) + hash ----------------
__global__ __launch_bounds__(256) void kern_packhash(
    const float* __restrict__ K, const float* __restrict__ V, const float* __restrict__ Q,
    const float* __restrict__ proj,
    ushort* __restrict__ Kb, ushort* __restrict__ Vb,
    int* __restrict__ hq, int* __restrict__ hk) {
  const int bb = blockIdx.x;
  if (bb < 4096) {               // pack
    const int which = bb >> 11;
    const size_t idx = ((size_t)(bb & 2047)) * 256 + threadIdx.x;
    const float4* s = (const float4*)((which == 0 ? K : V) + idx * 8);
    float4 f0 = s[0], f1 = s[1];
    uint4 p = make_uint4(bfpack(f0.x, f0.y), bfpack(f0.z, f0.w),
                         bfpack(f1.x, f1.y), bfpack(f1.z, f1.w));
    *(uint4*)((which == 0 ? Kb : Vb) + idx * 8) = p;
    return;
  }
  // hash
  const int u = bb - 4096;
  const int h = u & 15, tile = (u >> 4) & 7, which = u >> 7;
  __shared__ float pr[448];
  for (int t = threadIdx.x; t < 448; t += 256) pr[t] = proj[t];
  __syncthreads();
  const int i = tile * 256 + (int)threadIdx.x;
  if (i >= NL_) return;
  const int orig = (which == 0) ? (SINK_ + NL_ + i) : (SINK_ + i);
  const float4* x = (const float4*)((which == 0 ? Q : K) + ((size_t)h * N_ + orig) * 64);
  float xr[64];
#pragma unroll
  for (int d = 0; d < 16; ++d) {
    float4 g = x[d];
    xr[4*d+0] = g.x; xr[4*d+1] = g.y; xr[4*d+2] = g.z; xr[4*d+3] = g.w;
  }
  int bin = 0;
#pragma unroll
  for (int r = 0; r < 7; ++r) {
    float acc = 0.f;
#pragma unroll
    for (int d = 0; d < 64; ++d) acc = fmaf(xr[d], pr[d * 7 + r], acc);
    if (acc > 0.f) bin |= (1 << r);
  }
  const int g = bin ^ (bin >> 1);   // _PERM = Gray code
  (which == 0 ? hq : hk)[h * NL_ + i] = g;
}

// ---------------- chunked stable counting sort + threefry sample ----------------
__global__ __launch_bounds__(256) void kern_sortsamp(
    const int* __restrict__ hq, const int* __restrict__ hk,
    int* __restrict__ q_sort, int* __restrict__ k_sort,
    int* __restrict__ samp_pos, int* __restrict__ samp_orig) {
  const int h = blockIdx.x, which = blockIdx.y;
  const int tid = threadIdx.x;

  __shared__ unsigned char keys8[NL_];
  __shared__ ushort M[64 * 130];
  __shared__ int btot[128];
  __shared__ int bscan[128];
  __shared__ ushort srt[NL_];

  const int* src = (which == 0 ? hq : hk) + h * NL_;
  for (int u = tid; u < 64 * 130 / 2; u += 256) ((uint*)M)[u] = 0u;
  for (int u = tid; u < NL_; u += 256) keys8[u] = (unsigned char)src[u];
  __syncthreads();

  if (tid < 64) {
    const int c = tid;
#pragma unroll 4
    for (int j = 0; j < 32; ++j) {
      const int u = c * 32 + j;
      if (u < NL_) ++M[c * 130 + keys8[u]];
    }
  }
  __syncthreads();

  if (tid < 128) {
    const int b = tid;
    int run = 0;
    for (int c = 0; c < 64; ++c) {
      const int v = M[c * 130 + b];
      M[c * 130 + b] = (ushort)run;
      run += v;
    }
    btot[b] = run;
    bscan[b] = run;
  }
  __syncthreads();

  for (int ofs = 1; ofs < 128; ofs <<= 1) {
    int v = 0;
    if (tid < 128 && tid >= ofs) v = bscan[tid - ofs];
    __syncthreads();
    if (tid < 128) bscan[tid] += v;
    __syncthreads();
  }

  int* dst = (which == 0 ? q_sort : k_sort) + h * NL_;
  if (tid < 64) {
    const int c = tid;
    for (int j = 0; j < 32; ++j) {
      const int u = c * 32 + j;
      if (u < NL_) {
        const int k = keys8[u];
        const int pos = (bscan[k] - btot[k]) + M[c * 130 + k];
        M[c * 130 + k] += 1;
        dst[pos] = u;
        srt[pos] = (ushort)u;
      }
    }
  }
  __syncthreads();

  if (which == 1) {
    const int s = tid;
    uint32_t a0 = 0u, a1 = 0u; tf2x32(0u, 1234u, a0, a1);
    uint32_t b0 = 0u, b1 = 0u; tf2x32(a0, a1, b0, b1);
    uint32_t c0 = 0u, c1 = 1u; tf2x32(a0, a1, c0, c1);
    const uint32_t j = (uint32_t)(h * SAMP_ + s);
    uint32_t h0 = 0u, h1 = j; tf2x32(b0, b1, h0, h1);
    uint32_t l0 = 0u, l1 = j; tf2x32(c0, c1, l0, l1);
    const uint32_t Hb = h0 ^ h1, Lb = l0 ^ l1;
    const uint32_t off = ((Hb % 2032u) * 16u + (Lb % 2032u)) % 2032u;
    samp_pos[h * SAMP_ + s] = (int)off;
    samp_orig[h * SAMP_ + s] = (int)srt[off];
  }
}

// =========================================================================
// MFMA flash attention, 128 q-rows/block, 128-key LDS tiles, reg prefetch.
// LDS: kk[128 keys][64 d] bf16 stride 144B; vv=V^T[64 d][128 keys] stride 272B;
// pbuf per wave [16 q][80B].
// =========================================================================
__global__ __launch_bounds__(256) void kern_attn_mfma(
    const float* __restrict__ Q, const ushort* __restrict__ Kb, const ushort* __restrict__ Vb,
    float* __restrict__ tail_attn, float* __restrict__ tail_lse,
    float* __restrict__ attn2, float* __restrict__ lse2) {
  __shared__ uint kk[4608];    // 18432 B
  __shared__ uint vv[4352];    // 17408 B
  __shared__ uint pbuf[1280];  // 5120 B

  const int b = blockIdx.x;
  const int tid = threadIdx.x;
  const int lane = tid & 63, w = tid >> 6;
  const int g = lane >> 4, q = lane & 15;

  int h, q0, qbase, kbase, ntiles, p2vh = 0, chunkc = 0;
  bool causal;
  if (b < 256) {                       // P2: 8 qt x 32 vh
    const int vh = b & 31; const int qt = b >> 5;
    h = vh >> 1; const int pp = vh & 1;
    q0 = qt * 128;
    qbase = SINK_ + pp * 2032 + 1016;
    kbase = SINK_ + pp * 2032;
    ntiles = 8; causal = false; p2vh = vh;
  } else {                             // P1: LPT descending qt
    const int u = b - 256; const int vh = u & 63;
    const int qt = 7 - (u >> 6);
    h = vh >> 2; chunkc = vh & 3;
    q0 = qt * 128;
    qbase = SINK_ + chunkc * 1016;
    kbase = qbase;
    ntiles = qt + 1; causal = true;
  }
  const size_t hN = (size_t)h * N_;
  const int qrowA = q0 + w * 16 + q;
  const int qrowB = qrowA + 64;
  const int qcA = min(qrowA, 1015), qcB = min(qrowB, 1015);
  const int qwA_lo = q0 + w * 16, qwmaxA = qwA_lo + 15;
  const int qwB_lo = qwA_lo + 64;

  B8 qbA0, qbA1, qbB0, qbB1;
  {
    const float4* qp = (const float4*)(Q + (hN + qbase + qcA) * 64);
    float4 a = qp[2*g], c = qp[2*g+1], d = qp[8+2*g], e = qp[8+2*g+1];
    qbA0.u = make_uint4(bfpack(a.x*SCALE_, a.y*SCALE_), bfpack(a.z*SCALE_, a.w*SCALE_),
                        bfpack(c.x*SCALE_, c.y*SCALE_), bfpack(c.z*SCALE_, c.w*SCALE_));
    qbA1.u = make_uint4(bfpack(d.x*SCALE_, d.y*SCALE_), bfpack(d.z*SCALE_, d.w*SCALE_),
                        bfpack(e.x*SCALE_, e.y*SCALE_), bfpack(e.z*SCALE_, e.w*SCALE_));
    const float4* qp2 = (const float4*)(Q + (hN + qbase + qcB) * 64);
    a = qp2[2*g]; c = qp2[2*g+1]; d = qp2[8+2*g]; e = qp2[8+2*g+1];
    qbB0.u = make_uint4(bfpack(a.x*SCALE_, a.y*SCALE_), bfpack(a.z*SCALE_, a.w*SCALE_),
                        bfpack(c.x*SCALE_, c.y*SCALE_), bfpack(c.z*SCALE_, c.w*SCALE_));
    qbB1.u = make_uint4(bfpack(d.x*SCALE_, d.y*SCALE_), bfpack(d.z*SCALE_, d.w*SCALE_),
                        bfpack(e.x*SCALE_, e.y*SCALE_), bfpack(e.z*SCALE_, e.w*SCALE_));
  }
  f32x4 oA[4] = {{0,0,0,0},{0,0,0,0},{0,0,0,0},{0,0,0,0}};
  f32x4 oB[4] = {{0,0,0,0},{0,0,0,0},{0,0,0,0},{0,0,0,0}};
  float mA = -INFINITY, sA_ = 0.f, mB = -INFINITY, sB_ = 0.f;

  // staging ids
  const int krow_l = tid >> 1, kpart = tid & 1;        // K: 2 thr/row, 64B each
  const int kpi = tid & 63;                            // V: key-pair
  const int vdb = (tid >> 6) * 16;                     // V: d-base (ushort)
  char* kdst = (char*)kk + krow_l * 144 + kpart * 64;
  char* vdst = (char*)vv + vdb * 272 + kpi * 4;
  const char* kq = (const char*)kk + q * 144 + g * 16;
  const char* vq = (const char*)vv + q * 272 + g * 16;
  char* pw = (char*)pbuf + w * 1280 + q * 80;

  const uint4 z4 = make_uint4(0, 0, 0, 0);
  uint4 kp0, kp1, kp2, kp3, va, va2, vb_, vb2;

#define LOADK(T) { const int kr = (T) * 128 + krow_l; \
    if (kr < 1016) { const uint4* s = (const uint4*)(Kb + (hN + kbase + kr) * 64 + kpart * 32); \
      kp0 = s[0]; kp1 = s[1]; kp2 = s[2]; kp3 = s[3]; } \
    else { kp0 = z4; kp1 = z4; kp2 = z4; kp3 = z4; } }
#define LOADV(T) { const int kr0 = (T) * 128 + 2 * kpi; \
    if (kr0 < 1016) { const uint4* s0 = (const uint4*)(Vb + (hN + kbase + kr0) * 64 + vdb); \
      const uint4* s1 = (const uint4*)(Vb + (hN + kbase + kr0 + 1) * 64 + vdb); \
      va = s0[0]; va2 = s0[1]; vb_ = s1[0]; vb2 = s1[1]; } \
    else { va = z4; va2 = z4; vb_ = z4; vb2 = z4; } }

  LOADK(0) LOADV(0)

  for (int t = 0; t < ntiles; ++t) {
    const int kt = t * 128;
    __syncthreads();
    // ---- stage from regs ----
    *(uint4*)kdst = kp0; *(uint4*)(kdst + 16) = kp1;
    *(uint4*)(kdst + 32) = kp2; *(uint4*)(kdst + 48) = kp3;
#define VP(BASE, JW, AW, BW) { \
    *(uint*)(vdst + (BASE + 2*(JW)) * 272) = (AW & 0xffffu) | (BW << 16); \
    *(uint*)(vdst + (BASE + 2*(JW) + 1) * 272) = (AW >> 16) | (BW & 0xffff0000u); }
    VP(0, 0, va.x, vb_.x) VP(0, 1, va.y, vb_.y) VP(0, 2, va.z, vb_.z) VP(0, 3, va.w, vb_.w)
    VP(8, 0, va2.x, vb2.x) VP(8, 1, va2.y, vb2.y) VP(8, 2, va2.z, vb2.z) VP(8, 3, va2.w, vb2.w)
#undef VP
    __syncthreads();
    if (t + 1 < ntiles) { LOADK(t + 1) LOADV(t + 1) }

    // ---- compute two 64-key halves ----
#pragma unroll
    for (int u2 = 0; u2 < 2; ++u2) {
      const int hb = kt + u2 * 64;
      const bool dA = !(causal && hb > qwmaxA);
      f32x4 sA[4], sB[4];
#pragma unroll
      for (int st = 0; st < 4; ++st) {
        B8 ka, kb2;
        ka.u  = *(const uint4*)(kq + (u2 * 64 + st * 16) * 144);
        kb2.u = *(const uint4*)(kq + (u2 * 64 + st * 16) * 144 + 64);
        if (dA) {
          f32x4 acc = {0.f, 0.f, 0.f, 0.f};
          acc = mfma16(ka, qbA0, acc); acc = mfma16(kb2, qbA1, acc);
          sA[st] = acc;
        }
        f32x4 acc2 = {0.f, 0.f, 0.f, 0.f};
        acc2 = mfma16(ka, qbB0, acc2); acc2 = mfma16(kb2, qbB1, acc2);
        sB[st] = acc2;
      }

      if (causal) {
        const int kb0 = hb + 4 * g;
        if (dA && hb + 63 > qwA_lo) {
#pragma unroll
          for (int st = 0; st < 4; ++st)
#pragma unroll
            for (int r = 0; r < 4; ++r)
              if (kb0 + st * 16 + r > qrowA) sA[st][r] = NEGBIG_;
        }
        if (hb + 63 > qwB_lo) {
#pragma unroll
          for (int st = 0; st < 4; ++st)
#pragma unroll
            for (int r = 0; r < 4; ++r)
              if (kb0 + st * 16 + r > qrowB) sB[st][r] = NEGBIG_;
        }
      } else if (hb + 63 >= 1016) {
        const int kb0 = hb + 4 * g;
#pragma unroll
        for (int st = 0; st < 4; ++st)
#pragma unroll
          for (int r = 0; r < 4; ++r)
            if (kb0 + st * 16 + r >= 1016) { sA[st][r] = NEGBIG_; sB[st][r] = NEGBIG_; }
      }

      if (dA) {
        online_sm(sA, mA, sA_, oA);
        // PV frag A
#pragma unroll
        for (int hk2 = 0; hk2 < 2; ++hk2) {
          const f32x4 pa = sA[2 * hk2], pc = sA[2 * hk2 + 1];
          *(uint2*)(pw + 8 * g) = make_uint2(bfpack(pa[0], pa[1]), bfpack(pa[2], pa[3]));
          *(uint2*)(pw + 32 + 8 * g) = make_uint2(bfpack(pc[0], pc[1]), bfpack(pc[2], pc[3]));
          B8 pf, vf;
          pf.u = *(const uint4*)(pw + g * 16);
          const int vb3 = u2 * 128 + hk2 * 64;
          vf.u = *(const uint4*)(vq + 0 * 4352 + vb3); oA[0] = mfma16(vf, pf, oA[0]);
          vf.u = *(const uint4*)(vq + 1 * 4352 + vb3); oA[1] = mfma16(vf, pf, oA[1]);
          vf.u = *(const uint4*)(vq + 2 * 4352 + vb3); oA[2] = mfma16(vf, pf, oA[2]);
          vf.u = *(const uint4*)(vq + 3 * 4352 + vb3); oA[3] = mfma16(vf, pf, oA[3]);
        }
      }
      online_sm(sB, mB, sB_, oB);
#pragma unroll
      for (int hk2 = 0; hk2 < 2; ++hk2) {
        const f32x4 pa = sB[2 * hk2], pc = sB[2 * hk2 + 1];
        *(uint2*)(pw + 8 * g) = make_uint2(bfpack(pa[0], pa[1]), bfpack(pa[2], pa[3]));
        *(uint2*)(pw + 32 + 8 * g) = make_uint2(bfpack(pc[0], pc[1]), bfpack(pc[2], pc[3]));
        B8 pf, vf;
        pf.u = *(const uint4*)(pw + g * 16);
        const int vb3 = u2 * 128 + hk2 * 64;
        vf.u = *(const uint4*)(vq + 0 * 4352 + vb3); oB[0] = mfma16(vf, pf, oB[0]);
        vf.u = *(const uint4*)(vq + 1 * 4352 + vb3); oB[1] = mfma16(vf, pf, oB[1]);
        vf.u = *(const uint4*)(vq + 2 * 4352 + vb3); oB[2] = mfma16(vf, pf, oB[2]);
        vf.u = *(const uint4*)(vq + 3 * 4352 + vb3); oB[3] = mfma16(vf, pf, oB[3]);
      }
    }
  }
#undef LOADK
#undef LOADV

  // ---- epilogue ----
#pragma unroll
  for (int fr = 0; fr < 2; ++fr) {
    const int qrow = fr == 0 ? qrowA : qrowB;
    if (qrow >= 1016) continue;
    f32x4* o = fr == 0 ? oA : oB;
    const float m = fr == 0 ? mA : mB;
    const float ss = fr == 0 ? sA_ : sB_;
    const float lse = m + __logf(ss);
    const float inv = 1.f / ss;
    if (causal) {
      const int trow = chunkc * 1016 + qrow;
      float* tp = tail_attn + ((size_t)h * NT_ + trow) * 64;
      *(f32x4*)(tp +  0 + 4*g) = o[0] * inv;
      *(f32x4*)(tp + 16 + 4*g) = o[1] * inv;
      *(f32x4*)(tp + 32 + 4*g) = o[2] * inv;
      *(f32x4*)(tp + 48 + 4*g) = o[3] * inv;
      if (lane < 16) tail_lse[h * NT_ + trow] = lse;
    } else {
      float* tp = attn2 + ((size_t)p2vh * 1016 + qrow) * 64;
      *(f32x4*)(tp +  0 + 4*g) = o[0] * inv;
      *(f32x4*)(tp + 16 + 4*g) = o[1] * inv;
      *(f32x4*)(tp + 32 + 4*g) = o[2] * inv;
      *(f32x4*)(tp + 48 + 4*g) = o[3] * inv;
      if (lane < 16) lse2[p2vh * 1016 + qrow] = lse;
    }
  }
}

// ---------------- merge P2 into tail ----------------
__global__ __launch_bounds__(128) void kern_merge2(float* __restrict__ tail_attn, float* __restrict__ tail_lse,
                                                   const float* __restrict__ attn2, const float* __restrict__ lse2) {
  const int vh = blockIdx.x;
  const int i = blockIdx.y * 128 + (int)threadIdx.x;
  if (i >= 1016) return;
  const int h = vh >> 1, pp = vh & 1;
  const int t = pp * 2032 + 1016 + i;
  const float l2 = lse2[vh * 1016 + i];
  float* tlp = tail_lse + h * NT_ + t;
  const float bl = *tlp;
  const float c = 1.f / (1.f + __expf(l2 - bl));
  const float4* ap = (const float4*)(attn2 + ((size_t)vh * 1016 + i) * 64);
  float4* tp = (float4*)(tail_attn + ((size_t)h * NT_ + t) * 64);
#pragma unroll
  for (int d = 0; d < 16; ++d) {
    const float4 bd = tp[d], a2 = ap[d];
    tp[d] = make_float4(c * bd.x + (1.f - c) * a2.x,
                        c * bd.y + (1.f - c) * a2.y,
                        c * bd.z + (1.f - c) * a2.z,
                        c * bd.w + (1.f - c) * a2.w);
  }
  *tlp = logaddexpf_(bl, l2);
}

// =========================================================================
// MFMA LSH attention (64-key tiles, upfront indices + reg prefetch).
// =========================================================================
__global__ __launch_bounds__(256) void kern_lsh_mfma(
    const float* __restrict__ Q, const ushort* __restrict__ Kb, const ushort* __restrict__ Vb,
    const int* __restrict__ q_sort, const int* __restrict__ k_sort,
    const int* __restrict__ samp_pos, const int* __restrict__ samp_orig,
    float* __restrict__ tail_attn, float* __restrict__ tail_lse) {
  __shared__ uint kk[2304];    // 64*144
  __shared__ uint vv[2304];    // 64 d rows * 144B
  __shared__ uint pbuf[1280];
  __shared__ float bias_s[64];

  const int b = blockIdx.x;
  const int h = b >> 4, pt = b & 15;
  const int tid = threadIdx.x;
  const int lane = tid & 63, w = tid >> 6;
  const int g = lane >> 4, q = lane & 15;
  const int blkq = pt >> 1;
  const size_t hN = (size_t)h * N_;

  const int pA = pt * 128 + w * 16 + q;
  const int pB = pA + 64;
  const int qiA = q_sort[h * NL_ + min(pA, NL_ - 1)];
  const int qiB = q_sort[h * NL_ + min(pB, NL_ - 1)];

  // ---- upfront gather indices ----
  const int skey = tid >> 2, kpart = tid & 3;
  const int kpi = tid & 31, vdb = (tid >> 5) * 8;
  int kidx[8], vi0[8], vi1[8];
#pragma unroll
  for (int t = 0; t < 8; ++t) {
    if (t < 4) {
      const int slot = blkq * 256 + t * 64 + skey;
      kidx[t] = (slot < NL_) ? k_sort[h * NL_ + slot] : -1;
      const int s0 = blkq * 256 + t * 64 + 2 * kpi;
      vi0[t] = (s0 < NL_) ? k_sort[h * NL_ + s0] : -1;
      vi1[t] = (s0 + 1 < NL_) ? k_sort[h * NL_ + s0 + 1] : -1;
    } else {
      kidx[t] = samp_orig[h * SAMP_ + (t - 4) * 64 + skey];
      const int si = (t - 4) * 64 + 2 * kpi;
      vi0[t] = samp_orig[h * SAMP_ + si];
      vi1[t] = samp_orig[h * SAMP_ + si + 1];
    }
  }
  float biasr[4];
  if (tid < 64) {
#pragma unroll
    for (int j = 0; j < 4; ++j)
      biasr[j] = ((samp_pos[h * SAMP_ + j * 64 + tid] >> 8) == blkq) ? NEGBIG_ : LOGOFF_;
  }

  B8 qbA0, qbA1, qbB0, qbB1;
  {
    const float4* qp = (const float4*)(Q + (hN + SINK_ + NL_ + qiA) * 64);
    float4 a = qp[2*g], c = qp[2*g+1], d = qp[8+2*g], e = qp[8+2*g+1];
    qbA0.u = make_uint4(bfpack(a.x*SCALE_, a.y*SCALE_), bfpack(a.z*SCALE_, a.w*SCALE_),
                        bfpack(c.x*SCALE_, c.y*SCALE_), bfpack(c.z*SCALE_, c.w*SCALE_));
    qbA1.u = make_uint4(bfpack(d.x*SCALE_, d.y*SCALE_), bfpack(d.z*SCALE_, d.w*SCALE_),
                        bfpack(e.x*SCALE_, e.y*SCALE_), bfpack(e.z*SCALE_, e.w*SCALE_));
    const float4* qp2 = (const float4*)(Q + (hN + SINK_ + NL_ + qiB) * 64);
    a = qp2[2*g]; c = qp2[2*g+1]; d = qp2[8+2*g]; e = qp2[8+2*g+1];
    qbB0.u = make_uint4(bfpack(a.x*SCALE_, a.y*SCALE_), bfpack(a.z*SCALE_, a.w*SCALE_),
                        bfpack(c.x*SCALE_, c.y*SCALE_), bfpack(c.z*SCALE_, c.w*SCALE_));
    qbB1.u = make_uint4(bfpack(d.x*SCALE_, d.y*SCALE_), bfpack(d.z*SCALE_, d.w*SCALE_),
                        bfpack(e.x*SCALE_, e.y*SCALE_), bfpack(e.z*SCALE_, e.w*SCALE_));
  }
  f32x4 oA[4] = {{0,0,0,0},{0,0,0,0},{0,0,0,0},{0,0,0,0}};
  f32x4 oB[4] = {{0,0,0,0},{0,0,0,0},{0,0,0,0},{0,0,0,0}};
  float mA = -INFINITY, sA_ = 0.f, mB = -INFINITY, sB_ = 0.f;

  char* kdst = (char*)kk + skey * 144 + kpart * 32;
  char* vdst = (char*)vv + vdb * 144 + kpi * 4;
  const char* kq = (const char*)kk + q * 144 + g * 16;
  const char* vq = (const char*)vv + q * 144 + g * 16;
  char* pw = (char*)pbuf + w * 1280 + q * 80;

  const uint4 z4 = make_uint4(0, 0, 0, 0);
  uint4 kp0, kp1, va, vb_;

#define LLOADK(T) { const int kr = kidx[T]; \
    if (kr >= 0) { const uint4* s = (const uint4*)(Kb + (hN + SINK_ + kr) * 64 + kpart * 16); \
      kp0 = s[0]; kp1 = s[1]; } else { kp0 = z4; kp1 = z4; } }
#define LLOADV(T) { const int r0 = vi0[T], r1 = vi1[T]; \
    va  = (r0 >= 0) ? *(const uint4*)(Vb + (hN + SINK_ + r0) * 64 + vdb) : z4; \
    vb_ = (r1 >= 0) ? *(const uint4*)(Vb + (hN + SINK_ + r1) * 64 + vdb) : z4; }

  LLOADK(0) LLOADV(0)

  for (int t = 0; t < 8; ++t) {
    __syncthreads();
    *(uint4*)kdst = kp0; *(uint4*)(kdst + 16) = kp1;
#define VP(JW, AW, BW) { \
    *(uint*)(vdst + (2*(JW)) * 144) = (AW & 0xffffu) | (BW << 16); \
    *(uint*)(vdst + (2*(JW) + 1) * 144) = (AW >> 16) | (BW & 0xffff0000u); }
    VP(0, va.x, vb_.x) VP(1, va.y, vb_.y) VP(2, va.z, vb_.z) VP(3, va.w, vb_.w)
#undef VP
    if (t >= 4 && tid < 64) bias_s[tid] = biasr[t - 4];
    __syncthreads();
    if (t + 1 < 8) { LLOADK(t + 1) LLOADV(t + 1) }

    f32x4 sA[4], sB[4];
#pragma unroll
    for (int st = 0; st < 4; ++st) {
      B8 ka, kb2;
      ka.u  = *(const uint4*)(kq + (st * 16) * 144);
      kb2.u = *(const uint4*)(kq + (st * 16) * 144 + 64);
      f32x4 acc = {0.f, 0.f, 0.f, 0.f};
      acc = mfma16(ka, qbA0, acc); acc = mfma16(kb2, qbA1, acc);
      sA[st] = acc;
      f32x4 acc2 = {0.f, 0.f, 0.f, 0.f};
      acc2 = mfma16(ka, qbB0, acc2); acc2 = mfma16(kb2, qbB1, acc2);
      sB[st] = acc2;
    }
    if (t >= 4) {
      const f32x4* bp = (const f32x4*)bias_s;
#pragma unroll
      for (int st = 0; st < 4; ++st) {
        sA[st] = sA[st] + bp[st * 4 + g];
        sB[st] = sB[st] + bp[st * 4 + g];
      }
    }

    online_sm(sA, mA, sA_, oA);
    pv_step144(sA, oA, vq, pw, g);
    online_sm(sB, mB, sB_, oB);
    pv_step144(sB, oB, vq, pw, g);
  }
#undef LLOADK
#undef LLOADV

#pragma unroll
  for (int fr = 0; fr < 2; ++fr) {
    const int p = fr == 0 ? pA : pB;
    if (p >= NL_) continue;
    const int qi = fr == 0 ? qiA : qiB;
    f32x4* o = fr == 0 ? oA : oB;
    const float m = fr == 0 ? mA : mB;
    const float ss = fr == 0 ? sA_ : sB_;
    const float un = m + __logf(ss);
    const float inv = 1.f / ss;
    const int trow = NL_ + qi;
    float* tlp = tail_lse + h * NT_ + trow;
    const float bd = *tlp;
    const float c2 = 1.f / (1.f + __expf(un - bd));
    const float w2 = inv * (1.f - c2);
    float* tp = tail_attn + ((size_t)h * NT_ + trow) * 64;
    f32x4 t0 = *(f32x4*)(tp +  0 + 4*g);
    f32x4 t1 = *(f32x4*)(tp + 16 + 4*g);
    f32x4 t2 = *(f32x4*)(tp + 32 + 4*g);
    f32x4 t3 = *(f32x4*)(tp + 48 + 4*g);
    *(f32x4*)(tp +  0 + 4*g) = t0 * c2 + o[0] * w2;
    *(f32x4*)(tp + 16 + 4*g) = t1 * c2 + o[1] * w2;
    *(f32x4*)(tp + 32 + 4*g) = t2 * c2 + o[2] * w2;
    *(f32x4*)(tp + 48 + 4*g) = t3 * c2 + o[3] * w2;
    if (lane < 16) *tlp = logaddexpf_(bd, un);
  }
}

// ---------------- sink prefix + final merge ----------------
__global__ __launch_bounds__(256) void kern_final(const float* __restrict__ Q, const float* __restrict__ K,
                                                  const float* __restrict__ V,
                                                  const float* __restrict__ tail_attn, const float* __restrict__ tail_lse,
                                                  float* __restrict__ out) {
  const int h = blockIdx.x;
  const int r = blockIdx.y * 256 + (int)threadIdx.x;

  __shared__ float4 kk[SINK_ * 16];
  __shared__ float4 vv[SINK_ * 16];
  for (int u = threadIdx.x; u < SINK_ * 16; u += 256) {
    const int row = u >> 4, d4 = u & 15;
    kk[u] = ((const float4*)(K + ((size_t)h * N_ + row) * 64))[d4];
    vv[u] = ((const float4*)(V + ((size_t)h * N_ + row) * 64))[d4];
  }
  __syncthreads();

  float4 q4[16], acc[16];
  const float4* qp = (const float4*)(Q + ((size_t)h * N_ + r) * 64);
#pragma unroll
  for (int d = 0; d < 16; ++d) { q4[d] = qp[d]; acc[d] = make_float4(0.f, 0.f, 0.f, 0.f); }

  float m = -INFINITY, ssum = 0.f;
  const int nk = min(SINK_, r + 1);
  for (int j = 0; j < nk; ++j) {
    float s = 0.f;
#pragma unroll
    for (int d = 0; d < 16; ++d) {
      float4 x = q4[d], y = kk[j * 16 + d];
      s = fmaf(x.x, y.x, s); s = fmaf(x.y, y.y, s);
      s = fmaf(x.z, y.z, s); s = fmaf(x.w, y.w, s);
    }
    s *= SCALE_;
    const float nm = fmaxf(m, s);
    const float f = __expf(m - nm), wgt = __expf(s - nm);
    ssum = ssum * f + wgt;
    const float4* v4 = &vv[j * 16];
#pragma unroll
    for (int d = 0; d < 16; ++d) {
      acc[d].x = acc[d].x * f + wgt * v4[d].x;
      acc[d].y = acc[d].y * f + wgt * v4[d].y;
      acc[d].z = acc[d].z * f + wgt * v4[d].z;
      acc[d].w = acc[d].w * f + wgt * v4[d].w;
    }
    m = nm;
  }
  const float pl = m + __logf(ssum);
  const float inv = 1.f / ssum;
  float4* op = (float4*)(out + ((size_t)h * N_ + r) * 64);
  if (r < SINK_) {
#pragma unroll
    for (int d = 0; d < 16; ++d)
      op[d] = make_float4(acc[d].x * inv, acc[d].y * inv, acc[d].z * inv, acc[d].w * inv);
  } else {
    const int t = r - SINK_;
    const float tl = tail_lse[h * NT_ + t];
    const float cc = 1.f / (1.f + __expf(tl - pl));
    const float4* tp = (const float4*)(tail_attn + ((size_t)h * NT_ + t) * 64);
#pragma unroll
    for (int d = 0; d < 16; ++d) {
      const float4 tv = tp[d];
      op[d] = make_float4(cc * acc[d].x * inv + (1.f - cc) * tv.x,
                          cc * acc[d].y * inv + (1.f - cc) * tv.y,
                          cc * acc[d].z * inv + (1.f - cc) * tv.z,
                          cc * acc[d].w * inv + (1.f - cc) * tv.w);
    }
  }
}

// ---------------- host ----------------
extern "C" void kernel_launch(void* const* d_in, const int* in_sizes, int n_in,
                              void* d_out, int out_size, void* d_ws, size_t ws_size,
                              hipStream_t stream) {
  (void)in_sizes; (void)n_in; (void)out_size; (void)ws_size;
  const float* Q = (const float*)d_in[0];
  const float* K = (const float*)d_in[1];
  const float* V = (const float*)d_in[2];
  const float* proj = (const float*)d_in[3];
  float* out = (float*)d_out;

  char* w = (char*)d_ws;
  auto carve = [&](size_t bytes) { char* p = w; w += (bytes + 255) & ~(size_t)255; return p; };
  float* tail_attn = (float*)carve((size_t)H_ * NT_ * 64 * sizeof(float));
  float* tail_lse  = (float*)carve((size_t)H_ * NT_ * sizeof(float));
  float* attn2     = (float*)carve((size_t)32 * 1016 * 64 * sizeof(float));
  float* lse2      = (float*)carve((size_t)32 * 1016 * sizeof(float));
  ushort* Kb     = (ushort*)carve((size_t)H_ * N_ * 64 * sizeof(ushort));
  ushort* Vb     = (ushort*)carve((size_t)H_ * N_ * 64 * sizeof(ushort));
  int* hq        = (int*)carve((size_t)H_ * NL_ * sizeof(int));
  int* hk        = (int*)carve((size_t)H_ * NL_ * sizeof(int));
  int* q_sort    = (int*)carve((size_t)H_ * NL_ * sizeof(int));
  int* k_sort    = (int*)carve((size_t)H_ * NL_ * sizeof(int));
  int* samp_pos  = (int*)carve((size_t)H_ * SAMP_ * sizeof(int));
  int* samp_orig = (int*)carve((size_t)H_ * SAMP_ * sizeof(int));

  kern_packhash<<<dim3(4352), 256, 0, stream>>>(K, V, Q, proj, Kb, Vb, hq, hk);
  kern_sortsamp<<<dim3(H_, 2), 256, 0, stream>>>(hq, hk, q_sort, k_sort, samp_pos, samp_orig);
  kern_attn_mfma<<<dim3(768), 256, 0, stream>>>(Q, Kb, Vb, tail_attn, tail_lse, attn2, lse2);
  kern_merge2<<<dim3(32, 8), 128, 0, stream>>>(tail_attn, tail_lse, attn2, lse2);
  kern_lsh_mfma<<<dim3(256), 256, 0, stream>>>(Q, Kb, Vb, q_sort, k_sort, samp_pos, samp_orig,
                                               tail_attn, tail_lse);
  kern_final<<<dim3(H_, 16), 256, 0, stream>>>(Q, K, V, tail_attn, tail_lse, out);
}

// Round 7
// 159.036 us; speedup vs baseline: 19.6451x; 1.0523x over previous
//
#include <hip/hip_runtime.h>
#include <hip/hip_bf16.h>
#include <math.h>
#include <stdint.h>

#define H_ 16
#define N_ 4096
#define NT_ 4064        // tail length
#define NL_ 2032        // LSH segment length
#define SINK_ 32
#define SAMP_ 256
#define SCALE_ 0.125f
#define QSCALE_ 0.18033688f    // 0.125 * log2(e)  -> scores in log2 domain
#define M0L2_ 11.5415606f      // 8 * log2(e)      -> fixed softmax offset (log2 domain)
#define M0_ 8.0f               // natural-log offset for lse reconstruction
#define NEGBIG_ -3.0e38f
#define LOGOFF_L2_ 2.9886841f  // log2(2032/256)

typedef unsigned int uint;
typedef unsigned short ushort;
typedef short bf16x8 __attribute__((ext_vector_type(8)));
typedef float f32x4 __attribute__((ext_vector_type(4)));

union B8 { uint4 u; bf16x8 b; };

__device__ __forceinline__ f32x4 mfma16(const B8& a, const B8& b, f32x4 c) {
  return __builtin_amdgcn_mfma_f32_16x16x32_bf16(a.b, b.b, c, 0, 0, 0);
}

// manual RNE pack (used in pack kernel / Q frags; not hot)
__device__ __forceinline__ uint bfpack(float a, float b) {
  uint ua = __float_as_uint(a), ub = __float_as_uint(b);
  ua += 0x7fffu + ((ua >> 16) & 1u);
  ub += 0x7fffu + ((ub >> 16) & 1u);
  return (ua >> 16) | (ub & 0xffff0000u);
}

// compiler-cast pack (hot path; RNE, compiler may fuse to v_cvt_pk_bf16_f32)
__device__ __forceinline__ uint cvtpk(float a, float b) {
  union { __hip_bfloat162 h; uint u; } r;
  r.h.x = __float2bfloat16(a);
  r.h.y = __float2bfloat16(b);
  return r.u;
}

__device__ __forceinline__ float logaddexpf_(float a, float b) {
  float mx = fmaxf(a, b);
  return mx + __logf(__expf(a - mx) + __expf(b - mx));
}

__device__ __forceinline__ uint32_t rotl32_(uint32_t v, uint32_t d) {
  return (v << d) | (v >> (32u - d));
}

// JAX threefry2x32 (20 rounds)
__device__ inline void tf2x32(uint32_t k0, uint32_t k1, uint32_t& x0, uint32_t& x1) {
  uint32_t ks2 = k0 ^ k1 ^ 0x1BD11BDAu;
  x0 += k0; x1 += k1;
#define TFR(r) { x0 += x1; x1 = rotl32_(x1, r); x1 ^= x0; }
  TFR(13u) TFR(15u) TFR(26u) TFR(6u)
  x0 += k1;  x1 += ks2 + 1u;
  TFR(17u) TFR(29u) TFR(16u) TFR(24u)
  x0 += ks2; x1 += k0 + 2u;
  TFR(13u) TFR(15u) TFR(26u) TFR(6u)
  x0 += k0;  x1 += k1 + 3u;
  TFR(17u) TFR(29u) TFR(16u) TFR(24u)
  x0 += k1;  x1 += ks2 + 4u;
  TFR(13u) TFR(15u) TFR(26u) TFR(6u)
  x0 += ks2; x1 += k0 + 5u;
#undef TFR
}

// ---------------- fixed-offset softmax: s (log2 domain, pre-biased) -> P = 2^s ----------------
__device__ __forceinline__ void nomax_sm(f32x4 s[4], float& ssum) {
#pragma unroll
  for (int st = 0; st < 4; ++st)
#pragma unroll
    for (int r = 0; r < 4; ++r) {
      s[st][r] = __builtin_exp2f(s[st][r]);
      ssum += s[st][r];
    }
}

// ---------------- PV: P round-trip via per-wave pbuf, V^T rows stride 144 ----------------
__device__ __forceinline__ void pv_go(const f32x4 s[4], f32x4 o[4],
                                      const char* vbase, char* pw, int g) {
#pragma unroll
  for (int hk2 = 0; hk2 < 2; ++hk2) {
    const f32x4 pa = s[2 * hk2], pc = s[2 * hk2 + 1];
    *(uint2*)(pw + 8 * g)      = make_uint2(cvtpk(pa[0], pa[1]), cvtpk(pa[2], pa[3]));
    *(uint2*)(pw + 32 + 8 * g) = make_uint2(cvtpk(pc[0], pc[1]), cvtpk(pc[2], pc[3]));
    B8 pf, vf;
    pf.u = *(const uint4*)(pw + g * 16);
    vf.u = *(const uint4*)(vbase + 0 * 2304 + hk2 * 64); o[0] = mfma16(vf, pf, o[0]);
    vf.u = *(const uint4*)(vbase + 1 * 2304 + hk2 * 64); o[1] = mfma16(vf, pf, o[1]);
    vf.u = *(const uint4*)(vbase + 2 * 2304 + hk2 * 64); o[2] = mfma16(vf, pf, o[2]);
    vf.u = *(const uint4*)(vbase + 3 * 2304 + hk2 * 64); o[3] = mfma16(vf, pf, o[3]);
  }
}

// ---------------- fused pack (bf16 K/V) + hash ----------------
__global__ __launch_bounds__(256) void kern_packhash(
    const float* __restrict__ K, const float* __restrict__ V, const float* __restrict__ Q,
    const float* __restrict__ proj,
    ushort* __restrict__ Kb, ushort* __restrict__ Vb,
    int* __restrict__ hq, int* __restrict__ hk) {
  const int bb = blockIdx.x;
  if (bb < 4096) {               // pack
    const int which = bb >> 11;
    const size_t idx = ((size_t)(bb & 2047)) * 256 + threadIdx.x;
    const float4* s = (const float4*)((which == 0 ? K : V) + idx * 8);
    float4 f0 = s[0], f1 = s[1];
    uint4 p = make_uint4(bfpack(f0.x, f0.y), bfpack(f0.z, f0.w),
                         bfpack(f1.x, f1.y), bfpack(f1.z, f1.w));
    *(uint4*)((which == 0 ? Kb : Vb) + idx * 8) = p;
    return;
  }
  // hash
  const int u = bb - 4096;
  const int h = u & 15, tile = (u >> 4) & 7, which = u >> 7;
  __shared__ float pr[448];
  for (int t = threadIdx.x; t < 448; t += 256) pr[t] = proj[t];
  __syncthreads();
  const int i = tile * 256 + (int)threadIdx.x;
  if (i >= NL_) return;
  const int orig = (which == 0) ? (SINK_ + NL_ + i) : (SINK_ + i);
  const float4* x = (const float4*)((which == 0 ? Q : K) + ((size_t)h * N_ + orig) * 64);
  float xr[64];
#pragma unroll
  for (int d = 0; d < 16; ++d) {
    float4 g = x[d];
    xr[4*d+0] = g.x; xr[4*d+1] = g.y; xr[4*d+2] = g.z; xr[4*d+3] = g.w;
  }
  int bin = 0;
#pragma unroll
  for (int r = 0; r < 7; ++r) {
    float acc = 0.f;
#pragma unroll
    for (int d = 0; d < 64; ++d) acc = fmaf(xr[d], pr[d * 7 + r], acc);
    if (acc > 0.f) bin |= (1 << r);
  }
  const int g = bin ^ (bin >> 1);   // _PERM = Gray code
  (which == 0 ? hq : hk)[h * NL_ + i] = g;
}

// ---------------- chunked stable counting sort + threefry sample ----------------
__global__ __launch_bounds__(256) void kern_sortsamp(
    const int* __restrict__ hq, const int* __restrict__ hk,
    int* __restrict__ q_sort, int* __restrict__ k_sort,
    int* __restrict__ samp_pos, int* __restrict__ samp_orig) {
  const int h = blockIdx.x, which = blockIdx.y;
  const int tid = threadIdx.x;

  __shared__ unsigned char keys8[NL_];
  __shared__ ushort M[64 * 130];
  __shared__ int btot[128];
  __shared__ int bscan[128];
  __shared__ ushort srt[NL_];

  const int* src = (which == 0 ? hq : hk) + h * NL_;
  for (int u = tid; u < 64 * 130 / 2; u += 256) ((uint*)M)[u] = 0u;
  for (int u = tid; u < NL_; u += 256) keys8[u] = (unsigned char)src[u];
  __syncthreads();

  if (tid < 64) {
    const int c = tid;
#pragma unroll 4
    for (int j = 0; j < 32; ++j) {
      const int u = c * 32 + j;
      if (u < NL_) ++M[c * 130 + keys8[u]];
    }
  }
  __syncthreads();

  if (tid < 128) {
    const int b = tid;
    int run = 0;
    for (int c = 0; c < 64; ++c) {
      const int v = M[c * 130 + b];
      M[c * 130 + b] = (ushort)run;
      run += v;
    }
    btot[b] = run;
    bscan[b] = run;
  }
  __syncthreads();

  for (int ofs = 1; ofs < 128; ofs <<= 1) {
    int v = 0;
    if (tid < 128 && tid >= ofs) v = bscan[tid - ofs];
    __syncthreads();
    if (tid < 128) bscan[tid] += v;
    __syncthreads();
  }

  int* dst = (which == 0 ? q_sort : k_sort) + h * NL_;
  if (tid < 64) {
    const int c = tid;
    for (int j = 0; j < 32; ++j) {
      const int u = c * 32 + j;
      if (u < NL_) {
        const int k = keys8[u];
        const int pos = (bscan[k] - btot[k]) + M[c * 130 + k];
        M[c * 130 + k] += 1;
        dst[pos] = u;
        srt[pos] = (ushort)u;
      }
    }
  }
  __syncthreads();

  if (which == 1) {
    const int s = tid;
    uint32_t a0 = 0u, a1 = 0u; tf2x32(0u, 1234u, a0, a1);
    uint32_t b0 = 0u, b1 = 0u; tf2x32(a0, a1, b0, b1);
    uint32_t c0 = 0u, c1 = 1u; tf2x32(a0, a1, c0, c1);
    const uint32_t j = (uint32_t)(h * SAMP_ + s);
    uint32_t h0 = 0u, h1 = j; tf2x32(b0, b1, h0, h1);
    uint32_t l0 = 0u, l1 = j; tf2x32(c0, c1, l0, l1);
    const uint32_t Hb = h0 ^ h1, Lb = l0 ^ l1;
    const uint32_t off = ((Hb % 2032u) * 16u + (Lb % 2032u)) % 2032u;
    samp_pos[h * SAMP_ + s] = (int)off;
    samp_orig[h * SAMP_ + s] = (int)srt[off];
  }
}

// =========================================================================
// MFMA flash attention, 128 q-rows/block, 128-key LDS tiles, reg prefetch,
// fixed-offset (no-max) softmax in exp2 domain.
// LDS: kk[128 keys][64 d] stride 144B; vv = 2 halves of V^T[64 d][64 keys]
// stride 144B (keys 0..63 / 64..127); pbuf per wave [16 q][80B].
// =========================================================================
__global__ __launch_bounds__(256) void kern_attn_mfma(
    const float* __restrict__ Q, const ushort* __restrict__ Kb, const ushort* __restrict__ Vb,
    float* __restrict__ tail_attn, float* __restrict__ tail_lse,
    float* __restrict__ attn2, float* __restrict__ lse2) {
  __shared__ uint kk[4608];    // 18432 B
  __shared__ uint vv[4608];    // 18432 B (two 9216 halves)
  __shared__ uint pbuf[1280];  // 5120 B

  const int b = blockIdx.x;
  const int tid = threadIdx.x;
  const int lane = tid & 63, w = tid >> 6;
  const int g = lane >> 4, q = lane & 15;

  int h, q0, qbase, kbase, ntiles, p2vh = 0, chunkc = 0;
  bool causal;
  if (b < 256) {                       // P2: 8 qt x 32 vh
    const int vh = b & 31; const int qt = b >> 5;
    h = vh >> 1; const int pp = vh & 1;
    q0 = qt * 128;
    qbase = SINK_ + pp * 2032 + 1016;
    kbase = SINK_ + pp * 2032;
    ntiles = 8; causal = false; p2vh = vh;
  } else {                             // P1: LPT descending qt
    const int u = b - 256; const int vh = u & 63;
    const int qt = 7 - (u >> 6);
    h = vh >> 2; chunkc = vh & 3;
    q0 = qt * 128;
    qbase = SINK_ + chunkc * 1016;
    kbase = qbase;
    ntiles = qt + 1; causal = true;
  }
  const size_t hN = (size_t)h * N_;
  const int qrowA = q0 + w * 16 + q;
  const int qrowB = qrowA + 64;
  const int qcA = min(qrowA, 1015), qcB = min(qrowB, 1015);
  const int qwA_lo = q0 + w * 16, qwmaxA = qwA_lo + 15;
  const int qwB_lo = qwA_lo + 64;

  B8 qbA0, qbA1, qbB0, qbB1;
  {
    const float4* qp = (const float4*)(Q + (hN + qbase + qcA) * 64);
    float4 a = qp[2*g], c = qp[2*g+1], d = qp[8+2*g], e = qp[8+2*g+1];
    qbA0.u = make_uint4(bfpack(a.x*QSCALE_, a.y*QSCALE_), bfpack(a.z*QSCALE_, a.w*QSCALE_),
                        bfpack(c.x*QSCALE_, c.y*QSCALE_), bfpack(c.z*QSCALE_, c.w*QSCALE_));
    qbA1.u = make_uint4(bfpack(d.x*QSCALE_, d.y*QSCALE_), bfpack(d.z*QSCALE_, d.w*QSCALE_),
                        bfpack(e.x*QSCALE_, e.y*QSCALE_), bfpack(e.z*QSCALE_, e.w*QSCALE_));
    const float4* qp2 = (const float4*)(Q + (hN + qbase + qcB) * 64);
    a = qp2[2*g]; c = qp2[2*g+1]; d = qp2[8+2*g]; e = qp2[8+2*g+1];
    qbB0.u = make_uint4(bfpack(a.x*QSCALE_, a.y*QSCALE_), bfpack(a.z*QSCALE_, a.w*QSCALE_),
                        bfpack(c.x*QSCALE_, c.y*QSCALE_), bfpack(c.z*QSCALE_, c.w*QSCALE_));
    qbB1.u = make_uint4(bfpack(d.x*QSCALE_, d.y*QSCALE_), bfpack(d.z*QSCALE_, d.w*QSCALE_),
                        bfpack(e.x*QSCALE_, e.y*QSCALE_), bfpack(e.z*QSCALE_, e.w*QSCALE_));
  }
  f32x4 oA[4] = {{0,0,0,0},{0,0,0,0},{0,0,0,0},{0,0,0,0}};
  f32x4 oB[4] = {{0,0,0,0},{0,0,0,0},{0,0,0,0},{0,0,0,0}};
  float ssA = 0.f, ssB = 0.f;
  const f32x4 accb = {-M0L2_, -M0L2_, -M0L2_, -M0L2_};   // pre-biased accumulator

  // staging ids
  const int krow_l = tid >> 1, kpart = tid & 1;        // K: 2 thr/row, 64B each
  const int kpi = tid & 63;                            // V: key-pair 2kpi,2kpi+1
  const int vdb = (tid >> 6) * 16;                     // V: d-base (ushort)
  char* kdst = (char*)kk + krow_l * 144 + kpart * 64;
  char* vdst = (char*)vv + (kpi >> 5) * 9216 + vdb * 144 + (kpi & 31) * 4;
  const char* kq = (const char*)kk + q * 144 + g * 16;
  const char* vq = (const char*)vv + q * 144 + g * 16;
  char* pw = (char*)pbuf + w * 1280 + q * 80;

  const uint4 z4 = make_uint4(0, 0, 0, 0);
  uint4 kp0, kp1, kp2, kp3, va, va2, vb_, vb2;

#define LOADK(T) { const int kr = (T) * 128 + krow_l; \
    if (kr < 1016) { const uint4* s = (const uint4*)(Kb + (hN + kbase + kr) * 64 + kpart * 32); \
      kp0 = s[0]; kp1 = s[1]; kp2 = s[2]; kp3 = s[3]; } \
    else { kp0 = z4; kp1 = z4; kp2 = z4; kp3 = z4; } }
#define LOADV(T) { const int kr0 = (T) * 128 + 2 * kpi; \
    if (kr0 < 1016) { const uint4* s0 = (const uint4*)(Vb + (hN + kbase + kr0) * 64 + vdb); \
      const uint4* s1 = (const uint4*)(Vb + (hN + kbase + kr0 + 1) * 64 + vdb); \
      va = s0[0]; va2 = s0[1]; vb_ = s1[0]; vb2 = s1[1]; } \
    else { va = z4; va2 = z4; vb_ = z4; vb2 = z4; } }

  LOADK(0) LOADV(0)

  for (int t = 0; t < ntiles; ++t) {
    const int kt = t * 128;
    __syncthreads();
    // ---- stage from regs ----
    *(uint4*)kdst = kp0; *(uint4*)(kdst + 16) = kp1;
    *(uint4*)(kdst + 32) = kp2; *(uint4*)(kdst + 48) = kp3;
#define VP(BASE, JW, AW, BW) { \
    *(uint*)(vdst + (BASE + 2*(JW)) * 144) = (AW & 0xffffu) | (BW << 16); \
    *(uint*)(vdst + (BASE + 2*(JW) + 1) * 144) = (AW >> 16) | (BW & 0xffff0000u); }
    VP(0, 0, va.x, vb_.x) VP(0, 1, va.y, vb_.y) VP(0, 2, va.z, vb_.z) VP(0, 3, va.w, vb_.w)
    VP(8, 0, va2.x, vb2.x) VP(8, 1, va2.y, vb2.y) VP(8, 2, va2.z, vb2.z) VP(8, 3, va2.w, vb2.w)
#undef VP
    __syncthreads();
    if (t + 1 < ntiles) { LOADK(t + 1) LOADV(t + 1) }

    // ---- compute two 64-key halves ----
#pragma unroll
    for (int u2 = 0; u2 < 2; ++u2) {
      const int hb = kt + u2 * 64;
      const bool dA = !(causal && hb > qwmaxA);
      f32x4 sA[4], sB[4];
#pragma unroll
      for (int st = 0; st < 4; ++st) {
        B8 ka, kb2;
        ka.u  = *(const uint4*)(kq + (u2 * 64 + st * 16) * 144);
        kb2.u = *(const uint4*)(kq + (u2 * 64 + st * 16) * 144 + 64);
        if (dA) {
          f32x4 acc = accb;
          acc = mfma16(ka, qbA0, acc); acc = mfma16(kb2, qbA1, acc);
          sA[st] = acc;
        }
        f32x4 acc2 = accb;
        acc2 = mfma16(ka, qbB0, acc2); acc2 = mfma16(kb2, qbB1, acc2);
        sB[st] = acc2;
      }

      if (causal) {
        const int kb0 = hb + 4 * g;
        if (dA && hb + 63 > qwA_lo) {
#pragma unroll
          for (int st = 0; st < 4; ++st)
#pragma unroll
            for (int r = 0; r < 4; ++r)
              if (kb0 + st * 16 + r > qrowA) sA[st][r] = NEGBIG_;
        }
        if (hb + 63 > qwB_lo) {
#pragma unroll
          for (int st = 0; st < 4; ++st)
#pragma unroll
            for (int r = 0; r < 4; ++r)
              if (kb0 + st * 16 + r > qrowB) sB[st][r] = NEGBIG_;
        }
      } else if (hb + 63 >= 1016) {
        const int kb0 = hb + 4 * g;
#pragma unroll
        for (int st = 0; st < 4; ++st)
#pragma unroll
          for (int r = 0; r < 4; ++r)
            if (kb0 + st * 16 + r >= 1016) { sA[st][r] = NEGBIG_; sB[st][r] = NEGBIG_; }
      }

      if (dA) {
        nomax_sm(sA, ssA);
        pv_go(sA, oA, vq + u2 * 9216, pw, g);
      }
      nomax_sm(sB, ssB);
      pv_go(sB, oB, vq + u2 * 9216, pw, g);
    }
  }
#undef LOADK
#undef LOADV

  // ---- epilogue: reduce ssum across g-lanes, then write ----
  ssA += __shfl_xor(ssA, 16); ssA += __shfl_xor(ssA, 32);
  ssB += __shfl_xor(ssB, 16); ssB += __shfl_xor(ssB, 32);
#pragma unroll
  for (int fr = 0; fr < 2; ++fr) {
    const int qrow = fr == 0 ? qrowA : qrowB;
    if (qrow >= 1016) continue;
    f32x4* o = fr == 0 ? oA : oB;
    const float ss = fr == 0 ? ssA : ssB;
    const float lse = M0_ + __logf(ss);
    const float inv = 1.f / ss;
    if (causal) {
      const int trow = chunkc * 1016 + qrow;
      float* tp = tail_attn + ((size_t)h * NT_ + trow) * 64;
      *(f32x4*)(tp +  0 + 4*g) = o[0] * inv;
      *(f32x4*)(tp + 16 + 4*g) = o[1] * inv;
      *(f32x4*)(tp + 32 + 4*g) = o[2] * inv;
      *(f32x4*)(tp + 48 + 4*g) = o[3] * inv;
      if (lane < 16) tail_lse[h * NT_ + trow] = lse;
    } else {
      float* tp = attn2 + ((size_t)p2vh * 1016 + qrow) * 64;
      *(f32x4*)(tp +  0 + 4*g) = o[0] * inv;
      *(f32x4*)(tp + 16 + 4*g) = o[1] * inv;
      *(f32x4*)(tp + 32 + 4*g) = o[2] * inv;
      *(f32x4*)(tp + 48 + 4*g) = o[3] * inv;
      if (lane < 16) lse2[p2vh * 1016 + qrow] = lse;
    }
  }
}

// ---------------- merge P2 into tail ----------------
__global__ __launch_bounds__(128) void kern_merge2(float* __restrict__ tail_attn, float* __restrict__ tail_lse,
                                                   const float* __restrict__ attn2, const float* __restrict__ lse2) {
  const int vh = blockIdx.x;
  const int i = blockIdx.y * 128 + (int)threadIdx.x;
  if (i >= 1016) return;
  const int h = vh >> 1, pp = vh & 1;
  const int t = pp * 2032 + 1016 + i;
  const float l2 = lse2[vh * 1016 + i];
  float* tlp = tail_lse + h * NT_ + t;
  const float bl = *tlp;
  const float c = 1.f / (1.f + __expf(l2 - bl));
  const float4* ap = (const float4*)(attn2 + ((size_t)vh * 1016 + i) * 64);
  float4* tp = (float4*)(tail_attn + ((size_t)h * NT_ + t) * 64);
#pragma unroll
  for (int d = 0; d < 16; ++d) {
    const float4 bd = tp[d], a2 = ap[d];
    tp[d] = make_float4(c * bd.x + (1.f - c) * a2.x,
                        c * bd.y + (1.f - c) * a2.y,
                        c * bd.z + (1.f - c) * a2.z,
                        c * bd.w + (1.f - c) * a2.w);
  }
  *tlp = logaddexpf_(bl, l2);
}

// =========================================================================
// MFMA LSH attention (64-key tiles, upfront indices + reg prefetch),
// fixed-offset softmax, merged into tail.
// =========================================================================
__global__ __launch_bounds__(256) void kern_lsh_mfma(
    const float* __restrict__ Q, const ushort* __restrict__ Kb, const ushort* __restrict__ Vb,
    const int* __restrict__ q_sort, const int* __restrict__ k_sort,
    const int* __restrict__ samp_pos, const int* __restrict__ samp_orig,
    float* __restrict__ tail_attn, float* __restrict__ tail_lse) {
  __shared__ uint kk[2304];    // 64*144
  __shared__ uint vv[2304];    // 64 d rows * 144B
  __shared__ uint pbuf[1280];
  __shared__ float bias_s[64];

  const int b = blockIdx.x;
  const int h = b >> 4, pt = b & 15;
  const int tid = threadIdx.x;
  const int lane = tid & 63, w = tid >> 6;
  const int g = lane >> 4, q = lane & 15;
  const int blkq = pt >> 1;
  const size_t hN = (size_t)h * N_;

  const int pA = pt * 128 + w * 16 + q;
  const int pB = pA + 64;
  const int qiA = q_sort[h * NL_ + min(pA, NL_ - 1)];
  const int qiB = q_sort[h * NL_ + min(pB, NL_ - 1)];

  // ---- upfront gather indices ----
  const int skey = tid >> 2, kpart = tid & 3;
  const int kpi = tid & 31, vdb = (tid >> 5) * 8;
  int kidx[8], vi0[8], vi1[8];
#pragma unroll
  for (int t = 0; t < 8; ++t) {
    if (t < 4) {
      const int slot = blkq * 256 + t * 64 + skey;
      kidx[t] = (slot < NL_) ? k_sort[h * NL_ + slot] : -1;
      const int s0 = blkq * 256 + t * 64 + 2 * kpi;
      vi0[t] = (s0 < NL_) ? k_sort[h * NL_ + s0] : -1;
      vi1[t] = (s0 + 1 < NL_) ? k_sort[h * NL_ + s0 + 1] : -1;
    } else {
      kidx[t] = samp_orig[h * SAMP_ + (t - 4) * 64 + skey];
      const int si = (t - 4) * 64 + 2 * kpi;
      vi0[t] = samp_orig[h * SAMP_ + si];
      vi1[t] = samp_orig[h * SAMP_ + si + 1];
    }
  }
  float biasr[4];
  if (tid < 64) {
#pragma unroll
    for (int j = 0; j < 4; ++j)
      biasr[j] = ((samp_pos[h * SAMP_ + j * 64 + tid] >> 8) == blkq) ? NEGBIG_ : LOGOFF_L2_;
  }

  B8 qbA0, qbA1, qbB0, qbB1;
  {
    const float4* qp = (const float4*)(Q + (hN + SINK_ + NL_ + qiA) * 64);
    float4 a = qp[2*g], c = qp[2*g+1], d = qp[8+2*g], e = qp[8+2*g+1];
    qbA0.u = make_uint4(bfpack(a.x*QSCALE_, a.y*QSCALE_), bfpack(a.z*QSCALE_, a.w*QSCALE_),
                        bfpack(c.x*QSCALE_, c.y*QSCALE_), bfpack(c.z*QSCALE_, c.w*QSCALE_));
    qbA1.u = make_uint4(bfpack(d.x*QSCALE_, d.y*QSCALE_), bfpack(d.z*QSCALE_, d.w*QSCALE_),
                        bfpack(e.x*QSCALE_, e.y*QSCALE_), bfpack(e.z*QSCALE_, e.w*QSCALE_));
    const float4* qp2 = (const float4*)(Q + (hN + SINK_ + NL_ + qiB) * 64);
    a = qp2[2*g]; c = qp2[2*g+1]; d = qp2[8+2*g]; e = qp2[8+2*g+1];
    qbB0.u = make_uint4(bfpack(a.x*QSCALE_, a.y*QSCALE_), bfpack(a.z*QSCALE_, a.w*QSCALE_),
                        bfpack(c.x*QSCALE_, c.y*QSCALE_), bfpack(c.z*QSCALE_, c.w*QSCALE_));
    qbB1.u = make_uint4(bfpack(d.x*QSCALE_, d.y*QSCALE_), bfpack(d.z*QSCALE_, d.w*QSCALE_),
                        bfpack(e.x*QSCALE_, e.y*QSCALE_), bfpack(e.z*QSCALE_, e.w*QSCALE_));
  }
  f32x4 oA[4] = {{0,0,0,0},{0,0,0,0},{0,0,0,0},{0,0,0,0}};
  f32x4 oB[4] = {{0,0,0,0},{0,0,0,0},{0,0,0,0},{0,0,0,0}};
  float ssA = 0.f, ssB = 0.f;
  const f32x4 accb = {-M0L2_, -M0L2_, -M0L2_, -M0L2_};

  char* kdst = (char*)kk + skey * 144 + kpart * 32;
  char* vdst = (char*)vv + vdb * 144 + kpi * 4;
  const char* kq = (const char*)kk + q * 144 + g * 16;
  const char* vq = (const char*)vv + q * 144 + g * 16;
  char* pw = (char*)pbuf + w * 1280 + q * 80;

  const uint4 z4 = make_uint4(0, 0, 0, 0);
  uint4 kp0, kp1, va, vb_;

#define LLOADK(T) { const int kr = kidx[T]; \
    if (kr >= 0) { const uint4* s = (const uint4*)(Kb + (hN + SINK_ + kr) * 64 + kpart * 16); \
      kp0 = s[0]; kp1 = s[1]; } else { kp0 = z4; kp1 = z4; } }
#define LLOADV(T) { const int r0 = vi0[T], r1 = vi1[T]; \
    va  = (r0 >= 0) ? *(const uint4*)(Vb + (hN + SINK_ + r0) * 64 + vdb) : z4; \
    vb_ = (r1 >= 0) ? *(const uint4*)(Vb + (hN + SINK_ + r1) * 64 + vdb) : z4; }

  LLOADK(0) LLOADV(0)

  for (int t = 0; t < 8; ++t) {
    __syncthreads();
    *(uint4*)kdst = kp0; *(uint4*)(kdst + 16) = kp1;
#define VP(JW, AW, BW) { \
    *(uint*)(vdst + (2*(JW)) * 144) = (AW & 0xffffu) | (BW << 16); \
    *(uint*)(vdst + (2*(JW) + 1) * 144) = (AW >> 16) | (BW & 0xffff0000u); }
    VP(0, va.x, vb_.x) VP(1, va.y, vb_.y) VP(2, va.z, vb_.z) VP(3, va.w, vb_.w)
#undef VP
    if (t >= 4 && tid < 64) bias_s[tid] = biasr[t - 4];
    __syncthreads();
    if (t + 1 < 8) { LLOADK(t + 1) LLOADV(t + 1) }

    f32x4 sA[4], sB[4];
#pragma unroll
    for (int st = 0; st < 4; ++st) {
      B8 ka, kb2;
      ka.u  = *(const uint4*)(kq + (st * 16) * 144);
      kb2.u = *(const uint4*)(kq + (st * 16) * 144 + 64);
      f32x4 acc = accb;
      acc = mfma16(ka, qbA0, acc); acc = mfma16(kb2, qbA1, acc);
      sA[st] = acc;
      f32x4 acc2 = accb;
      acc2 = mfma16(ka, qbB0, acc2); acc2 = mfma16(kb2, qbB1, acc2);
      sB[st] = acc2;
    }
    if (t >= 4) {
      const f32x4* bp = (const f32x4*)bias_s;
#pragma unroll
      for (int st = 0; st < 4; ++st) {
        sA[st] = sA[st] + bp[st * 4 + g];
        sB[st] = sB[st] + bp[st * 4 + g];
      }
    }

    nomax_sm(sA, ssA);
    pv_go(sA, oA, vq, pw, g);
    nomax_sm(sB, ssB);
    pv_go(sB, oB, vq, pw, g);
  }
#undef LLOADK
#undef LLOADV

  ssA += __shfl_xor(ssA, 16); ssA += __shfl_xor(ssA, 32);
  ssB += __shfl_xor(ssB, 16); ssB += __shfl_xor(ssB, 32);
#pragma unroll
  for (int fr = 0; fr < 2; ++fr) {
    const int p = fr == 0 ? pA : pB;
    if (p >= NL_) continue;
    const int qi = fr == 0 ? qiA : qiB;
    f32x4* o = fr == 0 ? oA : oB;
    const float ss = fr == 0 ? ssA : ssB;
    const float un = M0_ + __logf(ss);
    const float inv = 1.f / ss;
    const int trow = NL_ + qi;
    float* tlp = tail_lse + h * NT_ + trow;
    const float bd = *tlp;
    const float c2 = 1.f / (1.f + __expf(un - bd));
    const float w2 = inv * (1.f - c2);
    float* tp = tail_attn + ((size_t)h * NT_ + trow) * 64;
    f32x4 t0 = *(f32x4*)(tp +  0 + 4*g);
    f32x4 t1 = *(f32x4*)(tp + 16 + 4*g);
    f32x4 t2 = *(f32x4*)(tp + 32 + 4*g);
    f32x4 t3 = *(f32x4*)(tp + 48 + 4*g);
    *(f32x4*)(tp +  0 + 4*g) = t0 * c2 + o[0] * w2;
    *(f32x4*)(tp + 16 + 4*g) = t1 * c2 + o[1] * w2;
    *(f32x4*)(tp + 32 + 4*g) = t2 * c2 + o[2] * w2;
    *(f32x4*)(tp + 48 + 4*g) = t3 * c2 + o[3] * w2;
    if (lane < 16) *tlp = logaddexpf_(bd, un);
  }
}

// ---------------- sink prefix + final merge ----------------
__global__ __launch_bounds__(256) void kern_final(const float* __restrict__ Q, const float* __restrict__ K,
                                                  const float* __restrict__ V,
                                                  const float* __restrict__ tail_attn, const float* __restrict__ tail_lse,
                                                  float* __restrict__ out) {
  const int h = blockIdx.x;
  const int r = blockIdx.y * 256 + (int)threadIdx.x;

  __shared__ float4 kk[SINK_ * 16];
  __shared__ float4 vv[SINK_ * 16];
  for (int u = threadIdx.x; u < SINK_ * 16; u += 256) {
    const int row = u >> 4, d4 = u & 15;
    kk[u] = ((const float4*)(K + ((size_t)h * N_ + row) * 64))[d4];
    vv[u] = ((const float4*)(V + ((size_t)h * N_ + row) * 64))[d4];
  }
  __syncthreads();

  float4 q4[16], acc[16];
  const float4* qp = (const float4*)(Q + ((size_t)h * N_ + r) * 64);
#pragma unroll
  for (int d = 0; d < 16; ++d) { q4[d] = qp[d]; acc[d] = make_float4(0.f, 0.f, 0.f, 0.f); }

  float m = -INFINITY, ssum = 0.f;
  const int nk = min(SINK_, r + 1);
  for (int j = 0; j < nk; ++j) {
    float s = 0.f;
#pragma unroll
    for (int d = 0; d < 16; ++d) {
      float4 x = q4[d], y = kk[j * 16 + d];
      s = fmaf(x.x, y.x, s); s = fmaf(x.y, y.y, s);
      s = fmaf(x.z, y.z, s); s = fmaf(x.w, y.w, s);
    }
    s *= SCALE_;
    const float nm = fmaxf(m, s);
    const float f = __expf(m - nm), wgt = __expf(s - nm);
    ssum = ssum * f + wgt;
    const float4* v4 = &vv[j * 16];
#pragma unroll
    for (int d = 0; d < 16; ++d) {
      acc[d].x = acc[d].x * f + wgt * v4[d].x;
      acc[d].y = acc[d].y * f + wgt * v4[d].y;
      acc[d].z = acc[d].z * f + wgt * v4[d].z;
      acc[d].w = acc[d].w * f + wgt * v4[d].w;
    }
    m = nm;
  }
  const float pl = m + __logf(ssum);
  const float inv = 1.f / ssum;
  float4* op = (float4*)(out + ((size_t)h * N_ + r) * 64);
  if (r < SINK_) {
#pragma unroll
    for (int d = 0; d < 16; ++d)
      op[d] = make_float4(acc[d].x * inv, acc[d].y * inv, acc[d].z * inv, acc[d].w * inv);
  } else {
    const int t = r - SINK_;
    const float tl = tail_lse[h * NT_ + t];
    const float cc = 1.f / (1.f + __expf(tl - pl));
    const float4* tp = (const float4*)(tail_attn + ((size_t)h * NT_ + t) * 64);
#pragma unroll
    for (int d = 0; d < 16; ++d) {
      const float4 tv = tp[d];
      op[d] = make_float4(cc * acc[d].x * inv + (1.f - cc) * tv.x,
                          cc * acc[d].y * inv + (1.f - cc) * tv.y,
                          cc * acc[d].z * inv + (1.f - cc) * tv.z,
                          cc * acc[d].w * inv + (1.f - cc) * tv.w);
    }
  }
}

// ---------------- host ----------------
extern "C" void kernel_launch(void* const* d_in, const int* in_sizes, int n_in,
                              void* d_out, int out_size, void* d_ws, size_t ws_size,
                              hipStream_t stream) {
  (void)in_sizes; (void)n_in; (void)out_size; (void)ws_size;
  const float* Q = (const float*)d_in[0];
  const float* K = (const float*)d_in[1];
  const float* V = (const float*)d_in[2];
  const float* proj = (const float*)d_in[3];
  float* out = (float*)d_out;

  char* w = (char*)d_ws;
  auto carve = [&](size_t bytes) { char* p = w; w += (bytes + 255) & ~(size_t)255; return p; };
  float* tail_attn = (float*)carve((size_t)H_ * NT_ * 64 * sizeof(float));
  float* tail_lse  = (float*)carve((size_t)H_ * NT_ * sizeof(float));
  float* attn2     = (float*)carve((size_t)32 * 1016 * 64 * sizeof(float));
  float* lse2      = (float*)carve((size_t)32 * 1016 * sizeof(float));
  ushort* Kb     = (ushort*)carve((size_t)H_ * N_ * 64 * sizeof(ushort));
  ushort* Vb     = (ushort*)carve((size_t)H_ * N_ * 64 * sizeof(ushort));
  int* hq        = (int*)carve((size_t)H_ * NL_ * sizeof(int));
  int* hk        = (int*)carve((size_t)H_ * NL_ * sizeof(int));
  int* q_sort    = (int*)carve((size_t)H_ * NL_ * sizeof(int));
  int* k_sort    = (int*)carve((size_t)H_ * NL_ * sizeof(int));
  int* samp_pos  = (int*)carve((size_t)H_ * SAMP_ * sizeof(int));
  int* samp_orig = (int*)carve((size_t)H_ * SAMP_ * sizeof(int));

  kern_packhash<<<dim3(4352), 256, 0, stream>>>(K, V, Q, proj, Kb, Vb, hq, hk);
  kern_sortsamp<<<dim3(H_, 2), 256, 0, stream>>>(hq, hk, q_sort, k_sort, samp_pos, samp_orig);
  kern_attn_mfma<<<dim3(768), 256, 0, stream>>>(Q, Kb, Vb, tail_attn, tail_lse, attn2, lse2);
  kern_merge2<<<dim3(32, 8), 128, 0, stream>>>(tail_attn, tail_lse, attn2, lse2);
  kern_lsh_mfma<<<dim3(256), 256, 0, stream>>>(Q, Kb, Vb, q_sort, k_sort, samp_pos, samp_orig,
                                               tail_attn, tail_lse);
  kern_final<<<dim3(H_, 16), 256, 0, stream>>>(Q, K, V, tail_attn, tail_lse, out);
}